// Round 1
// baseline (940.951 us; speedup 1.0000x reference)
//
#include <hip/hip_runtime.h>
#include <hip/hip_bf16.h>
#include <stdint.h>

#define N_NODES 100000
#define N_EDGES 3200000
#define IN_CH 256
#define HID 128
#define EPS 1e-5f
#define NB 391  // ceil(100000/256)

using bf16x8 = __attribute__((ext_vector_type(8))) short;
using f32x4  = __attribute__((ext_vector_type(4))) float;

__device__ __forceinline__ uint16_t f2bf(float f) {
  uint32_t u = __float_as_uint(f);
  uint32_t r = (u + 0x7FFFu + ((u >> 16) & 1u)) >> 16;
  return (uint16_t)r;
}
__device__ __forceinline__ float bflo(uint32_t u) { return __uint_as_float(u << 16); }
__device__ __forceinline__ float bfhi(uint32_t u) { return __uint_as_float(u & 0xFFFF0000u); }

// ---- workspace layout (bytes) ----
static const size_t OFF_SEDGE = 0;                    // int2[3.2M] = 25,600,000
static const size_t OFF_COUNTS = 25600000;            // int[100000]
static const size_t OFF_OFFS   = 26000000;            // int[100001]
static const size_t OFF_CURS   = 26400256;            // int[100000]
static const size_t OFF_DINV   = 26800256;            // float[100000]
static const size_t OFF_WPK0   = 27200256;            // 65536 B
static const size_t OFF_WPK1   = 27265792;            // 32768 B
static const size_t OFF_WPK2   = 27298560;            // 32768 B
static const size_t OFF_WPKR   = 27331328;            // 65536 B
static const size_t OFF_FLAG   = 27396864;            // int
static const size_t OFF_BSUM   = 27397120;            // int[391]
static const size_t OFF_RES    = 27400000;            // float[100000*128] = 51,200,000
static const size_t OFF_SRC32  = 27400000;            // int[3.2M] (dead before RES written)
static const size_t OFF_DST32  = 40200000;            // int[3.2M] (dead before RES written)
static const size_t OFF_HWB    = 78600000;            // bf16[100000*128] = 25,600,000
static const size_t OFF_HB16   = 104200000;           // bf16[100000*128]
static const size_t OFF_XB16   = 129800000;           // bf16[100000*256] = 51,200,000
static const size_t OFF_H      = 129800000;           // float[100000*128] (aliases XB16; XB16 dead by then)

// ---- edge dtype detection: int64 edges have zero high words ----
__global__ void k_flag(const uint32_t* __restrict__ e, int* flag) {
  __shared__ int any;
  if (threadIdx.x == 0) any = 0;
  __syncthreads();
  uint32_t acc = 0;
  for (int i = threadIdx.x; i < 2048; i += blockDim.x) acc |= e[2 * i + 1];
  if (acc) atomicOr(&any, 1);
  __syncthreads();
  if (threadIdx.x == 0) *flag = (any == 0) ? 1 : 0;  // 1 => int64 layout
}

__global__ void k_convert(const void* __restrict__ eidx, const int* __restrict__ flag,
                          int* __restrict__ src, int* __restrict__ dst) {
  int e = blockIdx.x * blockDim.x + threadIdx.x;
  if (e >= N_EDGES) return;
  if (*flag) {
    const uint32_t* u = (const uint32_t*)eidx;
    src[e] = (int)u[2 * (size_t)e];
    dst[e] = (int)u[2 * ((size_t)N_EDGES + e)];
  } else {
    const int* u = (const int*)eidx;
    src[e] = u[e];
    dst[e] = u[N_EDGES + e];
  }
}

__global__ void k_deg(const int* __restrict__ dst, int* __restrict__ counts) {
  int e = blockIdx.x * blockDim.x + threadIdx.x;
  if (e < N_EDGES) atomicAdd(&counts[dst[e]], 1);
}

__global__ void k_dinv(const int* __restrict__ counts, float* __restrict__ dinv) {
  int v = blockIdx.x * blockDim.x + threadIdx.x;
  if (v < N_NODES) dinv[v] = rsqrtf((float)(counts[v] + 1));
}

__global__ void k_scan1(const int* __restrict__ counts, int* __restrict__ bsum) {
  __shared__ int sm[256];
  int i = blockIdx.x * 256 + threadIdx.x;
  sm[threadIdx.x] = (i < N_NODES) ? counts[i] : 0;
  __syncthreads();
  for (int s = 128; s > 0; s >>= 1) {
    if (threadIdx.x < s) sm[threadIdx.x] += sm[threadIdx.x + s];
    __syncthreads();
  }
  if (threadIdx.x == 0) bsum[blockIdx.x] = sm[0];
}

__global__ void k_scan2(int* __restrict__ bsum, int* __restrict__ offs) {
  if (threadIdx.x == 0 && blockIdx.x == 0) {
    int run = 0;
    for (int b = 0; b < NB; ++b) { int t = bsum[b]; bsum[b] = run; run += t; }
    offs[N_NODES] = run;
  }
}

__global__ void k_scan3(const int* __restrict__ counts, const int* __restrict__ bsum,
                        int* __restrict__ offs, int* __restrict__ cursor) {
  __shared__ int sm[256];
  int i = blockIdx.x * 256 + threadIdx.x;
  int vc = (i < N_NODES) ? counts[i] : 0;
  sm[threadIdx.x] = vc;
  __syncthreads();
  for (int s = 1; s < 256; s <<= 1) {
    int t = (threadIdx.x >= (unsigned)s) ? sm[threadIdx.x - s] : 0;
    __syncthreads();
    sm[threadIdx.x] += t;
    __syncthreads();
  }
  if (i < N_NODES) {
    int excl = sm[threadIdx.x] - vc + bsum[blockIdx.x];
    offs[i] = excl;
    cursor[i] = excl;
  }
}

__global__ void k_fill(const int* __restrict__ src, const int* __restrict__ dst,
                       const float* __restrict__ dinv, int* __restrict__ cursor,
                       int2* __restrict__ sedge) {
  int e = blockIdx.x * blockDim.x + threadIdx.x;
  if (e >= N_EDGES) return;
  int s = src[e], d = dst[e];
  float nrm = dinv[s] * dinv[d];
  int p = atomicAdd(&cursor[d], 1);
  sedge[p] = make_int2(s, __float_as_int(nrm));
}

// f32 -> bf16, 4 at a time
__global__ void k_cvt(const float* __restrict__ in, uint16_t* __restrict__ out, int n4) {
  int i = blockIdx.x * blockDim.x + threadIdx.x;
  if (i >= n4) return;
  float4 v = ((const float4*)in)[i];
  uint2 o;
  o.x = (uint32_t)f2bf(v.x) | ((uint32_t)f2bf(v.y) << 16);
  o.y = (uint32_t)f2bf(v.z) | ((uint32_t)f2bf(v.w) << 16);
  ((uint2*)out)[i] = o;
}

// pack W [K][HID] f32 row-major into MFMA B-fragment-ready bf16 layout
__global__ void k_packW(const float* __restrict__ W, uint16_t* __restrict__ Wp, int K) {
  int t = blockIdx.x * blockDim.x + threadIdx.x;
  int total = (K / 32) * 8 * 64;
  if (t >= total) return;
  int l = t & 63;
  int nt = (t >> 6) & 7;
  int ks = t >> 9;
  int kbase = ks * 32 + (l >> 4) * 8;
  int col = nt * 16 + (l & 15);
  #pragma unroll
  for (int j = 0; j < 8; ++j)
    Wp[(size_t)t * 8 + j] = f2bf(W[(size_t)(kbase + j) * HID + col]);
}

// C = A[M,K]_bf16 @ Wpack -> [M,128], one wave = 16 rows x 128 cols, no LDS
__global__ __launch_bounds__(256) void k_gemm(const uint16_t* __restrict__ A, int K,
                                              const uint16_t* __restrict__ Wp,
                                              float* __restrict__ Cf,
                                              uint16_t* __restrict__ Cb) {
  int wid = threadIdx.x >> 6, l = threadIdx.x & 63;
  int tile = blockIdx.x * 4 + wid;
  if (tile >= N_NODES / 16) return;
  int row0 = tile * 16;
  f32x4 acc[8] = {};
  int ar = row0 + (l & 15);
  int ak = (l >> 4) * 8;
  const bf16x8* Bp = (const bf16x8*)Wp;
  int nks = K >> 5;
  for (int ks = 0; ks < nks; ++ks) {
    bf16x8 a = *(const bf16x8*)(A + (size_t)ar * K + ks * 32 + ak);
    #pragma unroll
    for (int nt = 0; nt < 8; ++nt) {
      bf16x8 b = Bp[(size_t)(ks * 8 + nt) * 64 + l];
      acc[nt] = __builtin_amdgcn_mfma_f32_16x16x32_bf16(a, b, acc[nt], 0, 0, 0);
    }
  }
  int crow = row0 + (l >> 4) * 4;
  int ccol = l & 15;
  if (Cf) {
    #pragma unroll
    for (int nt = 0; nt < 8; ++nt)
      #pragma unroll
      for (int j = 0; j < 4; ++j)
        Cf[(size_t)(crow + j) * HID + nt * 16 + ccol] = acc[nt][j];
  } else {
    #pragma unroll
    for (int nt = 0; nt < 8; ++nt)
      #pragma unroll
      for (int j = 0; j < 4; ++j)
        Cb[(size_t)(crow + j) * HID + nt * 16 + ccol] = f2bf(acc[nt][j]);
  }
}

// fused: degree-normalized gather-sum + bias + LN + ReLU + residual
// one wave per node, lane l owns channels 2l, 2l+1
__global__ __launch_bounds__(256) void k_agg(const uint16_t* __restrict__ hWb,
                                             const int2* __restrict__ sedge,
                                             const int* __restrict__ offs,
                                             const float* __restrict__ dinv,
                                             const float* __restrict__ bias,
                                             const float* __restrict__ g,
                                             const float* __restrict__ be,
                                             const float* __restrict__ resid,
                                             float* __restrict__ outF,
                                             uint16_t* __restrict__ outB) {
  int wid = threadIdx.x >> 6, l = threadIdx.x & 63;
  int v = blockIdx.x * 4 + wid;
  if (v >= N_NODES) return;
  const uint32_t* H = (const uint32_t*)hWb;
  float a0 = 0.f, a1 = 0.f;
  int p0 = offs[v], p1 = offs[v + 1];
  int p = p0;
  for (; p + 3 < p1; p += 4) {
    int2 e0 = sedge[p], e1 = sedge[p + 1], e2 = sedge[p + 2], e3 = sedge[p + 3];
    uint32_t u0 = H[(size_t)e0.x * 64 + l];
    uint32_t u1 = H[(size_t)e1.x * 64 + l];
    uint32_t u2 = H[(size_t)e2.x * 64 + l];
    uint32_t u3 = H[(size_t)e3.x * 64 + l];
    float w0 = __int_as_float(e0.y), w1 = __int_as_float(e1.y);
    float w2 = __int_as_float(e2.y), w3 = __int_as_float(e3.y);
    a0 += w0 * bflo(u0) + w1 * bflo(u1) + w2 * bflo(u2) + w3 * bflo(u3);
    a1 += w0 * bfhi(u0) + w1 * bfhi(u1) + w2 * bfhi(u2) + w3 * bfhi(u3);
  }
  for (; p < p1; ++p) {
    int2 e = sedge[p];
    uint32_t u = H[(size_t)e.x * 64 + l];
    float w = __int_as_float(e.y);
    a0 += w * bflo(u);
    a1 += w * bfhi(u);
  }
  {  // self loop
    float dv = dinv[v];
    float w = dv * dv;
    uint32_t u = H[(size_t)v * 64 + l];
    a0 += w * bflo(u);
    a1 += w * bfhi(u);
  }
  float2 bb = *(const float2*)(bias + 2 * l);
  a0 += bb.x;
  a1 += bb.y;
  // LayerNorm over 128 channels (wave reduction)
  float s = a0 + a1;
  #pragma unroll
  for (int m = 1; m < 64; m <<= 1) s += __shfl_xor(s, m, 64);
  float mu = s * (1.f / 128.f);
  float d0 = a0 - mu, d1 = a1 - mu;
  float q = d0 * d0 + d1 * d1;
  #pragma unroll
  for (int m = 1; m < 64; m <<= 1) q += __shfl_xor(q, m, 64);
  float rs = rsqrtf(q * (1.f / 128.f) + EPS);
  float2 gg = *(const float2*)(g + 2 * l);
  float2 ee = *(const float2*)(be + 2 * l);
  float y0 = fmaxf(d0 * rs * gg.x + ee.x, 0.f);
  float y1 = fmaxf(d1 * rs * gg.y + ee.y, 0.f);
  float2 rr = *(const float2*)(resid + (size_t)v * HID + 2 * l);
  y0 += rr.x;
  y1 += rr.y;
  ((float2*)(outF + (size_t)v * HID))[l] = make_float2(y0, y1);
  if (outB) {
    uint32_t o = (uint32_t)f2bf(y0) | ((uint32_t)f2bf(y1) << 16);
    ((uint32_t*)outB)[(size_t)v * 64 + l] = o;
  }
}

extern "C" void kernel_launch(void* const* d_in, const int* in_sizes, int n_in,
                              void* d_out, int out_size, void* d_ws, size_t ws_size,
                              hipStream_t stream) {
  const float* x   = (const float*)d_in[0];
  const void*  ei  = d_in[1];
  const float* W0  = (const float*)d_in[2];
  const float* b0  = (const float*)d_in[3];
  const float* g0  = (const float*)d_in[4];
  const float* be0 = (const float*)d_in[5];
  const float* W1  = (const float*)d_in[6];
  const float* b1  = (const float*)d_in[7];
  const float* g1  = (const float*)d_in[8];
  const float* be1 = (const float*)d_in[9];
  const float* W2  = (const float*)d_in[10];
  const float* b2  = (const float*)d_in[11];
  const float* g2  = (const float*)d_in[12];
  const float* be2 = (const float*)d_in[13];
  const float* Wr  = (const float*)d_in[14];

  char* ws = (char*)d_ws;
  int2*     sedge  = (int2*)(ws + OFF_SEDGE);
  int*      counts = (int*)(ws + OFF_COUNTS);
  int*      offs   = (int*)(ws + OFF_OFFS);
  int*      cursor = (int*)(ws + OFF_CURS);
  float*    dinv   = (float*)(ws + OFF_DINV);
  uint16_t* wpk0   = (uint16_t*)(ws + OFF_WPK0);
  uint16_t* wpk1   = (uint16_t*)(ws + OFF_WPK1);
  uint16_t* wpk2   = (uint16_t*)(ws + OFF_WPK2);
  uint16_t* wpkr   = (uint16_t*)(ws + OFF_WPKR);
  int*      flag   = (int*)(ws + OFF_FLAG);
  int*      bsum   = (int*)(ws + OFF_BSUM);
  float*    res    = (float*)(ws + OFF_RES);
  int*      src32  = (int*)(ws + OFF_SRC32);
  int*      dst32  = (int*)(ws + OFF_DST32);
  uint16_t* hWb    = (uint16_t*)(ws + OFF_HWB);
  uint16_t* hb16   = (uint16_t*)(ws + OFF_HB16);
  uint16_t* xb16   = (uint16_t*)(ws + OFF_XB16);
  float*    hbuf   = (float*)(ws + OFF_H);
  float*    out    = (float*)d_out;

  // ---- edge preprocessing ----
  k_flag<<<1, 256, 0, stream>>>((const uint32_t*)ei, flag);
  k_convert<<<12500, 256, 0, stream>>>(ei, flag, src32, dst32);
  hipMemsetAsync(counts, 0, N_NODES * sizeof(int), stream);
  k_deg<<<12500, 256, 0, stream>>>(dst32, counts);
  k_dinv<<<NB, 256, 0, stream>>>(counts, dinv);
  k_scan1<<<NB, 256, 0, stream>>>(counts, bsum);
  k_scan2<<<1, 64, 0, stream>>>(bsum, offs);
  k_scan3<<<NB, 256, 0, stream>>>(counts, bsum, offs, cursor);
  k_fill<<<12500, 256, 0, stream>>>(src32, dst32, dinv, cursor, sedge);

  // ---- weight packing + x conversion ----
  k_packW<<<16, 256, 0, stream>>>(W0, wpk0, IN_CH);
  k_packW<<<8, 256, 0, stream>>>(W1, wpk1, HID);
  k_packW<<<8, 256, 0, stream>>>(W2, wpk2, HID);
  k_packW<<<16, 256, 0, stream>>>(Wr, wpkr, IN_CH);
  k_cvt<<<25000, 256, 0, stream>>>(x, xb16, N_NODES * IN_CH / 4);

  // ---- residual projection (f32 out), layer-0 GEMM (bf16 out) ----
  k_gemm<<<1563, 256, 0, stream>>>(xb16, IN_CH, wpkr, res, nullptr);
  k_gemm<<<1563, 256, 0, stream>>>(xb16, IN_CH, wpk0, nullptr, hWb);
  k_agg<<<25000, 256, 0, stream>>>(hWb, sedge, offs, dinv, b0, g0, be0, res, hbuf, hb16);

  // ---- layer 1 ----
  k_gemm<<<1563, 256, 0, stream>>>(hb16, HID, wpk1, nullptr, hWb);
  k_agg<<<25000, 256, 0, stream>>>(hWb, sedge, offs, dinv, b1, g1, be1, hbuf, hbuf, hb16);

  // ---- layer 2 (writes d_out) ----
  k_gemm<<<1563, 256, 0, stream>>>(hb16, HID, wpk2, nullptr, hWb);
  k_agg<<<25000, 256, 0, stream>>>(hWb, sedge, offs, dinv, b2, g2, be2, hbuf, out, nullptr);

  (void)in_sizes; (void)n_in; (void)out_size; (void)ws_size;
}

// Round 2
// 908.056 us; speedup vs baseline: 1.0362x; 1.0362x over previous
//
#include <hip/hip_runtime.h>
#include <hip/hip_bf16.h>
#include <stdint.h>

#define N_NODES 100000
#define N_EDGES 3200000
#define IN_CH 256
#define HID 128
#define EPS 1e-5f
#define NB 391  // ceil(100000/256)

using bf16x8 = __attribute__((ext_vector_type(8))) short;
using f32x4  = __attribute__((ext_vector_type(4))) float;

__device__ __forceinline__ uint16_t f2bf(float f) {
  uint32_t u = __float_as_uint(f);
  uint32_t r = (u + 0x7FFFu + ((u >> 16) & 1u)) >> 16;
  return (uint16_t)r;
}
__device__ __forceinline__ float bflo(uint32_t u) { return __uint_as_float(u << 16); }
__device__ __forceinline__ float bfhi(uint32_t u) { return __uint_as_float(u & 0xFFFF0000u); }

// ---- workspace layout (bytes), all 128-aligned ----
static const size_t OFF_SEDGE  = 0;           // int2[3.2M] = 25,600,000
static const size_t OFF_COUNTS = 25600000;    // int[100000]
static const size_t OFF_OFFS   = 26000128;    // int[100001]
static const size_t OFF_CURS   = 26400256;    // int[100000]
static const size_t OFF_DINV   = 26800384;    // float[100000]
static const size_t OFF_WPK0   = 27200512;    // 65,536
static const size_t OFF_WPK1   = 27266048;    // 32,768
static const size_t OFF_WPK2   = 27298816;    // 32,768
static const size_t OFF_WPKR   = 27331584;    // 65,536
static const size_t OFF_FLAG   = 27397120;    // int (+pad)
static const size_t OFF_SCL    = 27397504;    // float[100000]
static const size_t OFF_H8     = 27797504;    // u8[100000*128] = 12,800,000
static const size_t OFF_RESB   = 40597504;    // bf16[100000*128] = 25,600,000
static const size_t OFF_HBA    = 66197504;    // bf16[100000*128]
static const size_t OFF_HBB    = 91797504;    // bf16[100000*128]  (end ~117.4MB)

// ---- edge dtype detection: int64 edges have zero high words ----
__global__ void k_flag(const uint32_t* __restrict__ e, int* flag) {
  __shared__ int any;
  if (threadIdx.x == 0) any = 0;
  __syncthreads();
  uint32_t acc = 0;
  for (int i = threadIdx.x; i < 2048; i += blockDim.x) acc |= e[2 * i + 1];
  if (acc) atomicOr(&any, 1);
  __syncthreads();
  if (threadIdx.x == 0) *flag = (any == 0) ? 1 : 0;  // 1 => int64 layout
}

__global__ void k_deg(const void* __restrict__ eidx, const int* __restrict__ flag,
                      int* __restrict__ counts) {
  int e = blockIdx.x * blockDim.x + threadIdx.x;
  if (e >= N_EDGES) return;
  int d;
  if (*flag) d = (int)((const uint32_t*)eidx)[2 * ((size_t)N_EDGES + e)];
  else       d = ((const int*)eidx)[N_EDGES + e];
  atomicAdd(&counts[d], 1);
}

__global__ void k_dinv(const int* __restrict__ counts, float* __restrict__ dinv) {
  int v = blockIdx.x * blockDim.x + threadIdx.x;
  if (v < N_NODES) dinv[v] = rsqrtf((float)(counts[v] + 1));
}

__global__ void k_scan1(const int* __restrict__ counts, int* __restrict__ bsum) {
  __shared__ int sm[256];
  int i = blockIdx.x * 256 + threadIdx.x;
  sm[threadIdx.x] = (i < N_NODES) ? counts[i] : 0;
  __syncthreads();
  for (int s = 128; s > 0; s >>= 1) {
    if (threadIdx.x < s) sm[threadIdx.x] += sm[threadIdx.x + s];
    __syncthreads();
  }
  if (threadIdx.x == 0) bsum[blockIdx.x] = sm[0];
}

__global__ void k_scan2(int* __restrict__ bsum, int* __restrict__ offs) {
  if (threadIdx.x == 0 && blockIdx.x == 0) {
    int run = 0;
    for (int b = 0; b < NB; ++b) { int t = bsum[b]; bsum[b] = run; run += t; }
    offs[N_NODES] = run;
  }
}

__global__ void k_scan3(const int* __restrict__ counts, const int* __restrict__ bsum,
                        int* __restrict__ offs, int* __restrict__ cursor) {
  __shared__ int sm[256];
  int i = blockIdx.x * 256 + threadIdx.x;
  int vc = (i < N_NODES) ? counts[i] : 0;
  sm[threadIdx.x] = vc;
  __syncthreads();
  for (int s = 1; s < 256; s <<= 1) {
    int t = (threadIdx.x >= (unsigned)s) ? sm[threadIdx.x - s] : 0;
    __syncthreads();
    sm[threadIdx.x] += t;
    __syncthreads();
  }
  if (i < N_NODES) {
    int excl = sm[threadIdx.x] - vc + bsum[blockIdx.x];
    offs[i] = excl;
    cursor[i] = excl;
  }
}

__global__ void k_fill(const void* __restrict__ eidx, const int* __restrict__ flag,
                       const float* __restrict__ dinv, int* __restrict__ cursor,
                       int2* __restrict__ sedge) {
  int e = blockIdx.x * blockDim.x + threadIdx.x;
  if (e >= N_EDGES) return;
  int s, d;
  if (*flag) {
    const uint32_t* u = (const uint32_t*)eidx;
    s = (int)u[2 * (size_t)e];
    d = (int)u[2 * ((size_t)N_EDGES + e)];
  } else {
    const int* u = (const int*)eidx;
    s = u[e];
    d = u[N_EDGES + e];
  }
  float nrm = dinv[s] * dinv[d];
  int p = atomicAdd(&cursor[d], 1);
  sedge[p] = make_int2(s, __float_as_int(nrm));
}

// pack W [K][HID] f32 row-major into MFMA B-fragment-ready bf16 layout
__global__ void k_packW(const float* __restrict__ W, uint16_t* __restrict__ Wp, int K) {
  int t = blockIdx.x * blockDim.x + threadIdx.x;
  int total = (K / 32) * 8 * 64;
  if (t >= total) return;
  int l = t & 63;
  int nt = (t >> 6) & 7;
  int ks = t >> 9;
  int kbase = ks * 32 + (l >> 4) * 8;
  int col = nt * 16 + (l & 15);
  #pragma unroll
  for (int j = 0; j < 8; ++j)
    Wp[(size_t)t * 8 + j] = f2bf(W[(size_t)(kbase + j) * HID + col]);
}

// shared epilogue helper: quantize acc tiles to biased-uint8 rows + scale, via LDS repack
__device__ __forceinline__ void epilogue_int8(const f32x4* acc, int l, int row0,
                                              uint8_t* lds_my,  // [16*128] for this wave
                                              uint8_t* __restrict__ H8,
                                              float* __restrict__ scl) {
  float inv[4];
  #pragma unroll
  for (int j = 0; j < 4; ++j) {
    float m = 0.f;
    #pragma unroll
    for (int nt = 0; nt < 8; ++nt) m = fmaxf(m, fabsf(acc[nt][j]));
    #pragma unroll
    for (int s = 1; s < 16; s <<= 1) m = fmaxf(m, __shfl_xor(m, s, 64));
    m = fmaxf(m, 1e-20f);
    if ((l & 15) == 0) scl[row0 + (l >> 4) * 4 + j] = m * (1.f / 127.f);
    inv[j] = 127.f / m;
  }
  #pragma unroll
  for (int nt = 0; nt < 8; ++nt)
    #pragma unroll
    for (int j = 0; j < 4; ++j) {
      int r = (l >> 4) * 4 + j, c = nt * 16 + (l & 15);
      float q = rintf(acc[nt][j] * inv[j]) + 128.f;
      lds_my[r * 128 + c] = (uint8_t)(int)q;
    }
  asm volatile("s_waitcnt lgkmcnt(0)" ::: "memory");
  // copy out: lane l handles bytes [32l, 32l+32) = row l>>2, col (l&3)*32
  uint4 d0 = ((const uint4*)lds_my)[l * 2];
  uint4 d1 = ((const uint4*)lds_my)[l * 2 + 1];
  uint4* gp = (uint4*)(H8 + (size_t)(row0 + (l >> 2)) * 128 + (l & 3) * 32);
  gp[0] = d0;
  gp[1] = d1;
}

// layer-0 fused dual GEMM: reads f32 X[N][256], computes X@W0 -> int8+scale,
// X@Wr -> bf16 residual. One wave = 16 rows.
__global__ __launch_bounds__(256) void k_gemm0(const float* __restrict__ X,
                                               const uint16_t* __restrict__ Wp0,
                                               const uint16_t* __restrict__ WpR,
                                               uint8_t* __restrict__ H8,
                                               float* __restrict__ scl,
                                               uint16_t* __restrict__ resB) {
  __shared__ uint8_t lds8[4][16 * 128];
  __shared__ uint16_t ldsb[4][16 * 128];
  int wid = threadIdx.x >> 6, l = threadIdx.x & 63;
  int tile = blockIdx.x * 4 + wid;
  if (tile >= N_NODES / 16) return;
  int row0 = tile * 16;
  f32x4 acc0[8] = {}, accR[8] = {};
  int ar = row0 + (l & 15);
  int ak = (l >> 4) * 8;
  const bf16x8* B0 = (const bf16x8*)Wp0;
  const bf16x8* BR = (const bf16x8*)WpR;
  const float* arow = X + (size_t)ar * IN_CH + ak;
  for (int ks = 0; ks < 8; ++ks) {
    float4 v0 = *(const float4*)(arow + ks * 32);
    float4 v1 = *(const float4*)(arow + ks * 32 + 4);
    bf16x8 a;
    a[0] = (short)f2bf(v0.x); a[1] = (short)f2bf(v0.y);
    a[2] = (short)f2bf(v0.z); a[3] = (short)f2bf(v0.w);
    a[4] = (short)f2bf(v1.x); a[5] = (short)f2bf(v1.y);
    a[6] = (short)f2bf(v1.z); a[7] = (short)f2bf(v1.w);
    #pragma unroll
    for (int nt = 0; nt < 8; ++nt) {
      acc0[nt] = __builtin_amdgcn_mfma_f32_16x16x32_bf16(a, B0[(size_t)(ks * 8 + nt) * 64 + l], acc0[nt], 0, 0, 0);
      accR[nt] = __builtin_amdgcn_mfma_f32_16x16x32_bf16(a, BR[(size_t)(ks * 8 + nt) * 64 + l], accR[nt], 0, 0, 0);
    }
  }
  epilogue_int8(acc0, l, row0, lds8[wid], H8, scl);
  // residual -> bf16 via LDS repack
  uint16_t* myb = ldsb[wid];
  #pragma unroll
  for (int nt = 0; nt < 8; ++nt)
    #pragma unroll
    for (int j = 0; j < 4; ++j)
      myb[((l >> 4) * 4 + j) * 128 + nt * 16 + (l & 15)] = f2bf(accR[nt][j]);
  asm volatile("s_waitcnt lgkmcnt(0)" ::: "memory");
  const uint4* sb = (const uint4*)myb;  // 4KB = 256 x16B; lane takes 4
  uint4* gb = (uint4*)(resB + (size_t)(row0 + (l >> 2)) * 128 + (l & 3) * 32);
  #pragma unroll
  for (int t = 0; t < 4; ++t) gb[t] = sb[l * 4 + t];
}

// layers 1/2 GEMM: A bf16 [N][128] @ Wpack -> int8+scale
__global__ __launch_bounds__(256) void k_gemm8(const uint16_t* __restrict__ A,
                                               const uint16_t* __restrict__ Wp,
                                               uint8_t* __restrict__ H8,
                                               float* __restrict__ scl) {
  __shared__ uint8_t lds8[4][16 * 128];
  int wid = threadIdx.x >> 6, l = threadIdx.x & 63;
  int tile = blockIdx.x * 4 + wid;
  if (tile >= N_NODES / 16) return;
  int row0 = tile * 16;
  f32x4 acc[8] = {};
  int ar = row0 + (l & 15);
  int ak = (l >> 4) * 8;
  const bf16x8* Bp = (const bf16x8*)Wp;
  for (int ks = 0; ks < 4; ++ks) {
    bf16x8 a = *(const bf16x8*)(A + (size_t)ar * HID + ks * 32 + ak);
    #pragma unroll
    for (int nt = 0; nt < 8; ++nt)
      acc[nt] = __builtin_amdgcn_mfma_f32_16x16x32_bf16(a, Bp[(size_t)(ks * 8 + nt) * 64 + l], acc[nt], 0, 0, 0);
  }
  epilogue_int8(acc, l, row0, lds8[wid], H8, scl);
}

// fused: int8 gather-sum + bias + LN + ReLU + bf16 residual
// one wave per node, lane l owns channels 2l, 2l+1
__global__ __launch_bounds__(256) void k_agg(const uint8_t* __restrict__ H8,
                                             const float* __restrict__ scl,
                                             const int2* __restrict__ sedge,
                                             const int* __restrict__ offs,
                                             const float* __restrict__ dinv,
                                             const float* __restrict__ bias,
                                             const float* __restrict__ g,
                                             const float* __restrict__ be,
                                             const uint16_t* __restrict__ residB,
                                             float* __restrict__ outF,
                                             uint16_t* __restrict__ outB) {
  int wid = threadIdx.x >> 6, l = threadIdx.x & 63;
  int v = blockIdx.x * 4 + wid;
  if (v >= N_NODES) return;
  float a0 = 0.f, a1 = 0.f, c = 0.f;
  int p0 = offs[v], p1 = offs[v + 1];
  int p = p0;
  for (; p + 3 < p1; p += 4) {
    int2 e0 = sedge[p], e1 = sedge[p + 1], e2 = sedge[p + 2], e3 = sedge[p + 3];
    uint32_t h0 = *(const uint16_t*)(H8 + (size_t)e0.x * 128 + 2 * l);
    uint32_t h1 = *(const uint16_t*)(H8 + (size_t)e1.x * 128 + 2 * l);
    uint32_t h2 = *(const uint16_t*)(H8 + (size_t)e2.x * 128 + 2 * l);
    uint32_t h3 = *(const uint16_t*)(H8 + (size_t)e3.x * 128 + 2 * l);
    float ws0 = __int_as_float(e0.y) * scl[e0.x];
    float ws1 = __int_as_float(e1.y) * scl[e1.x];
    float ws2 = __int_as_float(e2.y) * scl[e2.x];
    float ws3 = __int_as_float(e3.y) * scl[e3.x];
    c += ws0 + ws1 + ws2 + ws3;
    a0 += ws0 * (float)(h0 & 0xFFu) + ws1 * (float)(h1 & 0xFFu) +
          ws2 * (float)(h2 & 0xFFu) + ws3 * (float)(h3 & 0xFFu);
    a1 += ws0 * (float)(h0 >> 8) + ws1 * (float)(h1 >> 8) +
          ws2 * (float)(h2 >> 8) + ws3 * (float)(h3 >> 8);
  }
  for (; p < p1; ++p) {
    int2 e = sedge[p];
    uint32_t h = *(const uint16_t*)(H8 + (size_t)e.x * 128 + 2 * l);
    float ws = __int_as_float(e.y) * scl[e.x];
    c += ws;
    a0 += ws * (float)(h & 0xFFu);
    a1 += ws * (float)(h >> 8);
  }
  {  // self loop
    float dv = dinv[v];
    uint32_t h = *(const uint16_t*)(H8 + (size_t)v * 128 + 2 * l);
    float ws = dv * dv * scl[v];
    c += ws;
    a0 += ws * (float)(h & 0xFFu);
    a1 += ws * (float)(h >> 8);
  }
  float2 bb = *(const float2*)(bias + 2 * l);
  a0 = a0 - 128.f * c + bb.x;
  a1 = a1 - 128.f * c + bb.y;
  // LayerNorm over 128 channels (wave reduction)
  float s = a0 + a1;
  #pragma unroll
  for (int m = 1; m < 64; m <<= 1) s += __shfl_xor(s, m, 64);
  float mu = s * (1.f / 128.f);
  float d0 = a0 - mu, d1 = a1 - mu;
  float q = d0 * d0 + d1 * d1;
  #pragma unroll
  for (int m = 1; m < 64; m <<= 1) q += __shfl_xor(q, m, 64);
  float rs = rsqrtf(q * (1.f / 128.f) + EPS);
  float2 gg = *(const float2*)(g + 2 * l);
  float2 ee = *(const float2*)(be + 2 * l);
  float y0 = fmaxf(d0 * rs * gg.x + ee.x, 0.f);
  float y1 = fmaxf(d1 * rs * gg.y + ee.y, 0.f);
  uint32_t rr = ((const uint32_t*)residB)[(size_t)v * 64 + l];
  y0 += bflo(rr);
  y1 += bfhi(rr);
  if (outF) ((float2*)(outF + (size_t)v * HID))[l] = make_float2(y0, y1);
  if (outB) {
    uint32_t o = (uint32_t)f2bf(y0) | ((uint32_t)f2bf(y1) << 16);
    ((uint32_t*)outB)[(size_t)v * 64 + l] = o;
  }
}

extern "C" void kernel_launch(void* const* d_in, const int* in_sizes, int n_in,
                              void* d_out, int out_size, void* d_ws, size_t ws_size,
                              hipStream_t stream) {
  const float* x   = (const float*)d_in[0];
  const void*  ei  = d_in[1];
  const float* W0  = (const float*)d_in[2];
  const float* b0  = (const float*)d_in[3];
  const float* g0  = (const float*)d_in[4];
  const float* be0 = (const float*)d_in[5];
  const float* W1  = (const float*)d_in[6];
  const float* b1  = (const float*)d_in[7];
  const float* g1  = (const float*)d_in[8];
  const float* be1 = (const float*)d_in[9];
  const float* W2  = (const float*)d_in[10];
  const float* b2  = (const float*)d_in[11];
  const float* g2  = (const float*)d_in[12];
  const float* be2 = (const float*)d_in[13];
  const float* Wr  = (const float*)d_in[14];

  char* ws = (char*)d_ws;
  int2*     sedge  = (int2*)(ws + OFF_SEDGE);
  int*      counts = (int*)(ws + OFF_COUNTS);
  int*      offs   = (int*)(ws + OFF_OFFS);
  int*      cursor = (int*)(ws + OFF_CURS);
  float*    dinv   = (float*)(ws + OFF_DINV);
  uint16_t* wpk0   = (uint16_t*)(ws + OFF_WPK0);
  uint16_t* wpk1   = (uint16_t*)(ws + OFF_WPK1);
  uint16_t* wpk2   = (uint16_t*)(ws + OFF_WPK2);
  uint16_t* wpkr   = (uint16_t*)(ws + OFF_WPKR);
  int*      flag   = (int*)(ws + OFF_FLAG);
  int*      bsum   = (int*)(ws + OFF_FLAG + 128);  // reuse pad region? no -- need 391 ints
  float*    scl    = (float*)(ws + OFF_SCL);
  uint8_t*  h8     = (uint8_t*)(ws + OFF_H8);
  uint16_t* resB   = (uint16_t*)(ws + OFF_RESB);
  uint16_t* hbA    = (uint16_t*)(ws + OFF_HBA);
  uint16_t* hbB    = (uint16_t*)(ws + OFF_HBB);
  float*    out    = (float*)d_out;
  // bsum needs 391 ints: put it after HBB (plenty of ws)
  bsum = (int*)(ws + OFF_HBB + 25600000);

  // ---- edge preprocessing ----
  k_flag<<<1, 256, 0, stream>>>((const uint32_t*)ei, flag);
  hipMemsetAsync(counts, 0, N_NODES * sizeof(int), stream);
  k_deg<<<12500, 256, 0, stream>>>(ei, flag, counts);
  k_dinv<<<NB, 256, 0, stream>>>(counts, dinv);
  k_scan1<<<NB, 256, 0, stream>>>(counts, bsum);
  k_scan2<<<1, 64, 0, stream>>>(bsum, offs);
  k_scan3<<<NB, 256, 0, stream>>>(counts, bsum, offs, cursor);
  k_fill<<<12500, 256, 0, stream>>>(ei, flag, dinv, cursor, sedge);

  // ---- weight packing ----
  k_packW<<<16, 256, 0, stream>>>(W0, wpk0, IN_CH);
  k_packW<<<8, 256, 0, stream>>>(W1, wpk1, HID);
  k_packW<<<8, 256, 0, stream>>>(W2, wpk2, HID);
  k_packW<<<16, 256, 0, stream>>>(Wr, wpkr, IN_CH);

  // ---- layer 0: fused dual GEMM (x@W0 -> int8, x@Wr -> bf16 residual) ----
  k_gemm0<<<1563, 256, 0, stream>>>(x, wpk0, wpkr, h8, scl, resB);
  k_agg<<<25000, 256, 0, stream>>>(h8, scl, sedge, offs, dinv, b0, g0, be0, resB, nullptr, hbA);

  // ---- layer 1 ----
  k_gemm8<<<1563, 256, 0, stream>>>(hbA, wpk1, h8, scl);
  k_agg<<<25000, 256, 0, stream>>>(h8, scl, sedge, offs, dinv, b1, g1, be1, hbA, nullptr, hbB);

  // ---- layer 2 (writes d_out f32) ----
  k_gemm8<<<1563, 256, 0, stream>>>(hbB, wpk2, h8, scl);
  k_agg<<<25000, 256, 0, stream>>>(h8, scl, sedge, offs, dinv, b2, g2, be2, hbB, out, nullptr);

  (void)in_sizes; (void)n_in; (void)out_size; (void)ws_size;
}

// Round 3
// 662.293 us; speedup vs baseline: 1.4207x; 1.3711x over previous
//
#include <hip/hip_runtime.h>
#include <hip/hip_bf16.h>
#include <stdint.h>

#define N_NODES 100000
#define N_EDGES 3200000
#define IN_CH 256
#define HID 128
#define EPS 1e-5f
#define BSH 9              // bucket = dst >> 9  (512 nodes per bucket)
#define NBUK 196           // ceil(100000/512)
#define PCHUNK 4096

using bf16x8 = __attribute__((ext_vector_type(8))) short;
using f32x4  = __attribute__((ext_vector_type(4))) float;

__device__ __forceinline__ uint16_t f2bf(float f) {
  uint32_t u = __float_as_uint(f);
  uint32_t r = (u + 0x7FFFu + ((u >> 16) & 1u)) >> 16;
  return (uint16_t)r;
}
__device__ __forceinline__ float bflo(uint32_t u) { return __uint_as_float(u << 16); }
__device__ __forceinline__ float bfhi(uint32_t u) { return __uint_as_float(u & 0xFFFF0000u); }

// ---- workspace layout (bytes), all 128-aligned ----
static const size_t OFF_SRC   = 0;            // int[3.2M] = 12,800,000 (CSR src)
static const size_t OFF_OFFS  = 12800000;     // int[100001]
static const size_t OFF_DINV  = 13200128;     // float[100000]
static const size_t OFF_DSC   = 13600128;     // float[100000]
static const size_t OFF_WPK0  = 14000128;     // 65,536
static const size_t OFF_WPK1  = 14065664;     // 32,768
static const size_t OFF_WPK2  = 14098432;     // 32,768
static const size_t OFF_WPKR  = 14131200;     // 65,536
static const size_t OFF_FLAG  = 14196736;     // int (+pad)
static const size_t OFF_BCNT  = 14196864;     // int[NBUK]
static const size_t OFF_BBASE = 14197888;     // int[NBUK+1]
static const size_t OFF_BCUR  = 14198912;     // int[NBUK]
static const size_t OFF_H8    = 14200064;     // u8[100000*128] = 12,800,000
static const size_t OFF_PART  = 14200064;     // int2[3.2M] = 25.6MB (aliases H8+resB head; dead before GEMM)
static const size_t OFF_RESB  = 27000064;     // bf16[100000*128] = 25,600,000
static const size_t OFF_HBA   = 52600064;     // bf16[100000*128]
static const size_t OFF_HBB   = 78200064;     // bf16[100000*128]  (end ~103.8MB)

// ---- edge dtype detection: int64 edges have zero high words ----
__global__ void k_flag(const uint32_t* __restrict__ e, int* flag) {
  __shared__ int any;
  if (threadIdx.x == 0) any = 0;
  __syncthreads();
  uint32_t acc = 0;
  for (int i = threadIdx.x; i < 2048; i += blockDim.x) acc |= e[2 * i + 1];
  if (acc) atomicOr(&any, 1);
  __syncthreads();
  if (threadIdx.x == 0) *flag = (any == 0) ? 1 : 0;  // 1 => int64 layout
}

// ---- bucket histogram (LDS-aggregated) ----
__global__ __launch_bounds__(256) void k_hist(const void* __restrict__ eidx,
                                              const int* __restrict__ flag,
                                              int* __restrict__ bcnt) {
  __shared__ int h[NBUK];
  for (int t = threadIdx.x; t < NBUK; t += 256) h[t] = 0;
  __syncthreads();
  bool i64 = (*flag != 0);
  int stride = gridDim.x * blockDim.x;
  for (int e = blockIdx.x * blockDim.x + threadIdx.x; e < N_EDGES; e += stride) {
    int d = i64 ? (int)((const uint32_t*)eidx)[2 * ((size_t)N_EDGES + e)]
                : ((const int*)eidx)[N_EDGES + e];
    atomicAdd(&h[d >> BSH], 1);
  }
  __syncthreads();
  for (int t = threadIdx.x; t < NBUK; t += 256)
    if (h[t]) atomicAdd(&bcnt[t], h[t]);
}

// ---- serial bucket scan (196 elems) ----
__global__ void k_bscan(const int* __restrict__ bcnt, int* __restrict__ bbase,
                        int* __restrict__ bcur, int* __restrict__ offs) {
  if (threadIdx.x == 0 && blockIdx.x == 0) {
    int run = 0;
    for (int b = 0; b < NBUK; ++b) {
      bbase[b] = run;
      bcur[b] = run;
      run += bcnt[b];
    }
    bbase[NBUK] = run;
    offs[N_NODES] = run;
  }
}

// ---- LDS-staged partition into buckets (coalesced writes) ----
__global__ __launch_bounds__(256) void k_part(const void* __restrict__ eidx,
                                              const int* __restrict__ flag,
                                              int* __restrict__ bcur,
                                              int2* __restrict__ part) {
  __shared__ int lhist[NBUK];
  __shared__ int lbase[NBUK];
  __shared__ int gbase[NBUK];
  __shared__ int sm[256];
  __shared__ int2 sbuf[PCHUNK];
  __shared__ uint8_t bbuf[PCHUNK];
  int tid = threadIdx.x;
  int base = blockIdx.x * PCHUNK;
  int nE = N_EDGES - base;
  if (nE > PCHUNK) nE = PCHUNK;
  for (int t = tid; t < NBUK; t += 256) lhist[t] = 0;
  __syncthreads();
  bool i64 = (*flag != 0);
  int es[16], ed[16], ml[16];
  #pragma unroll
  for (int k = 0; k < 16; ++k) {
    int ci = k * 256 + tid;
    if (ci < nE) {
      int e = base + ci;
      int s, d;
      if (i64) {
        const uint32_t* u = (const uint32_t*)eidx;
        s = (int)u[2 * (size_t)e];
        d = (int)u[2 * ((size_t)N_EDGES + e)];
      } else {
        const int* u = (const int*)eidx;
        s = u[e];
        d = u[N_EDGES + e];
      }
      es[k] = s; ed[k] = d;
      ml[k] = atomicAdd(&lhist[d >> BSH], 1);
    }
  }
  __syncthreads();
  // exclusive scan of lhist -> lbase
  sm[tid] = (tid < NBUK) ? lhist[tid] : 0;
  __syncthreads();
  for (int s = 1; s < 256; s <<= 1) {
    int t = (tid >= s) ? sm[tid - s] : 0;
    __syncthreads();
    sm[tid] += t;
    __syncthreads();
  }
  if (tid < NBUK) lbase[tid] = sm[tid] - lhist[tid];
  __syncthreads();
  #pragma unroll
  for (int k = 0; k < 16; ++k) {
    int ci = k * 256 + tid;
    if (ci < nE) {
      int b = ed[k] >> BSH;
      int slot = lbase[b] + ml[k];
      sbuf[slot] = make_int2(es[k], ed[k]);
      bbuf[slot] = (uint8_t)b;
    }
  }
  if (tid < NBUK && lhist[tid] > 0) gbase[tid] = atomicAdd(&bcur[tid], lhist[tid]);
  __syncthreads();
  for (int i = tid; i < nE; i += 256) {
    int b = bbuf[i];
    part[(size_t)gbase[b] + (i - lbase[b])] = sbuf[i];
  }
}

// ---- per-bucket: count -> offs/dinv -> scatter src into L2-local CSR window ----
__global__ __launch_bounds__(256) void k_bucket(const int2* __restrict__ part,
                                                const int* __restrict__ bbase,
                                                int* __restrict__ offs,
                                                float* __restrict__ dinv,
                                                int* __restrict__ sedge) {
  __shared__ int cnt[512];
  __shared__ int pre[512];
  __shared__ int s2[256];
  int tid = threadIdx.x, b = blockIdx.x;
  int v0 = b << BSH;
  int e0 = bbase[b], e1 = bbase[b + 1];
  cnt[tid] = 0; cnt[tid + 256] = 0;
  __syncthreads();
  #pragma unroll 4
  for (int i = e0 + tid; i < e1; i += 256) atomicAdd(&cnt[part[i].y - v0], 1);
  __syncthreads();
  // exclusive scan of 512 counts
  int pa = cnt[2 * tid], pb = cnt[2 * tid + 1];
  s2[tid] = pa + pb;
  __syncthreads();
  for (int s = 1; s < 256; s <<= 1) {
    int t = (tid >= s) ? s2[tid - s] : 0;
    __syncthreads();
    s2[tid] += t;
    __syncthreads();
  }
  int eb = s2[tid] - (pa + pb);
  pre[2 * tid] = eb;
  pre[2 * tid + 1] = eb + pa;
  __syncthreads();
  #pragma unroll
  for (int k = 0; k < 2; ++k) {
    int t = tid + k * 256, v = v0 + t;
    if (v < N_NODES) {
      offs[v] = e0 + pre[t];
      dinv[v] = rsqrtf((float)(cnt[t] + 1));
    }
  }
  __syncthreads();
  cnt[tid] = pre[tid];
  cnt[tid + 256] = pre[tid + 256];
  __syncthreads();
  #pragma unroll 4
  for (int i = e0 + tid; i < e1; i += 256) {
    int2 e = part[i];
    int loc = atomicAdd(&cnt[e.y - v0], 1);
    sedge[e0 + loc] = e.x;
  }
}

// pack W [K][HID] f32 row-major into MFMA B-fragment-ready bf16 layout
__global__ void k_packW(const float* __restrict__ W, uint16_t* __restrict__ Wp, int K) {
  int t = blockIdx.x * blockDim.x + threadIdx.x;
  int total = (K / 32) * 8 * 64;
  if (t >= total) return;
  int l = t & 63;
  int nt = (t >> 6) & 7;
  int ks = t >> 9;
  int kbase = ks * 32 + (l >> 4) * 8;
  int col = nt * 16 + (l & 15);
  #pragma unroll
  for (int j = 0; j < 8; ++j)
    Wp[(size_t)t * 8 + j] = f2bf(W[(size_t)(kbase + j) * HID + col]);
}

// epilogue: quantize acc tiles to biased-uint8 rows + dsc (= scale * dinv), via LDS repack
__device__ __forceinline__ void epilogue_int8(const f32x4* acc, int l, int row0,
                                              uint8_t* lds_my,
                                              uint8_t* __restrict__ H8,
                                              float* __restrict__ dsc,
                                              const float* __restrict__ dinv) {
  float inv[4];
  #pragma unroll
  for (int j = 0; j < 4; ++j) {
    float m = 0.f;
    #pragma unroll
    for (int nt = 0; nt < 8; ++nt) m = fmaxf(m, fabsf(acc[nt][j]));
    #pragma unroll
    for (int s = 1; s < 16; s <<= 1) m = fmaxf(m, __shfl_xor(m, s, 64));
    m = fmaxf(m, 1e-20f);
    if ((l & 15) == 0) {
      int r = row0 + (l >> 4) * 4 + j;
      dsc[r] = m * (1.f / 127.f) * dinv[r];
    }
    inv[j] = 127.f / m;
  }
  #pragma unroll
  for (int nt = 0; nt < 8; ++nt)
    #pragma unroll
    for (int j = 0; j < 4; ++j) {
      int r = (l >> 4) * 4 + j, c = nt * 16 + (l & 15);
      float q = rintf(acc[nt][j] * inv[j]) + 128.f;
      lds_my[r * 128 + c] = (uint8_t)(int)q;
    }
  asm volatile("s_waitcnt lgkmcnt(0)" ::: "memory");
  uint4 d0 = ((const uint4*)lds_my)[l * 2];
  uint4 d1 = ((const uint4*)lds_my)[l * 2 + 1];
  uint4* gp = (uint4*)(H8 + (size_t)(row0 + (l >> 2)) * 128 + (l & 3) * 32);
  gp[0] = d0;
  gp[1] = d1;
}

// layer-0 fused dual GEMM: X f32 [N][256]: X@W0 -> int8+dsc, X@Wr -> bf16 residual
__global__ __launch_bounds__(256) void k_gemm0(const float* __restrict__ X,
                                               const uint16_t* __restrict__ Wp0,
                                               const uint16_t* __restrict__ WpR,
                                               uint8_t* __restrict__ H8,
                                               float* __restrict__ dsc,
                                               const float* __restrict__ dinv,
                                               uint16_t* __restrict__ resB) {
  __shared__ uint8_t lds8[4][16 * 128];
  __shared__ uint16_t ldsb[4][16 * 128];
  int wid = threadIdx.x >> 6, l = threadIdx.x & 63;
  int tile = blockIdx.x * 4 + wid;
  if (tile >= N_NODES / 16) return;
  int row0 = tile * 16;
  f32x4 acc0[8] = {}, accR[8] = {};
  int ar = row0 + (l & 15);
  int ak = (l >> 4) * 8;
  const bf16x8* B0 = (const bf16x8*)Wp0;
  const bf16x8* BR = (const bf16x8*)WpR;
  const float* arow = X + (size_t)ar * IN_CH + ak;
  for (int ks = 0; ks < 8; ++ks) {
    float4 v0 = *(const float4*)(arow + ks * 32);
    float4 v1 = *(const float4*)(arow + ks * 32 + 4);
    bf16x8 a;
    a[0] = (short)f2bf(v0.x); a[1] = (short)f2bf(v0.y);
    a[2] = (short)f2bf(v0.z); a[3] = (short)f2bf(v0.w);
    a[4] = (short)f2bf(v1.x); a[5] = (short)f2bf(v1.y);
    a[6] = (short)f2bf(v1.z); a[7] = (short)f2bf(v1.w);
    #pragma unroll
    for (int nt = 0; nt < 8; ++nt) {
      acc0[nt] = __builtin_amdgcn_mfma_f32_16x16x32_bf16(a, B0[(size_t)(ks * 8 + nt) * 64 + l], acc0[nt], 0, 0, 0);
      accR[nt] = __builtin_amdgcn_mfma_f32_16x16x32_bf16(a, BR[(size_t)(ks * 8 + nt) * 64 + l], accR[nt], 0, 0, 0);
    }
  }
  epilogue_int8(acc0, l, row0, lds8[wid], H8, dsc, dinv);
  uint16_t* myb = ldsb[wid];
  #pragma unroll
  for (int nt = 0; nt < 8; ++nt)
    #pragma unroll
    for (int j = 0; j < 4; ++j)
      myb[((l >> 4) * 4 + j) * 128 + nt * 16 + (l & 15)] = f2bf(accR[nt][j]);
  asm volatile("s_waitcnt lgkmcnt(0)" ::: "memory");
  const uint4* sb = (const uint4*)myb;
  uint4* gb = (uint4*)(resB + (size_t)(row0 + (l >> 2)) * 128 + (l & 3) * 32);
  #pragma unroll
  for (int t = 0; t < 4; ++t) gb[t] = sb[l * 4 + t];
}

// layers 1/2 GEMM: A bf16 [N][128] @ Wpack -> int8+dsc
__global__ __launch_bounds__(256) void k_gemm8(const uint16_t* __restrict__ A,
                                               const uint16_t* __restrict__ Wp,
                                               uint8_t* __restrict__ H8,
                                               float* __restrict__ dsc,
                                               const float* __restrict__ dinv) {
  __shared__ uint8_t lds8[4][16 * 128];
  int wid = threadIdx.x >> 6, l = threadIdx.x & 63;
  int tile = blockIdx.x * 4 + wid;
  if (tile >= N_NODES / 16) return;
  int row0 = tile * 16;
  f32x4 acc[8] = {};
  int ar = row0 + (l & 15);
  int ak = (l >> 4) * 8;
  const bf16x8* Bp = (const bf16x8*)Wp;
  for (int ks = 0; ks < 4; ++ks) {
    bf16x8 a = *(const bf16x8*)(A + (size_t)ar * HID + ks * 32 + ak);
    #pragma unroll
    for (int nt = 0; nt < 8; ++nt)
      acc[nt] = __builtin_amdgcn_mfma_f32_16x16x32_bf16(a, Bp[(size_t)(ks * 8 + nt) * 64 + l], acc[nt], 0, 0, 0);
  }
  epilogue_int8(acc, l, row0, lds8[wid], H8, dsc, dinv);
}

// fused: int8 gather-sum + bias + LN + ReLU + bf16 residual; lane l owns ch 2l,2l+1
__global__ __launch_bounds__(256) void k_agg(const uint8_t* __restrict__ H8,
                                             const float* __restrict__ dsc,
                                             const int* __restrict__ sedge,
                                             const int* __restrict__ offs,
                                             const float* __restrict__ dinv,
                                             const float* __restrict__ bias,
                                             const float* __restrict__ g,
                                             const float* __restrict__ be,
                                             const uint16_t* __restrict__ residB,
                                             float* __restrict__ outF,
                                             uint16_t* __restrict__ outB) {
  int wid = threadIdx.x >> 6, l = threadIdx.x & 63;
  int v = blockIdx.x * 4 + wid;
  if (v >= N_NODES) return;
  float a0 = 0.f, a1 = 0.f, c = 0.f;
  int p = offs[v], p1 = offs[v + 1];
  for (; p + 3 < p1; p += 4) {
    int s0 = sedge[p], s1 = sedge[p + 1], s2 = sedge[p + 2], s3 = sedge[p + 3];
    uint32_t h0 = *(const uint16_t*)(H8 + (size_t)s0 * 128 + 2 * l);
    uint32_t h1 = *(const uint16_t*)(H8 + (size_t)s1 * 128 + 2 * l);
    uint32_t h2 = *(const uint16_t*)(H8 + (size_t)s2 * 128 + 2 * l);
    uint32_t h3 = *(const uint16_t*)(H8 + (size_t)s3 * 128 + 2 * l);
    float ws0 = dsc[s0], ws1 = dsc[s1], ws2 = dsc[s2], ws3 = dsc[s3];
    c += ws0 + ws1 + ws2 + ws3;
    a0 += ws0 * (float)(h0 & 0xFFu) + ws1 * (float)(h1 & 0xFFu) +
          ws2 * (float)(h2 & 0xFFu) + ws3 * (float)(h3 & 0xFFu);
    a1 += ws0 * (float)(h0 >> 8) + ws1 * (float)(h1 >> 8) +
          ws2 * (float)(h2 >> 8) + ws3 * (float)(h3 >> 8);
  }
  for (; p < p1; ++p) {
    int s0 = sedge[p];
    uint32_t h = *(const uint16_t*)(H8 + (size_t)s0 * 128 + 2 * l);
    float ws = dsc[s0];
    c += ws;
    a0 += ws * (float)(h & 0xFFu);
    a1 += ws * (float)(h >> 8);
  }
  float dv = dinv[v];
  a0 = dv * (a0 - 128.f * c);
  a1 = dv * (a1 - 128.f * c);
  {  // self loop: weight dinv[v]^2 * scl[v] = dv * dsc[v]
    uint32_t h = *(const uint16_t*)(H8 + (size_t)v * 128 + 2 * l);
    float wss = dv * dsc[v];
    a0 += wss * ((float)(h & 0xFFu) - 128.f);
    a1 += wss * ((float)(h >> 8) - 128.f);
  }
  float2 bb = *(const float2*)(bias + 2 * l);
  a0 += bb.x;
  a1 += bb.y;
  float s = a0 + a1;
  #pragma unroll
  for (int m = 1; m < 64; m <<= 1) s += __shfl_xor(s, m, 64);
  float mu = s * (1.f / 128.f);
  float d0 = a0 - mu, d1 = a1 - mu;
  float q = d0 * d0 + d1 * d1;
  #pragma unroll
  for (int m = 1; m < 64; m <<= 1) q += __shfl_xor(q, m, 64);
  float rs = rsqrtf(q * (1.f / 128.f) + EPS);
  float2 gg = *(const float2*)(g + 2 * l);
  float2 ee = *(const float2*)(be + 2 * l);
  float y0 = fmaxf(d0 * rs * gg.x + ee.x, 0.f);
  float y1 = fmaxf(d1 * rs * gg.y + ee.y, 0.f);
  uint32_t rr = ((const uint32_t*)residB)[(size_t)v * 64 + l];
  y0 += bflo(rr);
  y1 += bfhi(rr);
  if (outF) ((float2*)(outF + (size_t)v * HID))[l] = make_float2(y0, y1);
  if (outB) {
    uint32_t o = (uint32_t)f2bf(y0) | ((uint32_t)f2bf(y1) << 16);
    ((uint32_t*)outB)[(size_t)v * 64 + l] = o;
  }
}

extern "C" void kernel_launch(void* const* d_in, const int* in_sizes, int n_in,
                              void* d_out, int out_size, void* d_ws, size_t ws_size,
                              hipStream_t stream) {
  const float* x   = (const float*)d_in[0];
  const void*  ei  = d_in[1];
  const float* W0  = (const float*)d_in[2];
  const float* b0  = (const float*)d_in[3];
  const float* g0  = (const float*)d_in[4];
  const float* be0 = (const float*)d_in[5];
  const float* W1  = (const float*)d_in[6];
  const float* b1  = (const float*)d_in[7];
  const float* g1  = (const float*)d_in[8];
  const float* be1 = (const float*)d_in[9];
  const float* W2  = (const float*)d_in[10];
  const float* b2  = (const float*)d_in[11];
  const float* g2  = (const float*)d_in[12];
  const float* be2 = (const float*)d_in[13];
  const float* Wr  = (const float*)d_in[14];

  char* ws = (char*)d_ws;
  int*      sedge  = (int*)(ws + OFF_SRC);
  int*      offs   = (int*)(ws + OFF_OFFS);
  float*    dinv   = (float*)(ws + OFF_DINV);
  float*    dsc    = (float*)(ws + OFF_DSC);
  uint16_t* wpk0   = (uint16_t*)(ws + OFF_WPK0);
  uint16_t* wpk1   = (uint16_t*)(ws + OFF_WPK1);
  uint16_t* wpk2   = (uint16_t*)(ws + OFF_WPK2);
  uint16_t* wpkr   = (uint16_t*)(ws + OFF_WPKR);
  int*      flag   = (int*)(ws + OFF_FLAG);
  int*      bcnt   = (int*)(ws + OFF_BCNT);
  int*      bbase  = (int*)(ws + OFF_BBASE);
  int*      bcur   = (int*)(ws + OFF_BCUR);
  uint8_t*  h8     = (uint8_t*)(ws + OFF_H8);
  int2*     part   = (int2*)(ws + OFF_PART);
  uint16_t* resB   = (uint16_t*)(ws + OFF_RESB);
  uint16_t* hbA    = (uint16_t*)(ws + OFF_HBA);
  uint16_t* hbB    = (uint16_t*)(ws + OFF_HBB);
  float*    out    = (float*)d_out;

  // ---- edge preprocessing: hist -> scan -> partition -> per-bucket CSR ----
  k_flag<<<1, 256, 0, stream>>>((const uint32_t*)ei, flag);
  hipMemsetAsync(bcnt, 0, NBUK * sizeof(int), stream);
  k_hist<<<2048, 256, 0, stream>>>(ei, flag, bcnt);
  k_bscan<<<1, 64, 0, stream>>>(bcnt, bbase, bcur, offs);
  k_part<<<(N_EDGES + PCHUNK - 1) / PCHUNK, 256, 0, stream>>>(ei, flag, bcur, part);
  k_bucket<<<NBUK, 256, 0, stream>>>(part, bbase, offs, dinv, sedge);

  // ---- weight packing ----
  k_packW<<<16, 256, 0, stream>>>(W0, wpk0, IN_CH);
  k_packW<<<8, 256, 0, stream>>>(W1, wpk1, HID);
  k_packW<<<8, 256, 0, stream>>>(W2, wpk2, HID);
  k_packW<<<16, 256, 0, stream>>>(Wr, wpkr, IN_CH);

  // ---- layer 0: fused dual GEMM (x@W0 -> int8, x@Wr -> bf16 residual) ----
  k_gemm0<<<1563, 256, 0, stream>>>(x, wpk0, wpkr, h8, dsc, dinv, resB);
  k_agg<<<25000, 256, 0, stream>>>(h8, dsc, sedge, offs, dinv, b0, g0, be0, resB, nullptr, hbA);

  // ---- layer 1 ----
  k_gemm8<<<1563, 256, 0, stream>>>(hbA, wpk1, h8, dsc, dinv);
  k_agg<<<25000, 256, 0, stream>>>(h8, dsc, sedge, offs, dinv, b1, g1, be1, hbA, nullptr, hbB);

  // ---- layer 2 (writes d_out f32) ----
  k_gemm8<<<1563, 256, 0, stream>>>(hbB, wpk2, h8, dsc, dinv);
  k_agg<<<25000, 256, 0, stream>>>(h8, dsc, sedge, offs, dinv, b2, g2, be2, hbB, out, nullptr);

  (void)in_sizes; (void)n_in; (void)out_size; (void)ws_size;
}

// Round 4
// 617.308 us; speedup vs baseline: 1.5243x; 1.0729x over previous
//
#include <hip/hip_runtime.h>
#include <hip/hip_bf16.h>
#include <stdint.h>

#define N_NODES 100000
#define N_EDGES 3200000
#define IN_CH 256
#define HID 128
#define EPS 1e-5f
#define BSH 9              // bucket = dst >> 9  (512 nodes per bucket)
#define NBUK 196           // ceil(100000/512)
#define PCHUNK 4096

using bf16x8 = __attribute__((ext_vector_type(8))) short;
using f32x4  = __attribute__((ext_vector_type(4))) float;

__device__ __forceinline__ uint32_t f2bf(float f) {
  uint32_t u = __float_as_uint(f);
  return (u + 0x7FFFu + ((u >> 16) & 1u)) >> 16;
}
__device__ __forceinline__ float bflo(uint32_t u) { return __uint_as_float(u << 16); }
__device__ __forceinline__ float bfhi(uint32_t u) { return __uint_as_float(u & 0xFFFF0000u); }

// ---- workspace layout (bytes), all 128-aligned ----
static const size_t OFF_SRC   = 0;            // int[3.2M] = 12,800,000 (CSR src)
static const size_t OFF_OFFS  = 12800000;     // int[100001]
static const size_t OFF_DINV  = 13200128;     // float[100000]
static const size_t OFF_DSC   = 13600128;     // float[100000]
static const size_t OFF_WPK0  = 14000128;     // 65,536
static const size_t OFF_WPK1  = 14065664;     // 32,768
static const size_t OFF_WPK2  = 14098432;     // 32,768
static const size_t OFF_WPKR  = 14131200;     // 65,536
static const size_t OFF_FLAG  = 14196736;     // int (+pad)
static const size_t OFF_BCNT  = 14196864;     // int[NBUK]
static const size_t OFF_BBASE = 14197888;     // int[NBUK+1]
static const size_t OFF_BCUR  = 14198912;     // int[NBUK]
static const size_t OFF_H8    = 14200064;     // u8[100000*128] = 12,800,000
static const size_t OFF_PART  = 14200064;     // int2[3.2M] = 25.6MB (aliases H8+resB head; dead before GEMM)
static const size_t OFF_RESB  = 27000064;     // bf16[100000*128] = 25,600,000
static const size_t OFF_HBA   = 52600064;     // bf16[100000*128]
static const size_t OFF_HBB   = 78200064;     // bf16[100000*128]  (end ~103.8MB)

// ---- edge dtype detection: int64 edges have zero high words ----
__global__ void k_flag(const uint32_t* __restrict__ e, int* flag) {
  __shared__ int any;
  if (threadIdx.x == 0) any = 0;
  __syncthreads();
  uint32_t acc = 0;
  for (int i = threadIdx.x; i < 2048; i += blockDim.x) acc |= e[2 * i + 1];
  if (acc) atomicOr(&any, 1);
  __syncthreads();
  if (threadIdx.x == 0) *flag = (any == 0) ? 1 : 0;  // 1 => int64 layout
}

// ---- bucket histogram (LDS-aggregated) ----
__global__ __launch_bounds__(256) void k_hist(const void* __restrict__ eidx,
                                              const int* __restrict__ flag,
                                              int* __restrict__ bcnt) {
  __shared__ int h[NBUK];
  for (int t = threadIdx.x; t < NBUK; t += 256) h[t] = 0;
  __syncthreads();
  bool i64 = (*flag != 0);
  int stride = gridDim.x * blockDim.x;
  for (int e = blockIdx.x * blockDim.x + threadIdx.x; e < N_EDGES; e += stride) {
    int d = i64 ? (int)((const uint32_t*)eidx)[2 * ((size_t)N_EDGES + e)]
                : ((const int*)eidx)[N_EDGES + e];
    atomicAdd(&h[d >> BSH], 1);
  }
  __syncthreads();
  for (int t = threadIdx.x; t < NBUK; t += 256)
    if (h[t]) atomicAdd(&bcnt[t], h[t]);
}

// ---- serial bucket scan (196 elems) ----
__global__ void k_bscan(const int* __restrict__ bcnt, int* __restrict__ bbase,
                        int* __restrict__ bcur, int* __restrict__ offs) {
  if (threadIdx.x == 0 && blockIdx.x == 0) {
    int run = 0;
    for (int b = 0; b < NBUK; ++b) {
      bbase[b] = run;
      bcur[b] = run;
      run += bcnt[b];
    }
    bbase[NBUK] = run;
    offs[N_NODES] = run;
  }
}

// ---- LDS-staged partition into buckets (coalesced writes) ----
__global__ __launch_bounds__(256) void k_part(const void* __restrict__ eidx,
                                              const int* __restrict__ flag,
                                              int* __restrict__ bcur,
                                              int2* __restrict__ part) {
  __shared__ int lhist[NBUK];
  __shared__ int lbase[NBUK];
  __shared__ int gbase[NBUK];
  __shared__ int sm[256];
  __shared__ int2 sbuf[PCHUNK];
  __shared__ uint8_t bbuf[PCHUNK];
  int tid = threadIdx.x;
  int base = blockIdx.x * PCHUNK;
  int nE = N_EDGES - base;
  if (nE > PCHUNK) nE = PCHUNK;
  for (int t = tid; t < NBUK; t += 256) lhist[t] = 0;
  __syncthreads();
  bool i64 = (*flag != 0);
  int es[16], ed[16], ml[16];
  #pragma unroll
  for (int k = 0; k < 16; ++k) {
    int ci = k * 256 + tid;
    if (ci < nE) {
      int e = base + ci;
      int s, d;
      if (i64) {
        const uint32_t* u = (const uint32_t*)eidx;
        s = (int)u[2 * (size_t)e];
        d = (int)u[2 * ((size_t)N_EDGES + e)];
      } else {
        const int* u = (const int*)eidx;
        s = u[e];
        d = u[N_EDGES + e];
      }
      es[k] = s; ed[k] = d;
      ml[k] = atomicAdd(&lhist[d >> BSH], 1);
    }
  }
  __syncthreads();
  sm[tid] = (tid < NBUK) ? lhist[tid] : 0;
  __syncthreads();
  for (int s = 1; s < 256; s <<= 1) {
    int t = (tid >= s) ? sm[tid - s] : 0;
    __syncthreads();
    sm[tid] += t;
    __syncthreads();
  }
  if (tid < NBUK) lbase[tid] = sm[tid] - lhist[tid];
  __syncthreads();
  #pragma unroll
  for (int k = 0; k < 16; ++k) {
    int ci = k * 256 + tid;
    if (ci < nE) {
      int b = ed[k] >> BSH;
      int slot = lbase[b] + ml[k];
      sbuf[slot] = make_int2(es[k], ed[k]);
      bbuf[slot] = (uint8_t)b;
    }
  }
  if (tid < NBUK && lhist[tid] > 0) gbase[tid] = atomicAdd(&bcur[tid], lhist[tid]);
  __syncthreads();
  for (int i = tid; i < nE; i += 256) {
    int b = bbuf[i];
    part[(size_t)gbase[b] + (i - lbase[b])] = sbuf[i];
  }
}

// ---- per-bucket: count -> offs/dinv -> scatter src into L2-local CSR window ----
__global__ __launch_bounds__(256) void k_bucket(const int2* __restrict__ part,
                                                const int* __restrict__ bbase,
                                                int* __restrict__ offs,
                                                float* __restrict__ dinv,
                                                int* __restrict__ sedge) {
  __shared__ int cnt[512];
  __shared__ int pre[512];
  __shared__ int s2[256];
  int tid = threadIdx.x, b = blockIdx.x;
  int v0 = b << BSH;
  int e0 = bbase[b], e1 = bbase[b + 1];
  cnt[tid] = 0; cnt[tid + 256] = 0;
  __syncthreads();
  #pragma unroll 4
  for (int i = e0 + tid; i < e1; i += 256) atomicAdd(&cnt[part[i].y - v0], 1);
  __syncthreads();
  int pa = cnt[2 * tid], pb = cnt[2 * tid + 1];
  s2[tid] = pa + pb;
  __syncthreads();
  for (int s = 1; s < 256; s <<= 1) {
    int t = (tid >= s) ? s2[tid - s] : 0;
    __syncthreads();
    s2[tid] += t;
    __syncthreads();
  }
  int eb = s2[tid] - (pa + pb);
  pre[2 * tid] = eb;
  pre[2 * tid + 1] = eb + pa;
  __syncthreads();
  #pragma unroll
  for (int k = 0; k < 2; ++k) {
    int t = tid + k * 256, v = v0 + t;
    if (v < N_NODES) {
      offs[v] = e0 + pre[t];
      dinv[v] = rsqrtf((float)(cnt[t] + 1));
    }
  }
  __syncthreads();
  cnt[tid] = pre[tid];
  cnt[tid + 256] = pre[tid + 256];
  __syncthreads();
  #pragma unroll 4
  for (int i = e0 + tid; i < e1; i += 256) {
    int2 e = part[i];
    int loc = atomicAdd(&cnt[e.y - v0], 1);
    sedge[e0 + loc] = e.x;
  }
}

// pack W [K][HID] f32 row-major into MFMA B-fragment-ready bf16 layout
__global__ void k_packW(const float* __restrict__ W, uint16_t* __restrict__ Wp, int K) {
  int t = blockIdx.x * blockDim.x + threadIdx.x;
  int total = (K / 32) * 8 * 64;
  if (t >= total) return;
  int l = t & 63;
  int nt = (t >> 6) & 7;
  int ks = t >> 9;
  int kbase = ks * 32 + (l >> 4) * 8;
  int col = nt * 16 + (l & 15);
  #pragma unroll
  for (int j = 0; j < 8; ++j)
    Wp[(size_t)t * 8 + j] = (uint16_t)f2bf(W[(size_t)(kbase + j) * HID + col]);
}

// epilogue: quantize acc tiles to biased-uint8 rows + dsc (= scale * dinv), via LDS repack
__device__ __forceinline__ void epilogue_int8(const f32x4* acc, int l, int row0,
                                              uint8_t* lds_my,
                                              uint8_t* __restrict__ H8,
                                              float* __restrict__ dsc,
                                              const float* __restrict__ dinv) {
  float inv[4];
  #pragma unroll
  for (int j = 0; j < 4; ++j) {
    float m = 0.f;
    #pragma unroll
    for (int nt = 0; nt < 8; ++nt) m = fmaxf(m, fabsf(acc[nt][j]));
    #pragma unroll
    for (int s = 1; s < 16; s <<= 1) m = fmaxf(m, __shfl_xor(m, s, 64));
    m = fmaxf(m, 1e-20f);
    if ((l & 15) == 0) {
      int r = row0 + (l >> 4) * 4 + j;
      dsc[r] = m * (1.f / 127.f) * dinv[r];
    }
    inv[j] = 127.f / m;
  }
  #pragma unroll
  for (int nt = 0; nt < 8; ++nt)
    #pragma unroll
    for (int j = 0; j < 4; ++j) {
      int r = (l >> 4) * 4 + j, c = nt * 16 + (l & 15);
      float q = rintf(acc[nt][j] * inv[j]) + 128.f;
      lds_my[r * 128 + (c ^ ((r & 7) << 2))] = (uint8_t)(int)q;  // swizzle 4B-granule by row
    }
  asm volatile("s_waitcnt lgkmcnt(0)" ::: "memory");
  // lane l copies row (l>>2), 32B piece (l&3); un-swizzle at 16B granularity:
  int r = l >> 2;
  uint32_t w[8];
  #pragma unroll
  for (int t = 0; t < 8; ++t) {
    int c4 = (l & 3) * 8 + t;                 // 4B-granule index 0..31
    w[t] = *(const uint32_t*)(lds_my + r * 128 + ((c4 ^ (r & 7)) << 2) - ((c4 ^ (r & 7)) << 2 & 3));
  }
  // note: ((c4 ^ (r&7)) << 2) is already 4-aligned; the extra term is 0
  uint4* gp = (uint4*)(H8 + (size_t)(row0 + r) * 128 + (l & 3) * 32);
  gp[0] = make_uint4(w[0], w[1], w[2], w[3]);
  gp[1] = make_uint4(w[4], w[5], w[6], w[7]);
}

// layer-0 fused dual GEMM: X f32 [N][256]: X@W0 -> int8+dsc, X@Wr -> bf16 residual
// LDS-staged A (coalesced f32 loads, in-flight bf16 cvt, XOR-swizzled tile)
__global__ __launch_bounds__(256) void k_gemm0(const float* __restrict__ X,
                                               const uint16_t* __restrict__ Wp0,
                                               const uint16_t* __restrict__ WpR,
                                               uint8_t* __restrict__ H8,
                                               float* __restrict__ dsc,
                                               const float* __restrict__ dinv,
                                               uint16_t* __restrict__ resB) {
  __shared__ __align__(16) char smem[32768];  // A-tile [64][256] bf16, swizzled
  int tid = threadIdx.x, wid = tid >> 6, l = tid & 63;
  int blk = blockIdx.x;
  #pragma unroll
  for (int k = 0; k < 8; ++k) {
    int chunk = k * 256 + tid;     // 16B-chunk of bf16 tile, [0,2048)
    int row = chunk >> 5;          // [0,64)
    int col = chunk & 31;
    int grow = blk * 64 + row;
    if (grow > N_NODES - 1) grow = N_NODES - 1;
    const float* src = X + (size_t)grow * 256 + col * 8;
    float4 v0 = *(const float4*)src;
    float4 v1 = *(const float4*)(src + 4);
    uint4 pk;
    pk.x = f2bf(v0.x) | (f2bf(v0.y) << 16);
    pk.y = f2bf(v0.z) | (f2bf(v0.w) << 16);
    pk.z = f2bf(v1.x) | (f2bf(v1.y) << 16);
    pk.w = f2bf(v1.z) | (f2bf(v1.w) << 16);
    *(uint4*)(smem + row * 512 + ((col ^ (row & 7)) << 4)) = pk;
  }
  __syncthreads();
  int tile = blk * 4 + wid;
  if (tile >= N_NODES / 16) return;
  int row0 = tile * 16;
  int rl = wid * 16 + (l & 15);
  int hk = l >> 4;
  f32x4 acc0[8] = {}, accR[8] = {};
  const bf16x8* B0 = (const bf16x8*)Wp0;
  const bf16x8* BR = (const bf16x8*)WpR;
  #pragma unroll
  for (int ks = 0; ks < 8; ++ks) {
    bf16x8 a = *(const bf16x8*)(smem + rl * 512 + (((ks * 4 + hk) ^ (rl & 7)) << 4));
    #pragma unroll
    for (int nt = 0; nt < 8; ++nt) {
      acc0[nt] = __builtin_amdgcn_mfma_f32_16x16x32_bf16(a, B0[(size_t)(ks * 8 + nt) * 64 + l], acc0[nt], 0, 0, 0);
      accR[nt] = __builtin_amdgcn_mfma_f32_16x16x32_bf16(a, BR[(size_t)(ks * 8 + nt) * 64 + l], accR[nt], 0, 0, 0);
    }
  }
  asm volatile("s_waitcnt lgkmcnt(0)" ::: "memory");
  // per-wave epilogue region inside this wave's own A rows (dead now)
  uint8_t*  lds8 = (uint8_t*)(smem + wid * 8192);
  uint16_t* ldsb = (uint16_t*)(smem + wid * 8192 + 2048);
  epilogue_int8(acc0, l, row0, lds8, H8, dsc, dinv);
  #pragma unroll
  for (int nt = 0; nt < 8; ++nt)
    #pragma unroll
    for (int j = 0; j < 4; ++j)
      ldsb[((l >> 4) * 4 + j) * 128 + nt * 16 + (l & 15)] = (uint16_t)f2bf(accR[nt][j]);
  asm volatile("s_waitcnt lgkmcnt(0)" ::: "memory");
  const uint4* sb = (const uint4*)ldsb;
  uint4* gb = (uint4*)(resB + (size_t)(row0 + (l >> 2)) * 128 + (l & 3) * 32);
  #pragma unroll
  for (int t = 0; t < 4; ++t) gb[t] = sb[l * 4 + t];
}

// layers 1/2 GEMM: A bf16 [N][128] @ Wpack -> int8+dsc, LDS-staged swizzled A
__global__ __launch_bounds__(256) void k_gemm8(const uint16_t* __restrict__ A,
                                               const uint16_t* __restrict__ Wp,
                                               uint8_t* __restrict__ H8,
                                               float* __restrict__ dsc,
                                               const float* __restrict__ dinv) {
  __shared__ __align__(16) char smem[16384];  // A-tile [64][128] bf16, swizzled
  int tid = threadIdx.x, wid = tid >> 6, l = tid & 63;
  int blk = blockIdx.x;
  #pragma unroll
  for (int k = 0; k < 4; ++k) {
    int chunk = k * 256 + tid;     // [0,1024)
    int row = chunk >> 4;          // [0,64)
    int col = chunk & 15;
    int grow = blk * 64 + row;
    if (grow > N_NODES - 1) grow = N_NODES - 1;
    uint4 pk = *(const uint4*)(A + (size_t)grow * 128 + col * 8);
    *(uint4*)(smem + row * 256 + ((col ^ (row & 7)) << 4)) = pk;
  }
  __syncthreads();
  int tile = blk * 4 + wid;
  if (tile >= N_NODES / 16) return;
  int row0 = tile * 16;
  int rl = wid * 16 + (l & 15);
  int hk = l >> 4;
  f32x4 acc[8] = {};
  const bf16x8* Bp = (const bf16x8*)Wp;
  #pragma unroll
  for (int ks = 0; ks < 4; ++ks) {
    bf16x8 a = *(const bf16x8*)(smem + rl * 256 + (((ks * 4 + hk) ^ (rl & 7)) << 4));
    #pragma unroll
    for (int nt = 0; nt < 8; ++nt)
      acc[nt] = __builtin_amdgcn_mfma_f32_16x16x32_bf16(a, Bp[(size_t)(ks * 8 + nt) * 64 + l], acc[nt], 0, 0, 0);
  }
  asm volatile("s_waitcnt lgkmcnt(0)" ::: "memory");
  uint8_t* lds8 = (uint8_t*)(smem + wid * 4096);
  epilogue_int8(acc, l, row0, lds8, H8, dsc, dinv);
}

// fused: int8 gather-sum + bias + LN + ReLU + bf16 residual
// two 32-lane halves: half g processes edges of parity g; lane owns 4 channels
__global__ __launch_bounds__(256) void k_agg(const uint8_t* __restrict__ H8,
                                             const float* __restrict__ dsc,
                                             const int* __restrict__ sedge,
                                             const int* __restrict__ offs,
                                             const float* __restrict__ dinv,
                                             const float* __restrict__ bias,
                                             const float* __restrict__ g,
                                             const float* __restrict__ be,
                                             const uint16_t* __restrict__ residB,
                                             float* __restrict__ outF,
                                             uint16_t* __restrict__ outB) {
  int wid = threadIdx.x >> 6, l = threadIdx.x & 63;
  int v = blockIdx.x * 4 + wid;
  if (v >= N_NODES) return;
  int gp = l >> 5, c = l & 31;
  float a0 = 0.f, a1 = 0.f, a2 = 0.f, a3 = 0.f, cs = 0.f;
  int p0 = offs[v], ne = offs[v + 1] - p0;
  int i = gp;
  for (; i + 2 < ne; i += 4) {
    int s0 = sedge[p0 + i], s1 = sedge[p0 + i + 2];
    uint32_t h0 = *(const uint32_t*)(H8 + (size_t)s0 * 128 + 4 * c);
    uint32_t h1 = *(const uint32_t*)(H8 + (size_t)s1 * 128 + 4 * c);
    float w0 = dsc[s0], w1 = dsc[s1];
    cs += w0 + w1;
    a0 += w0 * (float)(h0 & 0xFFu)         + w1 * (float)(h1 & 0xFFu);
    a1 += w0 * (float)((h0 >> 8) & 0xFFu)  + w1 * (float)((h1 >> 8) & 0xFFu);
    a2 += w0 * (float)((h0 >> 16) & 0xFFu) + w1 * (float)((h1 >> 16) & 0xFFu);
    a3 += w0 * (float)(h0 >> 24)           + w1 * (float)(h1 >> 24);
  }
  for (; i < ne; i += 2) {
    int s0 = sedge[p0 + i];
    uint32_t h0 = *(const uint32_t*)(H8 + (size_t)s0 * 128 + 4 * c);
    float w0 = dsc[s0];
    cs += w0;
    a0 += w0 * (float)(h0 & 0xFFu);
    a1 += w0 * (float)((h0 >> 8) & 0xFFu);
    a2 += w0 * (float)((h0 >> 16) & 0xFFu);
    a3 += w0 * (float)(h0 >> 24);
  }
  a0 += __shfl_xor(a0, 32, 64);
  a1 += __shfl_xor(a1, 32, 64);
  a2 += __shfl_xor(a2, 32, 64);
  a3 += __shfl_xor(a3, 32, 64);
  cs += __shfl_xor(cs, 32, 64);
  float dv = dinv[v];
  a0 = dv * (a0 - 128.f * cs);
  a1 = dv * (a1 - 128.f * cs);
  a2 = dv * (a2 - 128.f * cs);
  a3 = dv * (a3 - 128.f * cs);
  {  // self loop (both halves compute identically)
    uint32_t h = *(const uint32_t*)(H8 + (size_t)v * 128 + 4 * c);
    float wss = dv * dsc[v];
    a0 += wss * ((float)(h & 0xFFu) - 128.f);
    a1 += wss * ((float)((h >> 8) & 0xFFu) - 128.f);
    a2 += wss * ((float)((h >> 16) & 0xFFu) - 128.f);
    a3 += wss * ((float)(h >> 24) - 128.f);
  }
  float4 bb = *(const float4*)(bias + 4 * c);
  a0 += bb.x; a1 += bb.y; a2 += bb.z; a3 += bb.w;
  float s = a0 + a1 + a2 + a3;
  #pragma unroll
  for (int m = 1; m < 32; m <<= 1) s += __shfl_xor(s, m, 64);
  float mu = s * (1.f / 128.f);
  float d0 = a0 - mu, d1 = a1 - mu, d2 = a2 - mu, d3 = a3 - mu;
  float q = d0 * d0 + d1 * d1 + d2 * d2 + d3 * d3;
  #pragma unroll
  for (int m = 1; m < 32; m <<= 1) q += __shfl_xor(q, m, 64);
  float rs = rsqrtf(q * (1.f / 128.f) + EPS);
  float4 gg = *(const float4*)(g + 4 * c);
  float4 ee = *(const float4*)(be + 4 * c);
  float y0 = fmaxf(d0 * rs * gg.x + ee.x, 0.f);
  float y1 = fmaxf(d1 * rs * gg.y + ee.y, 0.f);
  float y2 = fmaxf(d2 * rs * gg.z + ee.z, 0.f);
  float y3 = fmaxf(d3 * rs * gg.w + ee.w, 0.f);
  uint2 rr = *(const uint2*)(residB + (size_t)v * 128 + 4 * c);
  y0 += bflo(rr.x); y1 += bfhi(rr.x);
  y2 += bflo(rr.y); y3 += bfhi(rr.y);
  if (gp == 0) {
    if (outF) *(float4*)(outF + (size_t)v * HID + 4 * c) = make_float4(y0, y1, y2, y3);
    if (outB) {
      uint2 o;
      o.x = f2bf(y0) | (f2bf(y1) << 16);
      o.y = f2bf(y2) | (f2bf(y3) << 16);
      *(uint2*)(outB + (size_t)v * 128 + 4 * c) = o;
    }
  }
}

extern "C" void kernel_launch(void* const* d_in, const int* in_sizes, int n_in,
                              void* d_out, int out_size, void* d_ws, size_t ws_size,
                              hipStream_t stream) {
  const float* x   = (const float*)d_in[0];
  const void*  ei  = d_in[1];
  const float* W0  = (const float*)d_in[2];
  const float* b0  = (const float*)d_in[3];
  const float* g0  = (const float*)d_in[4];
  const float* be0 = (const float*)d_in[5];
  const float* W1  = (const float*)d_in[6];
  const float* b1  = (const float*)d_in[7];
  const float* g1  = (const float*)d_in[8];
  const float* be1 = (const float*)d_in[9];
  const float* W2  = (const float*)d_in[10];
  const float* b2  = (const float*)d_in[11];
  const float* g2  = (const float*)d_in[12];
  const float* be2 = (const float*)d_in[13];
  const float* Wr  = (const float*)d_in[14];

  char* ws = (char*)d_ws;
  int*      sedge  = (int*)(ws + OFF_SRC);
  int*      offs   = (int*)(ws + OFF_OFFS);
  float*    dinv   = (float*)(ws + OFF_DINV);
  float*    dsc    = (float*)(ws + OFF_DSC);
  uint16_t* wpk0   = (uint16_t*)(ws + OFF_WPK0);
  uint16_t* wpk1   = (uint16_t*)(ws + OFF_WPK1);
  uint16_t* wpk2   = (uint16_t*)(ws + OFF_WPK2);
  uint16_t* wpkr   = (uint16_t*)(ws + OFF_WPKR);
  int*      flag   = (int*)(ws + OFF_FLAG);
  int*      bcnt   = (int*)(ws + OFF_BCNT);
  int*      bbase  = (int*)(ws + OFF_BBASE);
  int*      bcur   = (int*)(ws + OFF_BCUR);
  uint8_t*  h8     = (uint8_t*)(ws + OFF_H8);
  int2*     part   = (int2*)(ws + OFF_PART);
  uint16_t* resB   = (uint16_t*)(ws + OFF_RESB);
  uint16_t* hbA    = (uint16_t*)(ws + OFF_HBA);
  uint16_t* hbB    = (uint16_t*)(ws + OFF_HBB);
  float*    out    = (float*)d_out;

  // ---- edge preprocessing: hist -> scan -> partition -> per-bucket CSR ----
  k_flag<<<1, 256, 0, stream>>>((const uint32_t*)ei, flag);
  hipMemsetAsync(bcnt, 0, NBUK * sizeof(int), stream);
  k_hist<<<2048, 256, 0, stream>>>(ei, flag, bcnt);
  k_bscan<<<1, 64, 0, stream>>>(bcnt, bbase, bcur, offs);
  k_part<<<(N_EDGES + PCHUNK - 1) / PCHUNK, 256, 0, stream>>>(ei, flag, bcur, part);
  k_bucket<<<NBUK, 256, 0, stream>>>(part, bbase, offs, dinv, sedge);

  // ---- weight packing ----
  k_packW<<<16, 256, 0, stream>>>(W0, wpk0, IN_CH);
  k_packW<<<8, 256, 0, stream>>>(W1, wpk1, HID);
  k_packW<<<8, 256, 0, stream>>>(W2, wpk2, HID);
  k_packW<<<16, 256, 0, stream>>>(Wr, wpkr, IN_CH);

  // ---- layer 0: fused dual GEMM (x@W0 -> int8, x@Wr -> bf16 residual) ----
  k_gemm0<<<1563, 256, 0, stream>>>(x, wpk0, wpkr, h8, dsc, dinv, resB);
  k_agg<<<25000, 256, 0, stream>>>(h8, dsc, sedge, offs, dinv, b0, g0, be0, resB, nullptr, hbA);

  // ---- layer 1 ----
  k_gemm8<<<1563, 256, 0, stream>>>(hbA, wpk1, h8, dsc, dinv);
  k_agg<<<25000, 256, 0, stream>>>(h8, dsc, sedge, offs, dinv, b1, g1, be1, hbA, nullptr, hbB);

  // ---- layer 2 (writes d_out f32) ----
  k_gemm8<<<1563, 256, 0, stream>>>(hbB, wpk2, h8, dsc, dinv);
  k_agg<<<25000, 256, 0, stream>>>(h8, dsc, sedge, offs, dinv, b2, g2, be2, hbB, out, nullptr);

  (void)in_sizes; (void)n_in; (void)out_size; (void)ws_size;
}

// Round 5
// 595.588 us; speedup vs baseline: 1.5799x; 1.0365x over previous
//
#include <hip/hip_runtime.h>
#include <hip/hip_bf16.h>
#include <stdint.h>

#define N_NODES 100000
#define N_EDGES 3200000
#define IN_CH 256
#define HID 128
#define EPS 1e-5f
#define BSH 9              // bucket = dst >> 9  (512 nodes per bucket)
#define NBUK 196           // ceil(100000/512)
#define PCHUNK 4096
#define GEMM_GRID 782      // ceil(100000/128)

using bf16x8 = __attribute__((ext_vector_type(8))) short;
using f32x4  = __attribute__((ext_vector_type(4))) float;

__device__ __forceinline__ uint32_t f2bf(float f) {
  uint32_t u = __float_as_uint(f);
  return (u + 0x7FFFu + ((u >> 16) & 1u)) >> 16;
}
__device__ __forceinline__ float bflo(uint32_t u) { return __uint_as_float(u << 16); }
__device__ __forceinline__ float bfhi(uint32_t u) { return __uint_as_float(u & 0xFFFF0000u); }

// ---- workspace layout (bytes), all 128-aligned ----
static const size_t OFF_SRC   = 0;            // int[3.2M] = 12,800,000 (CSR src)
static const size_t OFF_OFFS  = 12800000;     // int[100001]
static const size_t OFF_DINV  = 13200128;     // float[100000]
static const size_t OFF_DSC   = 13600128;     // float[100000]
static const size_t OFF_WPK0  = 14000128;     // 65,536
static const size_t OFF_WPK1  = 14065664;     // 32,768
static const size_t OFF_WPK2  = 14098432;     // 32,768
static const size_t OFF_WPKR  = 14131200;     // 65,536
static const size_t OFF_FLAG  = 14196736;     // int (+pad)
static const size_t OFF_BCNT  = 14196864;     // int[NBUK]
static const size_t OFF_BBASE = 14197888;     // int[NBUK+1]
static const size_t OFF_BCUR  = 14198912;     // int[NBUK]
static const size_t OFF_H8    = 14200064;     // u8[100000*128] = 12,800,000
static const size_t OFF_PART  = 14200064;     // int2[3.2M] = 25.6MB (aliases H8+resB head; dead before GEMM)
static const size_t OFF_RESB  = 27000064;     // bf16[100000*128] = 25,600,000
static const size_t OFF_HBA   = 52600064;     // bf16[100000*128]
static const size_t OFF_HBB   = 78200064;     // bf16[100000*128]  (end ~103.8MB)

// ---- edge dtype detection: int64 edges have zero high words ----
__global__ void k_flag(const uint32_t* __restrict__ e, int* flag) {
  __shared__ int any;
  if (threadIdx.x == 0) any = 0;
  __syncthreads();
  uint32_t acc = 0;
  for (int i = threadIdx.x; i < 2048; i += blockDim.x) acc |= e[2 * i + 1];
  if (acc) atomicOr(&any, 1);
  __syncthreads();
  if (threadIdx.x == 0) *flag = (any == 0) ? 1 : 0;  // 1 => int64 layout
}

// ---- bucket histogram (LDS-aggregated) ----
__global__ __launch_bounds__(256) void k_hist(const void* __restrict__ eidx,
                                              const int* __restrict__ flag,
                                              int* __restrict__ bcnt) {
  __shared__ int h[NBUK];
  for (int t = threadIdx.x; t < NBUK; t += 256) h[t] = 0;
  __syncthreads();
  bool i64 = (*flag != 0);
  int stride = gridDim.x * blockDim.x;
  for (int e = blockIdx.x * blockDim.x + threadIdx.x; e < N_EDGES; e += stride) {
    int d = i64 ? (int)((const uint32_t*)eidx)[2 * ((size_t)N_EDGES + e)]
                : ((const int*)eidx)[N_EDGES + e];
    atomicAdd(&h[d >> BSH], 1);
  }
  __syncthreads();
  for (int t = threadIdx.x; t < NBUK; t += 256)
    if (h[t]) atomicAdd(&bcnt[t], h[t]);
}

// ---- serial bucket scan (196 elems) ----
__global__ void k_bscan(const int* __restrict__ bcnt, int* __restrict__ bbase,
                        int* __restrict__ bcur, int* __restrict__ offs) {
  if (threadIdx.x == 0 && blockIdx.x == 0) {
    int run = 0;
    for (int b = 0; b < NBUK; ++b) {
      bbase[b] = run;
      bcur[b] = run;
      run += bcnt[b];
    }
    bbase[NBUK] = run;
    offs[N_NODES] = run;
  }
}

// ---- LDS-staged partition into buckets (coalesced writes) ----
__global__ __launch_bounds__(256) void k_part(const void* __restrict__ eidx,
                                              const int* __restrict__ flag,
                                              int* __restrict__ bcur,
                                              int2* __restrict__ part) {
  __shared__ int lhist[NBUK];
  __shared__ int lbase[NBUK];
  __shared__ int gbase[NBUK];
  __shared__ int sm[256];
  __shared__ int2 sbuf[PCHUNK];
  __shared__ uint8_t bbuf[PCHUNK];
  int tid = threadIdx.x;
  int base = blockIdx.x * PCHUNK;
  int nE = N_EDGES - base;
  if (nE > PCHUNK) nE = PCHUNK;
  for (int t = tid; t < NBUK; t += 256) lhist[t] = 0;
  __syncthreads();
  bool i64 = (*flag != 0);
  int es[16], ed[16], ml[16];
  #pragma unroll
  for (int k = 0; k < 16; ++k) {
    int ci = k * 256 + tid;
    if (ci < nE) {
      int e = base + ci;
      int s, d;
      if (i64) {
        const uint32_t* u = (const uint32_t*)eidx;
        s = (int)u[2 * (size_t)e];
        d = (int)u[2 * ((size_t)N_EDGES + e)];
      } else {
        const int* u = (const int*)eidx;
        s = u[e];
        d = u[N_EDGES + e];
      }
      es[k] = s; ed[k] = d;
      ml[k] = atomicAdd(&lhist[d >> BSH], 1);
    }
  }
  __syncthreads();
  sm[tid] = (tid < NBUK) ? lhist[tid] : 0;
  __syncthreads();
  for (int s = 1; s < 256; s <<= 1) {
    int t = (tid >= s) ? sm[tid - s] : 0;
    __syncthreads();
    sm[tid] += t;
    __syncthreads();
  }
  if (tid < NBUK) lbase[tid] = sm[tid] - lhist[tid];
  __syncthreads();
  #pragma unroll
  for (int k = 0; k < 16; ++k) {
    int ci = k * 256 + tid;
    if (ci < nE) {
      int b = ed[k] >> BSH;
      int slot = lbase[b] + ml[k];
      sbuf[slot] = make_int2(es[k], ed[k]);
      bbuf[slot] = (uint8_t)b;
    }
  }
  if (tid < NBUK && lhist[tid] > 0) gbase[tid] = atomicAdd(&bcur[tid], lhist[tid]);
  __syncthreads();
  for (int i = tid; i < nE; i += 256) {
    int b = bbuf[i];
    part[(size_t)gbase[b] + (i - lbase[b])] = sbuf[i];
  }
}

// ---- per-bucket: count -> offs/dinv -> scatter src into L2-local CSR window ----
__global__ __launch_bounds__(256) void k_bucket(const int2* __restrict__ part,
                                                const int* __restrict__ bbase,
                                                int* __restrict__ offs,
                                                float* __restrict__ dinv,
                                                int* __restrict__ sedge) {
  __shared__ int cnt[512];
  __shared__ int pre[512];
  __shared__ int s2[256];
  int tid = threadIdx.x, b = blockIdx.x;
  int v0 = b << BSH;
  int e0 = bbase[b], e1 = bbase[b + 1];
  cnt[tid] = 0; cnt[tid + 256] = 0;
  __syncthreads();
  #pragma unroll 4
  for (int i = e0 + tid; i < e1; i += 256) atomicAdd(&cnt[part[i].y - v0], 1);
  __syncthreads();
  int pa = cnt[2 * tid], pb = cnt[2 * tid + 1];
  s2[tid] = pa + pb;
  __syncthreads();
  for (int s = 1; s < 256; s <<= 1) {
    int t = (tid >= s) ? s2[tid - s] : 0;
    __syncthreads();
    s2[tid] += t;
    __syncthreads();
  }
  int eb = s2[tid] - (pa + pb);
  pre[2 * tid] = eb;
  pre[2 * tid + 1] = eb + pa;
  __syncthreads();
  #pragma unroll
  for (int k = 0; k < 2; ++k) {
    int t = tid + k * 256, v = v0 + t;
    if (v < N_NODES) {
      offs[v] = e0 + pre[t];
      dinv[v] = rsqrtf((float)(cnt[t] + 1));
    }
  }
  __syncthreads();
  cnt[tid] = pre[tid];
  cnt[tid + 256] = pre[tid + 256];
  __syncthreads();
  #pragma unroll 4
  for (int i = e0 + tid; i < e1; i += 256) {
    int2 e = part[i];
    int loc = atomicAdd(&cnt[e.y - v0], 1);
    sedge[e0 + loc] = e.x;
  }
}

// pack W [K][HID] f32 row-major into MFMA B-fragment-ready bf16 layout
__global__ void k_packW(const float* __restrict__ W, uint16_t* __restrict__ Wp, int K) {
  int t = blockIdx.x * blockDim.x + threadIdx.x;
  int total = (K / 32) * 8 * 64;
  if (t >= total) return;
  int l = t & 63;
  int nt = (t >> 6) & 7;
  int ks = t >> 9;
  int kbase = ks * 32 + (l >> 4) * 8;
  int col = nt * 16 + (l & 15);
  #pragma unroll
  for (int j = 0; j < 8; ++j)
    Wp[(size_t)t * 8 + j] = (uint16_t)f2bf(W[(size_t)(kbase + j) * HID + col]);
}

// epilogue: quantize acc tiles to biased-uint8 rows + dsc (= scale * dinv), via LDS repack
__device__ __forceinline__ void epilogue_int8(const f32x4* acc, int l, int row0,
                                              uint8_t* lds_my,
                                              uint8_t* __restrict__ H8,
                                              float* __restrict__ dsc,
                                              const float* __restrict__ dinv) {
  float inv[4];
  #pragma unroll
  for (int j = 0; j < 4; ++j) {
    float m = 0.f;
    #pragma unroll
    for (int nt = 0; nt < 8; ++nt) m = fmaxf(m, fabsf(acc[nt][j]));
    #pragma unroll
    for (int s = 1; s < 16; s <<= 1) m = fmaxf(m, __shfl_xor(m, s, 64));
    m = fmaxf(m, 1e-20f);
    int r = row0 + (l >> 4) * 4 + j;
    if ((l & 15) == 0 && r < N_NODES) dsc[r] = m * (1.f / 127.f) * dinv[r];
    inv[j] = 127.f / m;
  }
  #pragma unroll
  for (int nt = 0; nt < 8; ++nt)
    #pragma unroll
    for (int j = 0; j < 4; ++j) {
      int r = (l >> 4) * 4 + j, c = nt * 16 + (l & 15);
      float q = rintf(acc[nt][j] * inv[j]) + 128.f;
      lds_my[r * 128 + (c ^ ((r & 7) << 2))] = (uint8_t)(int)q;  // 4B-granule swizzle by row
    }
  asm volatile("s_waitcnt lgkmcnt(0)" ::: "memory");
  int r = l >> 2;
  uint32_t w[8];
  #pragma unroll
  for (int t = 0; t < 8; ++t) {
    int c4 = (l & 3) * 8 + t;
    w[t] = *(const uint32_t*)(lds_my + r * 128 + ((c4 ^ (r & 7)) << 2));
  }
  if (row0 + r < N_NODES) {
    uint4* gp = (uint4*)(H8 + (size_t)(row0 + r) * 128 + (l & 3) * 32);
    gp[0] = make_uint4(w[0], w[1], w[2], w[3]);
    gp[1] = make_uint4(w[4], w[5], w[6], w[7]);
  }
}

// layer-0 fused dual GEMM: X f32 [N][256]: X@W0 -> int8+dsc, X@Wr -> bf16 residual
// Block = 4 waves x 32 rows = 128 rows. B staged in LDS in 2 K-phases (64 KB).
__global__ __launch_bounds__(256) void k_gemm0(const float* __restrict__ X,
                                               const uint16_t* __restrict__ Wp0,
                                               const uint16_t* __restrict__ WpR,
                                               uint8_t* __restrict__ H8,
                                               float* __restrict__ dsc,
                                               const float* __restrict__ dinv,
                                               uint16_t* __restrict__ resB) {
  __shared__ __align__(16) char smem[65536];
  int tid = threadIdx.x, wid = tid >> 6, l = tid & 63;
  int r0 = blockIdx.x * 128 + wid * 32;
  int hk = l >> 4, rl = l & 15;
  int ra0 = min(r0 + rl, N_NODES - 1);
  int ra1 = min(r0 + 16 + rl, N_NODES - 1);
  f32x4 acc0[2][8] = {}, accR[2][8] = {};
  #pragma unroll
  for (int kh = 0; kh < 2; ++kh) {
    __syncthreads();
    #pragma unroll
    for (int i = 0; i < 8; ++i) {
      int g = i * 256 + tid;
      *(uint4*)(smem + g * 16) =
          *(const uint4*)((const char*)Wp0 + kh * 32768 + g * 16);
      *(uint4*)(smem + 32768 + g * 16) =
          *(const uint4*)((const char*)WpR + kh * 32768 + g * 16);
    }
    __syncthreads();
    #pragma unroll
    for (int ksl = 0; ksl < 4; ++ksl) {
      int kof = kh * 128 + ksl * 32 + hk * 8;
      float4 u0 = *(const float4*)(X + (size_t)ra0 * 256 + kof);
      float4 u1 = *(const float4*)(X + (size_t)ra0 * 256 + kof + 4);
      float4 v0 = *(const float4*)(X + (size_t)ra1 * 256 + kof);
      float4 v1 = *(const float4*)(X + (size_t)ra1 * 256 + kof + 4);
      bf16x8 a0, a1;
      a0[0] = (short)f2bf(u0.x); a0[1] = (short)f2bf(u0.y);
      a0[2] = (short)f2bf(u0.z); a0[3] = (short)f2bf(u0.w);
      a0[4] = (short)f2bf(u1.x); a0[5] = (short)f2bf(u1.y);
      a0[6] = (short)f2bf(u1.z); a0[7] = (short)f2bf(u1.w);
      a1[0] = (short)f2bf(v0.x); a1[1] = (short)f2bf(v0.y);
      a1[2] = (short)f2bf(v0.z); a1[3] = (short)f2bf(v0.w);
      a1[4] = (short)f2bf(v1.x); a1[5] = (short)f2bf(v1.y);
      a1[6] = (short)f2bf(v1.z); a1[7] = (short)f2bf(v1.w);
      #pragma unroll
      for (int nt = 0; nt < 8; ++nt) {
        bf16x8 b0 = *(const bf16x8*)(smem + ((ksl * 8 + nt) * 64 + l) * 16);
        acc0[0][nt] = __builtin_amdgcn_mfma_f32_16x16x32_bf16(a0, b0, acc0[0][nt], 0, 0, 0);
        acc0[1][nt] = __builtin_amdgcn_mfma_f32_16x16x32_bf16(a1, b0, acc0[1][nt], 0, 0, 0);
        bf16x8 br = *(const bf16x8*)(smem + 32768 + ((ksl * 8 + nt) * 64 + l) * 16);
        accR[0][nt] = __builtin_amdgcn_mfma_f32_16x16x32_bf16(a0, br, accR[0][nt], 0, 0, 0);
        accR[1][nt] = __builtin_amdgcn_mfma_f32_16x16x32_bf16(a1, br, accR[1][nt], 0, 0, 0);
      }
    }
  }
  __syncthreads();  // B dead; smem becomes per-wave epilogue scratch
  uint8_t*  lds8 = (uint8_t*)(smem + wid * 16384);
  uint16_t* ldsb = (uint16_t*)(smem + wid * 16384 + 4096);
  #pragma unroll
  for (int rt = 0; rt < 2; ++rt) {
    int row0 = r0 + rt * 16;
    epilogue_int8(acc0[rt], l, row0, lds8, H8, dsc, dinv);
    #pragma unroll
    for (int nt = 0; nt < 8; ++nt)
      #pragma unroll
      for (int j = 0; j < 4; ++j)
        ldsb[((l >> 4) * 4 + j) * 128 + nt * 16 + (l & 15)] = (uint16_t)f2bf(accR[rt][nt][j]);
    asm volatile("s_waitcnt lgkmcnt(0)" ::: "memory");
    const uint4* sb = (const uint4*)ldsb;
    if (row0 + (l >> 2) < N_NODES) {
      uint4* gb = (uint4*)(resB + (size_t)(row0 + (l >> 2)) * 128 + (l & 3) * 32);
      #pragma unroll
      for (int t = 0; t < 4; ++t) gb[t] = sb[l * 4 + t];
    }
  }
}

// layers 1/2 GEMM: A bf16 [N][128] @ Wp(LDS-shared) -> int8+dsc
// Block = 4 waves x 32 rows = 128 rows; full B (32 KB) staged once.
__global__ __launch_bounds__(256) void k_gemm8(const uint16_t* __restrict__ A,
                                               const uint16_t* __restrict__ Wp,
                                               uint8_t* __restrict__ H8,
                                               float* __restrict__ dsc,
                                               const float* __restrict__ dinv) {
  __shared__ __align__(16) char smem[32768];
  int tid = threadIdx.x, wid = tid >> 6, l = tid & 63;
  #pragma unroll
  for (int i = 0; i < 8; ++i) {
    int g = i * 256 + tid;
    *(uint4*)(smem + g * 16) = *(const uint4*)((const char*)Wp + g * 16);
  }
  __syncthreads();
  int r0 = blockIdx.x * 128 + wid * 32;
  int hk = l >> 4, rl = l & 15;
  int ra0 = min(r0 + rl, N_NODES - 1);
  int ra1 = min(r0 + 16 + rl, N_NODES - 1);
  f32x4 acc[2][8] = {};
  #pragma unroll
  for (int ks = 0; ks < 4; ++ks) {
    bf16x8 a0 = *(const bf16x8*)(A + (size_t)ra0 * 128 + ks * 32 + hk * 8);
    bf16x8 a1 = *(const bf16x8*)(A + (size_t)ra1 * 128 + ks * 32 + hk * 8);
    #pragma unroll
    for (int nt = 0; nt < 8; ++nt) {
      bf16x8 b = *(const bf16x8*)(smem + ((ks * 8 + nt) * 64 + l) * 16);
      acc[0][nt] = __builtin_amdgcn_mfma_f32_16x16x32_bf16(a0, b, acc[0][nt], 0, 0, 0);
      acc[1][nt] = __builtin_amdgcn_mfma_f32_16x16x32_bf16(a1, b, acc[1][nt], 0, 0, 0);
    }
  }
  __syncthreads();  // B dead; reuse as epilogue scratch
  uint8_t* lds8 = (uint8_t*)(smem + wid * 4096);
  epilogue_int8(acc[0], l, r0, lds8, H8, dsc, dinv);
  epilogue_int8(acc[1], l, r0 + 16, lds8, H8, dsc, dinv);
}

// fused: int8 gather-sum + bias + LN + ReLU + bf16 residual
// two 32-lane halves: half g processes edges of parity g; lane owns 4 channels
__global__ __launch_bounds__(256) void k_agg(const uint8_t* __restrict__ H8,
                                             const float* __restrict__ dsc,
                                             const int* __restrict__ sedge,
                                             const int* __restrict__ offs,
                                             const float* __restrict__ dinv,
                                             const float* __restrict__ bias,
                                             const float* __restrict__ g,
                                             const float* __restrict__ be,
                                             const uint16_t* __restrict__ residB,
                                             float* __restrict__ outF,
                                             uint16_t* __restrict__ outB) {
  int wid = threadIdx.x >> 6, l = threadIdx.x & 63;
  int v = blockIdx.x * 4 + wid;
  if (v >= N_NODES) return;
  int gp = l >> 5, c = l & 31;
  float a0 = 0.f, a1 = 0.f, a2 = 0.f, a3 = 0.f, cs = 0.f;
  int p0 = offs[v], ne = offs[v + 1] - p0;
  int i = gp;
  for (; i + 2 < ne; i += 4) {
    int s0 = sedge[p0 + i], s1 = sedge[p0 + i + 2];
    uint32_t h0 = *(const uint32_t*)(H8 + (size_t)s0 * 128 + 4 * c);
    uint32_t h1 = *(const uint32_t*)(H8 + (size_t)s1 * 128 + 4 * c);
    float w0 = dsc[s0], w1 = dsc[s1];
    cs += w0 + w1;
    a0 += w0 * (float)(h0 & 0xFFu)         + w1 * (float)(h1 & 0xFFu);
    a1 += w0 * (float)((h0 >> 8) & 0xFFu)  + w1 * (float)((h1 >> 8) & 0xFFu);
    a2 += w0 * (float)((h0 >> 16) & 0xFFu) + w1 * (float)((h1 >> 16) & 0xFFu);
    a3 += w0 * (float)(h0 >> 24)           + w1 * (float)(h1 >> 24);
  }
  for (; i < ne; i += 2) {
    int s0 = sedge[p0 + i];
    uint32_t h0 = *(const uint32_t*)(H8 + (size_t)s0 * 128 + 4 * c);
    float w0 = dsc[s0];
    cs += w0;
    a0 += w0 * (float)(h0 & 0xFFu);
    a1 += w0 * (float)((h0 >> 8) & 0xFFu);
    a2 += w0 * (float)((h0 >> 16) & 0xFFu);
    a3 += w0 * (float)(h0 >> 24);
  }
  a0 += __shfl_xor(a0, 32, 64);
  a1 += __shfl_xor(a1, 32, 64);
  a2 += __shfl_xor(a2, 32, 64);
  a3 += __shfl_xor(a3, 32, 64);
  cs += __shfl_xor(cs, 32, 64);
  float dv = dinv[v];
  a0 = dv * (a0 - 128.f * cs);
  a1 = dv * (a1 - 128.f * cs);
  a2 = dv * (a2 - 128.f * cs);
  a3 = dv * (a3 - 128.f * cs);
  {  // self loop
    uint32_t h = *(const uint32_t*)(H8 + (size_t)v * 128 + 4 * c);
    float wss = dv * dsc[v];
    a0 += wss * ((float)(h & 0xFFu) - 128.f);
    a1 += wss * ((float)((h >> 8) & 0xFFu) - 128.f);
    a2 += wss * ((float)((h >> 16) & 0xFFu) - 128.f);
    a3 += wss * ((float)(h >> 24) - 128.f);
  }
  float4 bb = *(const float4*)(bias + 4 * c);
  a0 += bb.x; a1 += bb.y; a2 += bb.z; a3 += bb.w;
  float s = a0 + a1 + a2 + a3;
  #pragma unroll
  for (int m = 1; m < 32; m <<= 1) s += __shfl_xor(s, m, 64);
  float mu = s * (1.f / 128.f);
  float d0 = a0 - mu, d1 = a1 - mu, d2 = a2 - mu, d3 = a3 - mu;
  float q = d0 * d0 + d1 * d1 + d2 * d2 + d3 * d3;
  #pragma unroll
  for (int m = 1; m < 32; m <<= 1) q += __shfl_xor(q, m, 64);
  float rs = rsqrtf(q * (1.f / 128.f) + EPS);
  float4 gg = *(const float4*)(g + 4 * c);
  float4 ee = *(const float4*)(be + 4 * c);
  float y0 = fmaxf(d0 * rs * gg.x + ee.x, 0.f);
  float y1 = fmaxf(d1 * rs * gg.y + ee.y, 0.f);
  float y2 = fmaxf(d2 * rs * gg.z + ee.z, 0.f);
  float y3 = fmaxf(d3 * rs * gg.w + ee.w, 0.f);
  uint2 rr = *(const uint2*)(residB + (size_t)v * 128 + 4 * c);
  y0 += bflo(rr.x); y1 += bfhi(rr.x);
  y2 += bflo(rr.y); y3 += bfhi(rr.y);
  if (gp == 0) {
    if (outF) *(float4*)(outF + (size_t)v * HID + 4 * c) = make_float4(y0, y1, y2, y3);
    if (outB) {
      uint2 o;
      o.x = f2bf(y0) | (f2bf(y1) << 16);
      o.y = f2bf(y2) | (f2bf(y3) << 16);
      *(uint2*)(outB + (size_t)v * 128 + 4 * c) = o;
    }
  }
}

extern "C" void kernel_launch(void* const* d_in, const int* in_sizes, int n_in,
                              void* d_out, int out_size, void* d_ws, size_t ws_size,
                              hipStream_t stream) {
  const float* x   = (const float*)d_in[0];
  const void*  ei  = d_in[1];
  const float* W0  = (const float*)d_in[2];
  const float* b0  = (const float*)d_in[3];
  const float* g0  = (const float*)d_in[4];
  const float* be0 = (const float*)d_in[5];
  const float* W1  = (const float*)d_in[6];
  const float* b1  = (const float*)d_in[7];
  const float* g1  = (const float*)d_in[8];
  const float* be1 = (const float*)d_in[9];
  const float* W2  = (const float*)d_in[10];
  const float* b2  = (const float*)d_in[11];
  const float* g2  = (const float*)d_in[12];
  const float* be2 = (const float*)d_in[13];
  const float* Wr  = (const float*)d_in[14];

  char* ws = (char*)d_ws;
  int*      sedge  = (int*)(ws + OFF_SRC);
  int*      offs   = (int*)(ws + OFF_OFFS);
  float*    dinv   = (float*)(ws + OFF_DINV);
  float*    dsc    = (float*)(ws + OFF_DSC);
  uint16_t* wpk0   = (uint16_t*)(ws + OFF_WPK0);
  uint16_t* wpk1   = (uint16_t*)(ws + OFF_WPK1);
  uint16_t* wpk2   = (uint16_t*)(ws + OFF_WPK2);
  uint16_t* wpkr   = (uint16_t*)(ws + OFF_WPKR);
  int*      flag   = (int*)(ws + OFF_FLAG);
  int*      bcnt   = (int*)(ws + OFF_BCNT);
  int*      bbase  = (int*)(ws + OFF_BBASE);
  int*      bcur   = (int*)(ws + OFF_BCUR);
  uint8_t*  h8     = (uint8_t*)(ws + OFF_H8);
  int2*     part   = (int2*)(ws + OFF_PART);
  uint16_t* resB   = (uint16_t*)(ws + OFF_RESB);
  uint16_t* hbA    = (uint16_t*)(ws + OFF_HBA);
  uint16_t* hbB    = (uint16_t*)(ws + OFF_HBB);
  float*    out    = (float*)d_out;

  // ---- edge preprocessing: hist -> scan -> partition -> per-bucket CSR ----
  k_flag<<<1, 256, 0, stream>>>((const uint32_t*)ei, flag);
  hipMemsetAsync(bcnt, 0, NBUK * sizeof(int), stream);
  k_hist<<<2048, 256, 0, stream>>>(ei, flag, bcnt);
  k_bscan<<<1, 64, 0, stream>>>(bcnt, bbase, bcur, offs);
  k_part<<<(N_EDGES + PCHUNK - 1) / PCHUNK, 256, 0, stream>>>(ei, flag, bcur, part);
  k_bucket<<<NBUK, 256, 0, stream>>>(part, bbase, offs, dinv, sedge);

  // ---- weight packing ----
  k_packW<<<16, 256, 0, stream>>>(W0, wpk0, IN_CH);
  k_packW<<<8, 256, 0, stream>>>(W1, wpk1, HID);
  k_packW<<<8, 256, 0, stream>>>(W2, wpk2, HID);
  k_packW<<<16, 256, 0, stream>>>(Wr, wpkr, IN_CH);

  // ---- layer 0: fused dual GEMM (x@W0 -> int8, x@Wr -> bf16 residual) ----
  k_gemm0<<<GEMM_GRID, 256, 0, stream>>>(x, wpk0, wpkr, h8, dsc, dinv, resB);
  k_agg<<<25000, 256, 0, stream>>>(h8, dsc, sedge, offs, dinv, b0, g0, be0, resB, nullptr, hbA);

  // ---- layer 1 ----
  k_gemm8<<<GEMM_GRID, 256, 0, stream>>>(hbA, wpk1, h8, dsc, dinv);
  k_agg<<<25000, 256, 0, stream>>>(h8, dsc, sedge, offs, dinv, b1, g1, be1, hbA, nullptr, hbB);

  // ---- layer 2 (writes d_out f32) ----
  k_gemm8<<<GEMM_GRID, 256, 0, stream>>>(hbB, wpk2, h8, dsc, dinv);
  k_agg<<<25000, 256, 0, stream>>>(h8, dsc, sedge, offs, dinv, b2, g2, be2, hbB, out, nullptr);

  (void)in_sizes; (void)n_in; (void)out_size; (void)ws_size;
}

// Round 6
// 527.551 us; speedup vs baseline: 1.7836x; 1.1290x over previous
//
#include <hip/hip_runtime.h>
#include <hip/hip_bf16.h>
#include <stdint.h>

#define N_NODES 100000
#define N_EDGES 3200000
#define IN_CH 256
#define HID 128
#define EPS 1e-5f
#define BSH 9              // bucket = dst >> 9  (512 nodes per bucket)
#define NBUK 196           // ceil(100000/512)
#define PCHUNK 4096
#define GEMM_GRID 782      // ceil(100000/128)
#define SEGSH 14           // src segment = src >> 14  (16384 nodes = 2MB of H8)

using bf16x8 = __attribute__((ext_vector_type(8))) short;
using f32x4  = __attribute__((ext_vector_type(4))) float;

__device__ __forceinline__ uint32_t f2bf(float f) {
  uint32_t u = __float_as_uint(f);
  return (u + 0x7FFFu + ((u >> 16) & 1u)) >> 16;
}
__device__ __forceinline__ float bflo(uint32_t u) { return __uint_as_float(u << 16); }
__device__ __forceinline__ float bfhi(uint32_t u) { return __uint_as_float(u & 0xFFFF0000u); }

// ---- workspace layout (bytes), all 128-aligned ----
static const size_t OFF_SRC   = 0;            // int[3.2M] = 12,800,000 (CSR src)
static const size_t OFF_OFFS  = 12800000;     // int[100001]
static const size_t OFF_DINV  = 13200128;     // float[100000]
static const size_t OFF_DSC   = 13600128;     // float[100000]
static const size_t OFF_WPK0  = 14000128;     // 65,536
static const size_t OFF_WPK1  = 14065664;     // 32,768
static const size_t OFF_WPK2  = 14098432;     // 32,768
static const size_t OFF_WPKR  = 14131200;     // 65,536
static const size_t OFF_FLAG  = 14196736;     // int (+pad)
static const size_t OFF_BCNT  = 14196864;     // int[NBUK]
static const size_t OFF_BBASE = 14197888;     // int[NBUK+1]
static const size_t OFF_BCUR  = 14198912;     // int[NBUK]
static const size_t OFF_H8    = 14200064;     // u8[100000*128] = 12,800,000
static const size_t OFF_PART  = 14200064;     // int2[3.2M] = 25.6MB (aliases H8+resB head; dead before GEMM)
static const size_t OFF_RESB  = 27000064;     // bf16[100000*128] = 25,600,000
static const size_t OFF_HBA   = 52600064;     // bf16[100000*128]
static const size_t OFF_HBB   = 78200064;     // bf16[100000*128]  (end ~103.8MB)

// ---- edge dtype detection: int64 edges have zero high words ----
__global__ void k_flag(const uint32_t* __restrict__ e, int* flag) {
  __shared__ int any;
  if (threadIdx.x == 0) any = 0;
  __syncthreads();
  uint32_t acc = 0;
  for (int i = threadIdx.x; i < 2048; i += blockDim.x) acc |= e[2 * i + 1];
  if (acc) atomicOr(&any, 1);
  __syncthreads();
  if (threadIdx.x == 0) *flag = (any == 0) ? 1 : 0;  // 1 => int64 layout
}

// ---- bucket histogram (LDS-aggregated) ----
__global__ __launch_bounds__(256) void k_hist(const void* __restrict__ eidx,
                                              const int* __restrict__ flag,
                                              int* __restrict__ bcnt) {
  __shared__ int h[NBUK];
  for (int t = threadIdx.x; t < NBUK; t += 256) h[t] = 0;
  __syncthreads();
  bool i64 = (*flag != 0);
  int stride = gridDim.x * blockDim.x;
  for (int e = blockIdx.x * blockDim.x + threadIdx.x; e < N_EDGES; e += stride) {
    int d = i64 ? (int)((const uint32_t*)eidx)[2 * ((size_t)N_EDGES + e)]
                : ((const int*)eidx)[N_EDGES + e];
    atomicAdd(&h[d >> BSH], 1);
  }
  __syncthreads();
  for (int t = threadIdx.x; t < NBUK; t += 256)
    if (h[t]) atomicAdd(&bcnt[t], h[t]);
}

// ---- serial bucket scan (196 elems) ----
__global__ void k_bscan(const int* __restrict__ bcnt, int* __restrict__ bbase,
                        int* __restrict__ bcur, int* __restrict__ offs) {
  if (threadIdx.x == 0 && blockIdx.x == 0) {
    int run = 0;
    for (int b = 0; b < NBUK; ++b) {
      bbase[b] = run;
      bcur[b] = run;
      run += bcnt[b];
    }
    bbase[NBUK] = run;
    offs[N_NODES] = run;
  }
}

// ---- LDS-staged partition into buckets (coalesced writes) ----
__global__ __launch_bounds__(256) void k_part(const void* __restrict__ eidx,
                                              const int* __restrict__ flag,
                                              int* __restrict__ bcur,
                                              int2* __restrict__ part) {
  __shared__ int lhist[NBUK];
  __shared__ int lbase[NBUK];
  __shared__ int gbase[NBUK];
  __shared__ int sm[256];
  __shared__ int2 sbuf[PCHUNK];
  __shared__ uint8_t bbuf[PCHUNK];
  int tid = threadIdx.x;
  int base = blockIdx.x * PCHUNK;
  int nE = N_EDGES - base;
  if (nE > PCHUNK) nE = PCHUNK;
  for (int t = tid; t < NBUK; t += 256) lhist[t] = 0;
  __syncthreads();
  bool i64 = (*flag != 0);
  int es[16], ed[16], ml[16];
  #pragma unroll
  for (int k = 0; k < 16; ++k) {
    int ci = k * 256 + tid;
    if (ci < nE) {
      int e = base + ci;
      int s, d;
      if (i64) {
        const uint32_t* u = (const uint32_t*)eidx;
        s = (int)u[2 * (size_t)e];
        d = (int)u[2 * ((size_t)N_EDGES + e)];
      } else {
        const int* u = (const int*)eidx;
        s = u[e];
        d = u[N_EDGES + e];
      }
      es[k] = s; ed[k] = d;
      ml[k] = atomicAdd(&lhist[d >> BSH], 1);
    }
  }
  __syncthreads();
  sm[tid] = (tid < NBUK) ? lhist[tid] : 0;
  __syncthreads();
  for (int s = 1; s < 256; s <<= 1) {
    int t = (tid >= s) ? sm[tid - s] : 0;
    __syncthreads();
    sm[tid] += t;
    __syncthreads();
  }
  if (tid < NBUK) lbase[tid] = sm[tid] - lhist[tid];
  __syncthreads();
  #pragma unroll
  for (int k = 0; k < 16; ++k) {
    int ci = k * 256 + tid;
    if (ci < nE) {
      int b = ed[k] >> BSH;
      int slot = lbase[b] + ml[k];
      sbuf[slot] = make_int2(es[k], ed[k]);
      bbuf[slot] = (uint8_t)b;
    }
  }
  if (tid < NBUK && lhist[tid] > 0) gbase[tid] = atomicAdd(&bcur[tid], lhist[tid]);
  __syncthreads();
  for (int i = tid; i < nE; i += 256) {
    int b = bbuf[i];
    part[(size_t)gbase[b] + (i - lbase[b])] = sbuf[i];
  }
}

// ---- per-bucket: (dst,srcseg)-keyed counting sort -> offs/dinv + seg-grouped CSR ----
__global__ __launch_bounds__(256) void k_bucket(const int2* __restrict__ part,
                                                const int* __restrict__ bbase,
                                                int* __restrict__ offs,
                                                float* __restrict__ dinv,
                                                int* __restrict__ sedge) {
  __shared__ int cnt[4096];
  __shared__ int s2[256];
  int tid = threadIdx.x, b = blockIdx.x;
  int v0 = b << BSH;
  int e0 = bbase[b], e1 = bbase[b + 1];
  int tot = e1 - e0;
  for (int i = tid; i < 4096; i += 256) cnt[i] = 0;
  __syncthreads();
  for (int i = e0 + tid; i < e1; i += 256) {
    int2 e = part[i];
    atomicAdd(&cnt[((e.y - v0) << 3) | (e.x >> SEGSH)], 1);
  }
  __syncthreads();
  // exclusive scan of 4096 keys (16 per thread, contiguous)
  int loc[16];
  int base = tid * 16, sum = 0;
  #pragma unroll
  for (int k = 0; k < 16; ++k) { loc[k] = cnt[base + k]; sum += loc[k]; }
  s2[tid] = sum;
  __syncthreads();
  for (int s = 1; s < 256; s <<= 1) {
    int t = (tid >= s) ? s2[tid - s] : 0;
    __syncthreads();
    s2[tid] += t;
    __syncthreads();
  }
  int run = s2[tid] - sum;
  #pragma unroll
  for (int k = 0; k < 16; ++k) { cnt[base + k] = run; run += loc[k]; }
  __syncthreads();
  // offs/dinv (each thread covers 2 nodes)
  #pragma unroll
  for (int k = 0; k < 2; ++k) {
    int dloc = 2 * tid + k;
    int v = v0 + dloc;
    if (v < N_NODES) {
      int st = cnt[dloc << 3];
      int en = (dloc == 511) ? tot : cnt[(dloc + 1) << 3];
      offs[v] = e0 + st;
      dinv[v] = rsqrtf((float)(en - st + 1));
    }
  }
  __syncthreads();
  // scatter (cnt now serves as cursor)
  for (int i = e0 + tid; i < e1; i += 256) {
    int2 e = part[i];
    int key = ((e.y - v0) << 3) | (e.x >> SEGSH);
    int p = atomicAdd(&cnt[key], 1);
    sedge[e0 + p] = e.x;
  }
}

// pack W [K][HID] f32 row-major into MFMA B-fragment-ready bf16 layout
__global__ void k_packW(const float* __restrict__ W, uint16_t* __restrict__ Wp, int K) {
  int t = blockIdx.x * blockDim.x + threadIdx.x;
  int total = (K / 32) * 8 * 64;
  if (t >= total) return;
  int l = t & 63;
  int nt = (t >> 6) & 7;
  int ks = t >> 9;
  int kbase = ks * 32 + (l >> 4) * 8;
  int col = nt * 16 + (l & 15);
  #pragma unroll
  for (int j = 0; j < 8; ++j)
    Wp[(size_t)t * 8 + j] = (uint16_t)f2bf(W[(size_t)(kbase + j) * HID + col]);
}

// epilogue: quantize acc tiles to biased-uint8 rows + dsc (= scale * dinv), via LDS repack
__device__ __forceinline__ void epilogue_int8(const f32x4* acc, int l, int row0,
                                              uint8_t* lds_my,
                                              uint8_t* __restrict__ H8,
                                              float* __restrict__ dsc,
                                              const float* __restrict__ dinv) {
  float inv[4];
  #pragma unroll
  for (int j = 0; j < 4; ++j) {
    float m = 0.f;
    #pragma unroll
    for (int nt = 0; nt < 8; ++nt) m = fmaxf(m, fabsf(acc[nt][j]));
    #pragma unroll
    for (int s = 1; s < 16; s <<= 1) m = fmaxf(m, __shfl_xor(m, s, 64));
    m = fmaxf(m, 1e-20f);
    int r = row0 + (l >> 4) * 4 + j;
    if ((l & 15) == 0 && r < N_NODES) dsc[r] = m * (1.f / 127.f) * dinv[r];
    inv[j] = 127.f / m;
  }
  #pragma unroll
  for (int nt = 0; nt < 8; ++nt)
    #pragma unroll
    for (int j = 0; j < 4; ++j) {
      int r = (l >> 4) * 4 + j, c = nt * 16 + (l & 15);
      float q = rintf(acc[nt][j] * inv[j]) + 128.f;
      lds_my[r * 128 + (c ^ ((r & 7) << 2))] = (uint8_t)(int)q;  // 4B-granule swizzle by row
    }
  asm volatile("s_waitcnt lgkmcnt(0)" ::: "memory");
  int r = l >> 2;
  uint32_t w[8];
  #pragma unroll
  for (int t = 0; t < 8; ++t) {
    int c4 = (l & 3) * 8 + t;
    w[t] = *(const uint32_t*)(lds_my + r * 128 + ((c4 ^ (r & 7)) << 2));
  }
  if (row0 + r < N_NODES) {
    uint4* gp = (uint4*)(H8 + (size_t)(row0 + r) * 128 + (l & 3) * 32);
    gp[0] = make_uint4(w[0], w[1], w[2], w[3]);
    gp[1] = make_uint4(w[4], w[5], w[6], w[7]);
  }
}

// layer-0 fused dual GEMM: X f32 [N][256]: X@W0 -> int8+dsc, X@Wr -> bf16 residual
// Block = 4 waves x 32 rows = 128 rows. B staged in LDS in 2 K-phases (64 KB).
__global__ __launch_bounds__(256) void k_gemm0(const float* __restrict__ X,
                                               const uint16_t* __restrict__ Wp0,
                                               const uint16_t* __restrict__ WpR,
                                               uint8_t* __restrict__ H8,
                                               float* __restrict__ dsc,
                                               const float* __restrict__ dinv,
                                               uint16_t* __restrict__ resB) {
  __shared__ __align__(16) char smem[65536];
  int tid = threadIdx.x, wid = tid >> 6, l = tid & 63;
  int r0 = blockIdx.x * 128 + wid * 32;
  int hk = l >> 4, rl = l & 15;
  int ra0 = min(r0 + rl, N_NODES - 1);
  int ra1 = min(r0 + 16 + rl, N_NODES - 1);
  f32x4 acc0[2][8] = {}, accR[2][8] = {};
  #pragma unroll
  for (int kh = 0; kh < 2; ++kh) {
    __syncthreads();
    #pragma unroll
    for (int i = 0; i < 8; ++i) {
      int g = i * 256 + tid;
      *(uint4*)(smem + g * 16) =
          *(const uint4*)((const char*)Wp0 + kh * 32768 + g * 16);
      *(uint4*)(smem + 32768 + g * 16) =
          *(const uint4*)((const char*)WpR + kh * 32768 + g * 16);
    }
    __syncthreads();
    #pragma unroll
    for (int ksl = 0; ksl < 4; ++ksl) {
      int kof = kh * 128 + ksl * 32 + hk * 8;
      float4 u0 = *(const float4*)(X + (size_t)ra0 * 256 + kof);
      float4 u1 = *(const float4*)(X + (size_t)ra0 * 256 + kof + 4);
      float4 v0 = *(const float4*)(X + (size_t)ra1 * 256 + kof);
      float4 v1 = *(const float4*)(X + (size_t)ra1 * 256 + kof + 4);
      bf16x8 a0, a1;
      a0[0] = (short)f2bf(u0.x); a0[1] = (short)f2bf(u0.y);
      a0[2] = (short)f2bf(u0.z); a0[3] = (short)f2bf(u0.w);
      a0[4] = (short)f2bf(u1.x); a0[5] = (short)f2bf(u1.y);
      a0[6] = (short)f2bf(u1.z); a0[7] = (short)f2bf(u1.w);
      a1[0] = (short)f2bf(v0.x); a1[1] = (short)f2bf(v0.y);
      a1[2] = (short)f2bf(v0.z); a1[3] = (short)f2bf(v0.w);
      a1[4] = (short)f2bf(v1.x); a1[5] = (short)f2bf(v1.y);
      a1[6] = (short)f2bf(v1.z); a1[7] = (short)f2bf(v1.w);
      #pragma unroll
      for (int nt = 0; nt < 8; ++nt) {
        bf16x8 b0 = *(const bf16x8*)(smem + ((ksl * 8 + nt) * 64 + l) * 16);
        acc0[0][nt] = __builtin_amdgcn_mfma_f32_16x16x32_bf16(a0, b0, acc0[0][nt], 0, 0, 0);
        acc0[1][nt] = __builtin_amdgcn_mfma_f32_16x16x32_bf16(a1, b0, acc0[1][nt], 0, 0, 0);
        bf16x8 br = *(const bf16x8*)(smem + 32768 + ((ksl * 8 + nt) * 64 + l) * 16);
        accR[0][nt] = __builtin_amdgcn_mfma_f32_16x16x32_bf16(a0, br, accR[0][nt], 0, 0, 0);
        accR[1][nt] = __builtin_amdgcn_mfma_f32_16x16x32_bf16(a1, br, accR[1][nt], 0, 0, 0);
      }
    }
  }
  __syncthreads();  // B dead; smem becomes per-wave epilogue scratch
  uint8_t*  lds8 = (uint8_t*)(smem + wid * 16384);
  uint16_t* ldsb = (uint16_t*)(smem + wid * 16384 + 4096);
  #pragma unroll
  for (int rt = 0; rt < 2; ++rt) {
    int row0 = r0 + rt * 16;
    epilogue_int8(acc0[rt], l, row0, lds8, H8, dsc, dinv);
    #pragma unroll
    for (int nt = 0; nt < 8; ++nt)
      #pragma unroll
      for (int j = 0; j < 4; ++j)
        ldsb[((l >> 4) * 4 + j) * 128 + nt * 16 + (l & 15)] = (uint16_t)f2bf(accR[rt][nt][j]);
    asm volatile("s_waitcnt lgkmcnt(0)" ::: "memory");
    const uint4* sb = (const uint4*)ldsb;
    if (row0 + (l >> 2) < N_NODES) {
      uint4* gb = (uint4*)(resB + (size_t)(row0 + (l >> 2)) * 128 + (l & 3) * 32);
      #pragma unroll
      for (int t = 0; t < 4; ++t) gb[t] = sb[l * 4 + t];
    }
  }
}

// layers 1/2 GEMM: A bf16 [N][128] @ Wp(LDS-shared) -> int8+dsc
__global__ __launch_bounds__(256) void k_gemm8(const uint16_t* __restrict__ A,
                                               const uint16_t* __restrict__ Wp,
                                               uint8_t* __restrict__ H8,
                                               float* __restrict__ dsc,
                                               const float* __restrict__ dinv) {
  __shared__ __align__(16) char smem[32768];
  int tid = threadIdx.x, wid = tid >> 6, l = tid & 63;
  #pragma unroll
  for (int i = 0; i < 8; ++i) {
    int g = i * 256 + tid;
    *(uint4*)(smem + g * 16) = *(const uint4*)((const char*)Wp + g * 16);
  }
  __syncthreads();
  int r0 = blockIdx.x * 128 + wid * 32;
  int hk = l >> 4, rl = l & 15;
  int ra0 = min(r0 + rl, N_NODES - 1);
  int ra1 = min(r0 + 16 + rl, N_NODES - 1);
  f32x4 acc[2][8] = {};
  #pragma unroll
  for (int ks = 0; ks < 4; ++ks) {
    bf16x8 a0 = *(const bf16x8*)(A + (size_t)ra0 * 128 + ks * 32 + hk * 8);
    bf16x8 a1 = *(const bf16x8*)(A + (size_t)ra1 * 128 + ks * 32 + hk * 8);
    #pragma unroll
    for (int nt = 0; nt < 8; ++nt) {
      bf16x8 b = *(const bf16x8*)(smem + ((ks * 8 + nt) * 64 + l) * 16);
      acc[0][nt] = __builtin_amdgcn_mfma_f32_16x16x32_bf16(a0, b, acc[0][nt], 0, 0, 0);
      acc[1][nt] = __builtin_amdgcn_mfma_f32_16x16x32_bf16(a1, b, acc[1][nt], 0, 0, 0);
    }
  }
  __syncthreads();  // B dead; reuse as epilogue scratch
  uint8_t* lds8 = (uint8_t*)(smem + wid * 4096);
  epilogue_int8(acc[0], l, r0, lds8, H8, dsc, dinv);
  epilogue_int8(acc[1], l, r0 + 16, lds8, H8, dsc, dinv);
}

// fused: int8 gather-sum + bias + LN + ReLU + bf16 residual
// four 16-lane quarters: quarter q processes edges i%4==q; lane owns 8 channels (8B load)
__global__ __launch_bounds__(256) void k_agg(const uint8_t* __restrict__ H8,
                                             const float* __restrict__ dsc,
                                             const int* __restrict__ sedge,
                                             const int* __restrict__ offs,
                                             const float* __restrict__ dinv,
                                             const float* __restrict__ bias,
                                             const float* __restrict__ g,
                                             const float* __restrict__ be,
                                             const uint16_t* __restrict__ residB,
                                             float* __restrict__ outF,
                                             uint16_t* __restrict__ outB) {
  int wid = threadIdx.x >> 6, l = threadIdx.x & 63;
  int v = blockIdx.x * 4 + wid;
  if (v >= N_NODES) return;
  int q = l >> 4, c = l & 15;
  float a0 = 0.f, a1 = 0.f, a2 = 0.f, a3 = 0.f;
  float a4 = 0.f, a5 = 0.f, a6 = 0.f, a7 = 0.f, cs = 0.f;
  int p0 = offs[v], ne = offs[v + 1] - p0;
  int i = q;
  for (; i + 4 < ne; i += 8) {
    int s0 = sedge[p0 + i], s1 = sedge[p0 + i + 4];
    uint2 h0 = *(const uint2*)(H8 + (size_t)s0 * 128 + 8 * c);
    uint2 h1 = *(const uint2*)(H8 + (size_t)s1 * 128 + 8 * c);
    float w0 = dsc[s0], w1 = dsc[s1];
    cs += w0 + w1;
    a0 += w0 * (float)(h0.x & 0xFFu)         + w1 * (float)(h1.x & 0xFFu);
    a1 += w0 * (float)((h0.x >> 8) & 0xFFu)  + w1 * (float)((h1.x >> 8) & 0xFFu);
    a2 += w0 * (float)((h0.x >> 16) & 0xFFu) + w1 * (float)((h1.x >> 16) & 0xFFu);
    a3 += w0 * (float)(h0.x >> 24)           + w1 * (float)(h1.x >> 24);
    a4 += w0 * (float)(h0.y & 0xFFu)         + w1 * (float)(h1.y & 0xFFu);
    a5 += w0 * (float)((h0.y >> 8) & 0xFFu)  + w1 * (float)((h1.y >> 8) & 0xFFu);
    a6 += w0 * (float)((h0.y >> 16) & 0xFFu) + w1 * (float)((h1.y >> 16) & 0xFFu);
    a7 += w0 * (float)(h0.y >> 24)           + w1 * (float)(h1.y >> 24);
  }
  for (; i < ne; i += 4) {
    int s0 = sedge[p0 + i];
    uint2 h0 = *(const uint2*)(H8 + (size_t)s0 * 128 + 8 * c);
    float w0 = dsc[s0];
    cs += w0;
    a0 += w0 * (float)(h0.x & 0xFFu);
    a1 += w0 * (float)((h0.x >> 8) & 0xFFu);
    a2 += w0 * (float)((h0.x >> 16) & 0xFFu);
    a3 += w0 * (float)(h0.x >> 24);
    a4 += w0 * (float)(h0.y & 0xFFu);
    a5 += w0 * (float)((h0.y >> 8) & 0xFFu);
    a6 += w0 * (float)((h0.y >> 16) & 0xFFu);
    a7 += w0 * (float)(h0.y >> 24);
  }
  // combine the 4 quarters
  #pragma unroll
  for (int m = 16; m <= 32; m <<= 1) {
    a0 += __shfl_xor(a0, m, 64); a1 += __shfl_xor(a1, m, 64);
    a2 += __shfl_xor(a2, m, 64); a3 += __shfl_xor(a3, m, 64);
    a4 += __shfl_xor(a4, m, 64); a5 += __shfl_xor(a5, m, 64);
    a6 += __shfl_xor(a6, m, 64); a7 += __shfl_xor(a7, m, 64);
    cs += __shfl_xor(cs, m, 64);
  }
  float dv = dinv[v];
  float bc = 128.f * cs;
  a0 = dv * (a0 - bc); a1 = dv * (a1 - bc); a2 = dv * (a2 - bc); a3 = dv * (a3 - bc);
  a4 = dv * (a4 - bc); a5 = dv * (a5 - bc); a6 = dv * (a6 - bc); a7 = dv * (a7 - bc);
  {  // self loop
    uint2 h = *(const uint2*)(H8 + (size_t)v * 128 + 8 * c);
    float wss = dv * dsc[v];
    a0 += wss * ((float)(h.x & 0xFFu) - 128.f);
    a1 += wss * ((float)((h.x >> 8) & 0xFFu) - 128.f);
    a2 += wss * ((float)((h.x >> 16) & 0xFFu) - 128.f);
    a3 += wss * ((float)(h.x >> 24) - 128.f);
    a4 += wss * ((float)(h.y & 0xFFu) - 128.f);
    a5 += wss * ((float)((h.y >> 8) & 0xFFu) - 128.f);
    a6 += wss * ((float)((h.y >> 16) & 0xFFu) - 128.f);
    a7 += wss * ((float)(h.y >> 24) - 128.f);
  }
  float4 bb0 = *(const float4*)(bias + 8 * c);
  float4 bb1 = *(const float4*)(bias + 8 * c + 4);
  a0 += bb0.x; a1 += bb0.y; a2 += bb0.z; a3 += bb0.w;
  a4 += bb1.x; a5 += bb1.y; a6 += bb1.z; a7 += bb1.w;
  // LayerNorm over 128 channels (16-lane reduction, replicated across quarters)
  float s = a0 + a1 + a2 + a3 + a4 + a5 + a6 + a7;
  #pragma unroll
  for (int m = 1; m < 16; m <<= 1) s += __shfl_xor(s, m, 64);
  float mu = s * (1.f / 128.f);
  float d0 = a0 - mu, d1 = a1 - mu, d2 = a2 - mu, d3 = a3 - mu;
  float d4 = a4 - mu, d5 = a5 - mu, d6 = a6 - mu, d7 = a7 - mu;
  float qq = d0 * d0 + d1 * d1 + d2 * d2 + d3 * d3 +
             d4 * d4 + d5 * d5 + d6 * d6 + d7 * d7;
  #pragma unroll
  for (int m = 1; m < 16; m <<= 1) qq += __shfl_xor(qq, m, 64);
  float rs = rsqrtf(qq * (1.f / 128.f) + EPS);
  float4 gg0 = *(const float4*)(g + 8 * c);
  float4 gg1 = *(const float4*)(g + 8 * c + 4);
  float4 ee0 = *(const float4*)(be + 8 * c);
  float4 ee1 = *(const float4*)(be + 8 * c + 4);
  float y0 = fmaxf(d0 * rs * gg0.x + ee0.x, 0.f);
  float y1 = fmaxf(d1 * rs * gg0.y + ee0.y, 0.f);
  float y2 = fmaxf(d2 * rs * gg0.z + ee0.z, 0.f);
  float y3 = fmaxf(d3 * rs * gg0.w + ee0.w, 0.f);
  float y4 = fmaxf(d4 * rs * gg1.x + ee1.x, 0.f);
  float y5 = fmaxf(d5 * rs * gg1.y + ee1.y, 0.f);
  float y6 = fmaxf(d6 * rs * gg1.z + ee1.z, 0.f);
  float y7 = fmaxf(d7 * rs * gg1.w + ee1.w, 0.f);
  uint4 rr = *(const uint4*)(residB + (size_t)v * 128 + 8 * c);
  y0 += bflo(rr.x); y1 += bfhi(rr.x);
  y2 += bflo(rr.y); y3 += bfhi(rr.y);
  y4 += bflo(rr.z); y5 += bfhi(rr.z);
  y6 += bflo(rr.w); y7 += bfhi(rr.w);
  if (q == 0) {
    if (outF) {
      float* op = outF + (size_t)v * HID + 8 * c;
      *(float4*)op = make_float4(y0, y1, y2, y3);
      *(float4*)(op + 4) = make_float4(y4, y5, y6, y7);
    }
    if (outB) {
      uint4 o;
      o.x = f2bf(y0) | (f2bf(y1) << 16);
      o.y = f2bf(y2) | (f2bf(y3) << 16);
      o.z = f2bf(y4) | (f2bf(y5) << 16);
      o.w = f2bf(y6) | (f2bf(y7) << 16);
      *(uint4*)(outB + (size_t)v * 128 + 8 * c) = o;
    }
  }
}

extern "C" void kernel_launch(void* const* d_in, const int* in_sizes, int n_in,
                              void* d_out, int out_size, void* d_ws, size_t ws_size,
                              hipStream_t stream) {
  const float* x   = (const float*)d_in[0];
  const void*  ei  = d_in[1];
  const float* W0  = (const float*)d_in[2];
  const float* b0  = (const float*)d_in[3];
  const float* g0  = (const float*)d_in[4];
  const float* be0 = (const float*)d_in[5];
  const float* W1  = (const float*)d_in[6];
  const float* b1  = (const float*)d_in[7];
  const float* g1  = (const float*)d_in[8];
  const float* be1 = (const float*)d_in[9];
  const float* W2  = (const float*)d_in[10];
  const float* b2  = (const float*)d_in[11];
  const float* g2  = (const float*)d_in[12];
  const float* be2 = (const float*)d_in[13];
  const float* Wr  = (const float*)d_in[14];

  char* ws = (char*)d_ws;
  int*      sedge  = (int*)(ws + OFF_SRC);
  int*      offs   = (int*)(ws + OFF_OFFS);
  float*    dinv   = (float*)(ws + OFF_DINV);
  float*    dsc    = (float*)(ws + OFF_DSC);
  uint16_t* wpk0   = (uint16_t*)(ws + OFF_WPK0);
  uint16_t* wpk1   = (uint16_t*)(ws + OFF_WPK1);
  uint16_t* wpk2   = (uint16_t*)(ws + OFF_WPK2);
  uint16_t* wpkr   = (uint16_t*)(ws + OFF_WPKR);
  int*      flag   = (int*)(ws + OFF_FLAG);
  int*      bcnt   = (int*)(ws + OFF_BCNT);
  int*      bbase  = (int*)(ws + OFF_BBASE);
  int*      bcur   = (int*)(ws + OFF_BCUR);
  uint8_t*  h8     = (uint8_t*)(ws + OFF_H8);
  int2*     part   = (int2*)(ws + OFF_PART);
  uint16_t* resB   = (uint16_t*)(ws + OFF_RESB);
  uint16_t* hbA    = (uint16_t*)(ws + OFF_HBA);
  uint16_t* hbB    = (uint16_t*)(ws + OFF_HBB);
  float*    out    = (float*)d_out;

  // ---- edge preprocessing: hist -> scan -> partition -> per-bucket CSR ----
  k_flag<<<1, 256, 0, stream>>>((const uint32_t*)ei, flag);
  hipMemsetAsync(bcnt, 0, NBUK * sizeof(int), stream);
  k_hist<<<2048, 256, 0, stream>>>(ei, flag, bcnt);
  k_bscan<<<1, 64, 0, stream>>>(bcnt, bbase, bcur, offs);
  k_part<<<(N_EDGES + PCHUNK - 1) / PCHUNK, 256, 0, stream>>>(ei, flag, bcur, part);
  k_bucket<<<NBUK, 256, 0, stream>>>(part, bbase, offs, dinv, sedge);

  // ---- weight packing ----
  k_packW<<<16, 256, 0, stream>>>(W0, wpk0, IN_CH);
  k_packW<<<8, 256, 0, stream>>>(W1, wpk1, HID);
  k_packW<<<8, 256, 0, stream>>>(W2, wpk2, HID);
  k_packW<<<16, 256, 0, stream>>>(Wr, wpkr, IN_CH);

  // ---- layer 0: fused dual GEMM (x@W0 -> int8, x@Wr -> bf16 residual) ----
  k_gemm0<<<GEMM_GRID, 256, 0, stream>>>(x, wpk0, wpkr, h8, dsc, dinv, resB);
  k_agg<<<25000, 256, 0, stream>>>(h8, dsc, sedge, offs, dinv, b0, g0, be0, resB, nullptr, hbA);

  // ---- layer 1 ----
  k_gemm8<<<GEMM_GRID, 256, 0, stream>>>(hbA, wpk1, h8, dsc, dinv);
  k_agg<<<25000, 256, 0, stream>>>(h8, dsc, sedge, offs, dinv, b1, g1, be1, hbA, nullptr, hbB);

  // ---- layer 2 (writes d_out f32) ----
  k_gemm8<<<GEMM_GRID, 256, 0, stream>>>(hbB, wpk2, h8, dsc, dinv);
  k_agg<<<25000, 256, 0, stream>>>(h8, dsc, sedge, offs, dinv, b2, g2, be2, hbB, out, nullptr);

  (void)in_sizes; (void)n_in; (void)out_size; (void)ws_size;
}

// Round 7
// 513.128 us; speedup vs baseline: 1.8338x; 1.0281x over previous
//
#include <hip/hip_runtime.h>
#include <hip/hip_bf16.h>
#include <stdint.h>

#define N_NODES 100000
#define N_EDGES 3200000
#define IN_CH 256
#define HID 128
#define EPS 1e-5f
#define BSH 9              // bucket = dst >> 9  (512 nodes per bucket)
#define NBUK 196           // ceil(100000/512)
#define PCHUNK 4096
#define GEMM_GRID 782      // ceil(100000/128)

using bf16x8 = __attribute__((ext_vector_type(8))) short;
using f32x4  = __attribute__((ext_vector_type(4))) float;

__device__ __forceinline__ uint32_t f2bf(float f) {
  uint32_t u = __float_as_uint(f);
  return (u + 0x7FFFu + ((u >> 16) & 1u)) >> 16;
}
__device__ __forceinline__ float bflo(uint32_t u) { return __uint_as_float(u << 16); }
__device__ __forceinline__ float bfhi(uint32_t u) { return __uint_as_float(u & 0xFFFF0000u); }

// ---- workspace layout (bytes), all 128-aligned ----
static const size_t OFF_SRC   = 0;            // int[3,600,000] padded CSR src = 14,400,000
static const size_t OFF_OFFS  = 14400000;     // int[100001]
static const size_t OFF_DINV  = 14800128;     // float[100000]
static const size_t OFF_DSC   = 15200128;     // float[100001]
static const size_t OFF_CNTG  = 15600256;     // int[100000]
static const size_t OFF_WPK0  = 16000256;     // 65,536
static const size_t OFF_WPK1  = 16065792;     // 32,768
static const size_t OFF_WPK2  = 16098560;     // 32,768
static const size_t OFF_WPKR  = 16131328;     // 65,536
static const size_t OFF_FLAG  = 16196864;     // int (+pad)
static const size_t OFF_BCNT  = 16196992;     // int[NBUK]
static const size_t OFF_BBASE = 16198016;     // int[NBUK+1]
static const size_t OFF_BCUR  = 16199040;     // int[NBUK]
static const size_t OFF_PTOT  = 16200064;     // int[NBUK]
static const size_t OFF_PBASE = 16201088;     // int[NBUK+1]
static const size_t OFF_H8    = 16202240;     // u8[100001*128] = 12,800,128
static const size_t OFF_PART  = 16202240;     // int2[3.2M] = 25.6MB (aliases H8; dead before GEMM)
static const size_t OFF_RESB  = 41802240;     // bf16[100000*128] = 25,600,000
static const size_t OFF_HBA   = 67402240;     // bf16[100000*128]
static const size_t OFF_HBB   = 93002240;     // bf16[100000*128]  (end ~118.6MB)

// ---- edge dtype detection: int64 edges have zero high words ----
__global__ void k_flag(const uint32_t* __restrict__ e, int* flag) {
  __shared__ int any;
  if (threadIdx.x == 0) any = 0;
  __syncthreads();
  uint32_t acc = 0;
  for (int i = threadIdx.x; i < 2048; i += blockDim.x) acc |= e[2 * i + 1];
  if (acc) atomicOr(&any, 1);
  __syncthreads();
  if (threadIdx.x == 0) *flag = (any == 0) ? 1 : 0;  // 1 => int64 layout
}

// ---- bucket histogram (LDS-aggregated) ----
__global__ __launch_bounds__(256) void k_hist(const void* __restrict__ eidx,
                                              const int* __restrict__ flag,
                                              int* __restrict__ bcnt) {
  __shared__ int h[NBUK];
  for (int t = threadIdx.x; t < NBUK; t += 256) h[t] = 0;
  __syncthreads();
  bool i64 = (*flag != 0);
  int stride = gridDim.x * blockDim.x;
  for (int e = blockIdx.x * blockDim.x + threadIdx.x; e < N_EDGES; e += stride) {
    int d = i64 ? (int)((const uint32_t*)eidx)[2 * ((size_t)N_EDGES + e)]
                : ((const int*)eidx)[N_EDGES + e];
    atomicAdd(&h[d >> BSH], 1);
  }
  __syncthreads();
  for (int t = threadIdx.x; t < NBUK; t += 256)
    if (h[t]) atomicAdd(&bcnt[t], h[t]);
}

// ---- serial bucket scan (196 elems) ----
__global__ void k_bscan(const int* __restrict__ bcnt, int* __restrict__ bbase,
                        int* __restrict__ bcur) {
  if (threadIdx.x == 0 && blockIdx.x == 0) {
    int run = 0;
    for (int b = 0; b < NBUK; ++b) {
      bbase[b] = run;
      bcur[b] = run;
      run += bcnt[b];
    }
    bbase[NBUK] = run;
  }
}

// ---- LDS-staged partition into buckets (coalesced writes) ----
__global__ __launch_bounds__(256) void k_part(const void* __restrict__ eidx,
                                              const int* __restrict__ flag,
                                              int* __restrict__ bcur,
                                              int2* __restrict__ part) {
  __shared__ int lhist[NBUK];
  __shared__ int lbase[NBUK];
  __shared__ int gbase[NBUK];
  __shared__ int sm[256];
  __shared__ int2 sbuf[PCHUNK];
  __shared__ uint8_t bbuf[PCHUNK];
  int tid = threadIdx.x;
  int base = blockIdx.x * PCHUNK;
  int nE = N_EDGES - base;
  if (nE > PCHUNK) nE = PCHUNK;
  for (int t = tid; t < NBUK; t += 256) lhist[t] = 0;
  __syncthreads();
  bool i64 = (*flag != 0);
  int es[16], ed[16], ml[16];
  #pragma unroll
  for (int k = 0; k < 16; ++k) {
    int ci = k * 256 + tid;
    if (ci < nE) {
      int e = base + ci;
      int s, d;
      if (i64) {
        const uint32_t* u = (const uint32_t*)eidx;
        s = (int)u[2 * (size_t)e];
        d = (int)u[2 * ((size_t)N_EDGES + e)];
      } else {
        const int* u = (const int*)eidx;
        s = u[e];
        d = u[N_EDGES + e];
      }
      es[k] = s; ed[k] = d;
      ml[k] = atomicAdd(&lhist[d >> BSH], 1);
    }
  }
  __syncthreads();
  sm[tid] = (tid < NBUK) ? lhist[tid] : 0;
  __syncthreads();
  for (int s = 1; s < 256; s <<= 1) {
    int t = (tid >= s) ? sm[tid - s] : 0;
    __syncthreads();
    sm[tid] += t;
    __syncthreads();
  }
  if (tid < NBUK) lbase[tid] = sm[tid] - lhist[tid];
  __syncthreads();
  #pragma unroll
  for (int k = 0; k < 16; ++k) {
    int ci = k * 256 + tid;
    if (ci < nE) {
      int b = ed[k] >> BSH;
      int slot = lbase[b] + ml[k];
      sbuf[slot] = make_int2(es[k], ed[k]);
      bbuf[slot] = (uint8_t)b;
    }
  }
  if (tid < NBUK && lhist[tid] > 0) gbase[tid] = atomicAdd(&bcur[tid], lhist[tid]);
  __syncthreads();
  for (int i = tid; i < nE; i += 256) {
    int b = bbuf[i];
    part[(size_t)gbase[b] + (i - lbase[b])] = sbuf[i];
  }
}

// ---- bucketA: per-node exact counts + dinv + padded bucket totals ----
__global__ __launch_bounds__(256) void k_bucketA(const int2* __restrict__ part,
                                                 const int* __restrict__ bbase,
                                                 int* __restrict__ cntg,
                                                 float* __restrict__ dinv,
                                                 int* __restrict__ ptot) {
  __shared__ int cnt[512];
  __shared__ int s2[256];
  int tid = threadIdx.x, b = blockIdx.x;
  int v0 = b << BSH;
  int e0 = bbase[b], e1 = bbase[b + 1];
  cnt[tid] = 0; cnt[tid + 256] = 0;
  __syncthreads();
  for (int i = e0 + tid; i < e1; i += 256) atomicAdd(&cnt[part[i].y - v0], 1);
  __syncthreads();
  int pa = (cnt[2 * tid] + 3) & ~3, pb = (cnt[2 * tid + 1] + 3) & ~3;
  s2[tid] = pa + pb;
  __syncthreads();
  for (int s = 128; s > 0; s >>= 1) {
    if (tid < s) s2[tid] += s2[tid + s];
    __syncthreads();
  }
  if (tid == 0) ptot[b] = s2[0];
  #pragma unroll
  for (int k = 0; k < 2; ++k) {
    int t = tid + k * 256, v = v0 + t;
    if (v < N_NODES) {
      cntg[v] = cnt[t];
      dinv[v] = rsqrtf((float)(cnt[t] + 1));
    }
  }
}

// ---- serial padded-base scan; also init sentinel dsc ----
__global__ void k_bscan2(const int* __restrict__ ptot, int* __restrict__ pbase,
                         int* __restrict__ offs, float* __restrict__ dsc) {
  if (threadIdx.x == 0 && blockIdx.x == 0) {
    int run = 0;
    for (int b = 0; b < NBUK; ++b) { pbase[b] = run; run += ptot[b]; }
    pbase[NBUK] = run;
    offs[N_NODES] = run;
    dsc[N_NODES] = 0.f;   // sentinel row weight
  }
}

// ---- bucketB: padded offs + scatter + sentinel pad fill ----
__global__ __launch_bounds__(256) void k_bucketB(const int2* __restrict__ part,
                                                 const int* __restrict__ bbase,
                                                 const int* __restrict__ pbase,
                                                 const int* __restrict__ cntg,
                                                 int* __restrict__ offs,
                                                 int* __restrict__ sedge) {
  __shared__ int pre[512];
  __shared__ int cur[512];
  __shared__ int s2[256];
  int tid = threadIdx.x, b = blockIdx.x;
  int v0 = b << BSH;
  int e0 = bbase[b], e1 = bbase[b + 1];
  int e0p = pbase[b];
  int c0 = (v0 + 2 * tid < N_NODES) ? cntg[v0 + 2 * tid] : 0;
  int c1 = (v0 + 2 * tid + 1 < N_NODES) ? cntg[v0 + 2 * tid + 1] : 0;
  int pa = (c0 + 3) & ~3, pb = (c1 + 3) & ~3;
  s2[tid] = pa + pb;
  __syncthreads();
  for (int s = 1; s < 256; s <<= 1) {
    int t = (tid >= s) ? s2[tid - s] : 0;
    __syncthreads();
    s2[tid] += t;
    __syncthreads();
  }
  int eb = s2[tid] - (pa + pb);
  pre[2 * tid] = eb;       cur[2 * tid] = eb;
  pre[2 * tid + 1] = eb + pa; cur[2 * tid + 1] = eb + pa;
  __syncthreads();
  #pragma unroll
  for (int k = 0; k < 2; ++k) {
    int t = tid + k * 256, v = v0 + t;
    if (v < N_NODES) offs[v] = e0p + pre[t];
  }
  for (int i = e0 + tid; i < e1; i += 256) {
    int2 e = part[i];
    int p = atomicAdd(&cur[e.y - v0], 1);
    sedge[e0p + p] = e.x;
  }
  __syncthreads();
  // pad fill: cur[t] == pre[t] + exact count
  #pragma unroll
  for (int k = 0; k < 2; ++k) {
    int t = tid + k * 256, v = v0 + t;
    if (v < N_NODES) {
      int endx = cur[t];
      int endp = pre[t] + ((endx - pre[t] + 3) & ~3);
      for (int u = endx; u < endp; ++u) sedge[e0p + u] = N_NODES;
    }
  }
}

// pack W [K][HID] f32 row-major into MFMA B-fragment-ready bf16 layout
__global__ void k_packW(const float* __restrict__ W, uint16_t* __restrict__ Wp, int K) {
  int t = blockIdx.x * blockDim.x + threadIdx.x;
  int total = (K / 32) * 8 * 64;
  if (t >= total) return;
  int l = t & 63;
  int nt = (t >> 6) & 7;
  int ks = t >> 9;
  int kbase = ks * 32 + (l >> 4) * 8;
  int col = nt * 16 + (l & 15);
  #pragma unroll
  for (int j = 0; j < 8; ++j)
    Wp[(size_t)t * 8 + j] = (uint16_t)f2bf(W[(size_t)(kbase + j) * HID + col]);
}

// epilogue: quantize acc tiles to biased-uint8 rows + dsc (= scale * dinv), via LDS repack
__device__ __forceinline__ void epilogue_int8(const f32x4* acc, int l, int row0,
                                              uint8_t* lds_my,
                                              uint8_t* __restrict__ H8,
                                              float* __restrict__ dsc,
                                              const float* __restrict__ dinv) {
  float inv[4];
  #pragma unroll
  for (int j = 0; j < 4; ++j) {
    float m = 0.f;
    #pragma unroll
    for (int nt = 0; nt < 8; ++nt) m = fmaxf(m, fabsf(acc[nt][j]));
    #pragma unroll
    for (int s = 1; s < 16; s <<= 1) m = fmaxf(m, __shfl_xor(m, s, 64));
    m = fmaxf(m, 1e-20f);
    int r = row0 + (l >> 4) * 4 + j;
    if ((l & 15) == 0 && r < N_NODES) dsc[r] = m * (1.f / 127.f) * dinv[r];
    inv[j] = 127.f / m;
  }
  #pragma unroll
  for (int nt = 0; nt < 8; ++nt)
    #pragma unroll
    for (int j = 0; j < 4; ++j) {
      int r = (l >> 4) * 4 + j, c = nt * 16 + (l & 15);
      float q = rintf(acc[nt][j] * inv[j]) + 128.f;
      lds_my[r * 128 + (c ^ ((r & 7) << 2))] = (uint8_t)(int)q;  // 4B-granule swizzle by row
    }
  asm volatile("s_waitcnt lgkmcnt(0)" ::: "memory");
  int r = l >> 2;
  uint32_t w[8];
  #pragma unroll
  for (int t = 0; t < 8; ++t) {
    int c4 = (l & 3) * 8 + t;
    w[t] = *(const uint32_t*)(lds_my + r * 128 + ((c4 ^ (r & 7)) << 2));
  }
  if (row0 + r < N_NODES) {
    uint4* gp = (uint4*)(H8 + (size_t)(row0 + r) * 128 + (l & 3) * 32);
    gp[0] = make_uint4(w[0], w[1], w[2], w[3]);
    gp[1] = make_uint4(w[4], w[5], w[6], w[7]);
  }
}

// layer-0 fused dual GEMM: X f32 [N][256]: X@W0 -> int8+dsc, X@Wr -> bf16 residual
__global__ __launch_bounds__(256) void k_gemm0(const float* __restrict__ X,
                                               const uint16_t* __restrict__ Wp0,
                                               const uint16_t* __restrict__ WpR,
                                               uint8_t* __restrict__ H8,
                                               float* __restrict__ dsc,
                                               const float* __restrict__ dinv,
                                               uint16_t* __restrict__ resB) {
  __shared__ __align__(16) char smem[65536];
  int tid = threadIdx.x, wid = tid >> 6, l = tid & 63;
  int r0 = blockIdx.x * 128 + wid * 32;
  int hk = l >> 4, rl = l & 15;
  int ra0 = min(r0 + rl, N_NODES - 1);
  int ra1 = min(r0 + 16 + rl, N_NODES - 1);
  f32x4 acc0[2][8] = {}, accR[2][8] = {};
  #pragma unroll
  for (int kh = 0; kh < 2; ++kh) {
    __syncthreads();
    #pragma unroll
    for (int i = 0; i < 8; ++i) {
      int g = i * 256 + tid;
      *(uint4*)(smem + g * 16) =
          *(const uint4*)((const char*)Wp0 + kh * 32768 + g * 16);
      *(uint4*)(smem + 32768 + g * 16) =
          *(const uint4*)((const char*)WpR + kh * 32768 + g * 16);
    }
    __syncthreads();
    #pragma unroll
    for (int ksl = 0; ksl < 4; ++ksl) {
      int kof = kh * 128 + ksl * 32 + hk * 8;
      float4 u0 = *(const float4*)(X + (size_t)ra0 * 256 + kof);
      float4 u1 = *(const float4*)(X + (size_t)ra0 * 256 + kof + 4);
      float4 v0 = *(const float4*)(X + (size_t)ra1 * 256 + kof);
      float4 v1 = *(const float4*)(X + (size_t)ra1 * 256 + kof + 4);
      bf16x8 a0, a1;
      a0[0] = (short)f2bf(u0.x); a0[1] = (short)f2bf(u0.y);
      a0[2] = (short)f2bf(u0.z); a0[3] = (short)f2bf(u0.w);
      a0[4] = (short)f2bf(u1.x); a0[5] = (short)f2bf(u1.y);
      a0[6] = (short)f2bf(u1.z); a0[7] = (short)f2bf(u1.w);
      a1[0] = (short)f2bf(v0.x); a1[1] = (short)f2bf(v0.y);
      a1[2] = (short)f2bf(v0.z); a1[3] = (short)f2bf(v0.w);
      a1[4] = (short)f2bf(v1.x); a1[5] = (short)f2bf(v1.y);
      a1[6] = (short)f2bf(v1.z); a1[7] = (short)f2bf(v1.w);
      #pragma unroll
      for (int nt = 0; nt < 8; ++nt) {
        bf16x8 b0 = *(const bf16x8*)(smem + ((ksl * 8 + nt) * 64 + l) * 16);
        acc0[0][nt] = __builtin_amdgcn_mfma_f32_16x16x32_bf16(a0, b0, acc0[0][nt], 0, 0, 0);
        acc0[1][nt] = __builtin_amdgcn_mfma_f32_16x16x32_bf16(a1, b0, acc0[1][nt], 0, 0, 0);
        bf16x8 br = *(const bf16x8*)(smem + 32768 + ((ksl * 8 + nt) * 64 + l) * 16);
        accR[0][nt] = __builtin_amdgcn_mfma_f32_16x16x32_bf16(a0, br, accR[0][nt], 0, 0, 0);
        accR[1][nt] = __builtin_amdgcn_mfma_f32_16x16x32_bf16(a1, br, accR[1][nt], 0, 0, 0);
      }
    }
  }
  __syncthreads();  // B dead; smem becomes per-wave epilogue scratch
  uint8_t*  lds8 = (uint8_t*)(smem + wid * 16384);
  uint16_t* ldsb = (uint16_t*)(smem + wid * 16384 + 4096);
  #pragma unroll
  for (int rt = 0; rt < 2; ++rt) {
    int row0 = r0 + rt * 16;
    epilogue_int8(acc0[rt], l, row0, lds8, H8, dsc, dinv);
    #pragma unroll
    for (int nt = 0; nt < 8; ++nt)
      #pragma unroll
      for (int j = 0; j < 4; ++j)
        ldsb[((l >> 4) * 4 + j) * 128 + nt * 16 + (l & 15)] = (uint16_t)f2bf(accR[rt][nt][j]);
    asm volatile("s_waitcnt lgkmcnt(0)" ::: "memory");
    const uint4* sb = (const uint4*)ldsb;
    if (row0 + (l >> 2) < N_NODES) {
      uint4* gb = (uint4*)(resB + (size_t)(row0 + (l >> 2)) * 128 + (l & 3) * 32);
      #pragma unroll
      for (int t = 0; t < 4; ++t) gb[t] = sb[l * 4 + t];
    }
  }
}

// layers 1/2 GEMM: A bf16 [N][128] @ Wp(LDS-shared) -> int8+dsc
__global__ __launch_bounds__(256) void k_gemm8(const uint16_t* __restrict__ A,
                                               const uint16_t* __restrict__ Wp,
                                               uint8_t* __restrict__ H8,
                                               float* __restrict__ dsc,
                                               const float* __restrict__ dinv) {
  __shared__ __align__(16) char smem[32768];
  int tid = threadIdx.x, wid = tid >> 6, l = tid & 63;
  #pragma unroll
  for (int i = 0; i < 8; ++i) {
    int g = i * 256 + tid;
    *(uint4*)(smem + g * 16) = *(const uint4*)((const char*)Wp + g * 16);
  }
  __syncthreads();
  int r0 = blockIdx.x * 128 + wid * 32;
  int hk = l >> 4, rl = l & 15;
  int ra0 = min(r0 + rl, N_NODES - 1);
  int ra1 = min(r0 + 16 + rl, N_NODES - 1);
  f32x4 acc[2][8] = {};
  #pragma unroll
  for (int ks = 0; ks < 4; ++ks) {
    bf16x8 a0 = *(const bf16x8*)(A + (size_t)ra0 * 128 + ks * 32 + hk * 8);
    bf16x8 a1 = *(const bf16x8*)(A + (size_t)ra1 * 128 + ks * 32 + hk * 8);
    #pragma unroll
    for (int nt = 0; nt < 8; ++nt) {
      bf16x8 b = *(const bf16x8*)(smem + ((ks * 8 + nt) * 64 + l) * 16);
      acc[0][nt] = __builtin_amdgcn_mfma_f32_16x16x32_bf16(a0, b, acc[0][nt], 0, 0, 0);
      acc[1][nt] = __builtin_amdgcn_mfma_f32_16x16x32_bf16(a1, b, acc[1][nt], 0, 0, 0);
    }
  }
  __syncthreads();  // B dead; reuse as epilogue scratch
  uint8_t* lds8 = (uint8_t*)(smem + wid * 4096);
  epilogue_int8(acc[0], l, r0, lds8, H8, dsc, dinv);
  epilogue_int8(acc[1], l, r0 + 16, lds8, H8, dsc, dinv);
}

// fused: int8 gather-sum + bias + LN + ReLU + bf16 residual
// four 16-lane quarters; quarter q owns 4-edge blocks jb%4==q (uint4 index loads);
// lane owns 8 channels (uint2 gather); 32-bit SADDR-friendly offsets.
#define ACC8(w, h)                              \
  do {                                          \
    cs += (w);                                  \
    a0 += (w) * (float)((h).x & 0xFFu);         \
    a1 += (w) * (float)(((h).x >> 8) & 0xFFu);  \
    a2 += (w) * (float)(((h).x >> 16) & 0xFFu); \
    a3 += (w) * (float)((h).x >> 24);           \
    a4 += (w) * (float)((h).y & 0xFFu);         \
    a5 += (w) * (float)(((h).y >> 8) & 0xFFu);  \
    a6 += (w) * (float)(((h).y >> 16) & 0xFFu); \
    a7 += (w) * (float)((h).y >> 24);           \
  } while (0)

__global__ __launch_bounds__(256) void k_agg(const uint8_t* __restrict__ H8,
                                             const float* __restrict__ dsc,
                                             const int* __restrict__ sedge,
                                             const int* __restrict__ offs,
                                             const float* __restrict__ dinv,
                                             const float* __restrict__ bias,
                                             const float* __restrict__ g,
                                             const float* __restrict__ be,
                                             const uint16_t* __restrict__ residB,
                                             float* __restrict__ outF,
                                             uint16_t* __restrict__ outB) {
  int wid = threadIdx.x >> 6, l = threadIdx.x & 63;
  int v = blockIdx.x * 4 + wid;
  if (v >= N_NODES) return;
  int q = l >> 4, c = l & 15;
  uint32_t coff = (uint32_t)c << 3;
  float a0 = 0.f, a1 = 0.f, a2 = 0.f, a3 = 0.f;
  float a4 = 0.f, a5 = 0.f, a6 = 0.f, a7 = 0.f, cs = 0.f;
  int p0 = offs[v];
  int nb = (offs[v + 1] - p0) >> 2;      // 4-edge blocks (padded, exact)
  const uint4* sblk = (const uint4*)(sedge + p0);
  int jb = q;
  for (; jb + 4 < nb; jb += 8) {
    uint4 i0 = sblk[jb];
    uint4 i1 = sblk[jb + 4];
    float w0 = dsc[i0.x], w1 = dsc[i0.y], w2 = dsc[i0.z], w3 = dsc[i0.w];
    float w4 = dsc[i1.x], w5 = dsc[i1.y], w6 = dsc[i1.z], w7 = dsc[i1.w];
    uint2 h0 = *(const uint2*)(H8 + (((uint32_t)i0.x << 7) | coff));
    uint2 h1 = *(const uint2*)(H8 + (((uint32_t)i0.y << 7) | coff));
    uint2 h2 = *(const uint2*)(H8 + (((uint32_t)i0.z << 7) | coff));
    uint2 h3 = *(const uint2*)(H8 + (((uint32_t)i0.w << 7) | coff));
    uint2 h4 = *(const uint2*)(H8 + (((uint32_t)i1.x << 7) | coff));
    uint2 h5 = *(const uint2*)(H8 + (((uint32_t)i1.y << 7) | coff));
    uint2 h6 = *(const uint2*)(H8 + (((uint32_t)i1.z << 7) | coff));
    uint2 h7 = *(const uint2*)(H8 + (((uint32_t)i1.w << 7) | coff));
    ACC8(w0, h0); ACC8(w1, h1); ACC8(w2, h2); ACC8(w3, h3);
    ACC8(w4, h4); ACC8(w5, h5); ACC8(w6, h6); ACC8(w7, h7);
  }
  for (; jb < nb; jb += 4) {
    uint4 i0 = sblk[jb];
    float w0 = dsc[i0.x], w1 = dsc[i0.y], w2 = dsc[i0.z], w3 = dsc[i0.w];
    uint2 h0 = *(const uint2*)(H8 + (((uint32_t)i0.x << 7) | coff));
    uint2 h1 = *(const uint2*)(H8 + (((uint32_t)i0.y << 7) | coff));
    uint2 h2 = *(const uint2*)(H8 + (((uint32_t)i0.z << 7) | coff));
    uint2 h3 = *(const uint2*)(H8 + (((uint32_t)i0.w << 7) | coff));
    ACC8(w0, h0); ACC8(w1, h1); ACC8(w2, h2); ACC8(w3, h3);
  }
  // combine the 4 quarters
  #pragma unroll
  for (int m = 16; m <= 32; m <<= 1) {
    a0 += __shfl_xor(a0, m, 64); a1 += __shfl_xor(a1, m, 64);
    a2 += __shfl_xor(a2, m, 64); a3 += __shfl_xor(a3, m, 64);
    a4 += __shfl_xor(a4, m, 64); a5 += __shfl_xor(a5, m, 64);
    a6 += __shfl_xor(a6, m, 64); a7 += __shfl_xor(a7, m, 64);
    cs += __shfl_xor(cs, m, 64);
  }
  float dv = dinv[v];
  float bc = 128.f * cs;
  a0 = dv * (a0 - bc); a1 = dv * (a1 - bc); a2 = dv * (a2 - bc); a3 = dv * (a3 - bc);
  a4 = dv * (a4 - bc); a5 = dv * (a5 - bc); a6 = dv * (a6 - bc); a7 = dv * (a7 - bc);
  {  // self loop
    uint2 h = *(const uint2*)(H8 + (((uint32_t)v << 7) | coff));
    float wss = dv * dsc[v];
    a0 += wss * ((float)(h.x & 0xFFu) - 128.f);
    a1 += wss * ((float)((h.x >> 8) & 0xFFu) - 128.f);
    a2 += wss * ((float)((h.x >> 16) & 0xFFu) - 128.f);
    a3 += wss * ((float)(h.x >> 24) - 128.f);
    a4 += wss * ((float)(h.y & 0xFFu) - 128.f);
    a5 += wss * ((float)((h.y >> 8) & 0xFFu) - 128.f);
    a6 += wss * ((float)((h.y >> 16) & 0xFFu) - 128.f);
    a7 += wss * ((float)(h.y >> 24) - 128.f);
  }
  float4 bb0 = *(const float4*)(bias + 8 * c);
  float4 bb1 = *(const float4*)(bias + 8 * c + 4);
  a0 += bb0.x; a1 += bb0.y; a2 += bb0.z; a3 += bb0.w;
  a4 += bb1.x; a5 += bb1.y; a6 += bb1.z; a7 += bb1.w;
  float s = a0 + a1 + a2 + a3 + a4 + a5 + a6 + a7;
  #pragma unroll
  for (int m = 1; m < 16; m <<= 1) s += __shfl_xor(s, m, 64);
  float mu = s * (1.f / 128.f);
  float d0 = a0 - mu, d1 = a1 - mu, d2 = a2 - mu, d3 = a3 - mu;
  float d4 = a4 - mu, d5 = a5 - mu, d6 = a6 - mu, d7 = a7 - mu;
  float qq = d0 * d0 + d1 * d1 + d2 * d2 + d3 * d3 +
             d4 * d4 + d5 * d5 + d6 * d6 + d7 * d7;
  #pragma unroll
  for (int m = 1; m < 16; m <<= 1) qq += __shfl_xor(qq, m, 64);
  float rs = rsqrtf(qq * (1.f / 128.f) + EPS);
  float4 gg0 = *(const float4*)(g + 8 * c);
  float4 gg1 = *(const float4*)(g + 8 * c + 4);
  float4 ee0 = *(const float4*)(be + 8 * c);
  float4 ee1 = *(const float4*)(be + 8 * c + 4);
  float y0 = fmaxf(d0 * rs * gg0.x + ee0.x, 0.f);
  float y1 = fmaxf(d1 * rs * gg0.y + ee0.y, 0.f);
  float y2 = fmaxf(d2 * rs * gg0.z + ee0.z, 0.f);
  float y3 = fmaxf(d3 * rs * gg0.w + ee0.w, 0.f);
  float y4 = fmaxf(d4 * rs * gg1.x + ee1.x, 0.f);
  float y5 = fmaxf(d5 * rs * gg1.y + ee1.y, 0.f);
  float y6 = fmaxf(d6 * rs * gg1.z + ee1.z, 0.f);
  float y7 = fmaxf(d7 * rs * gg1.w + ee1.w, 0.f);
  uint4 rr = *(const uint4*)(residB + (size_t)v * 128 + 8 * c);
  y0 += bflo(rr.x); y1 += bfhi(rr.x);
  y2 += bflo(rr.y); y3 += bfhi(rr.y);
  y4 += bflo(rr.z); y5 += bfhi(rr.z);
  y6 += bflo(rr.w); y7 += bfhi(rr.w);
  if (q == 0) {
    if (outF) {
      float* op = outF + (size_t)v * HID + 8 * c;
      *(float4*)op = make_float4(y0, y1, y2, y3);
      *(float4*)(op + 4) = make_float4(y4, y5, y6, y7);
    }
    if (outB) {
      uint4 o;
      o.x = f2bf(y0) | (f2bf(y1) << 16);
      o.y = f2bf(y2) | (f2bf(y3) << 16);
      o.z = f2bf(y4) | (f2bf(y5) << 16);
      o.w = f2bf(y6) | (f2bf(y7) << 16);
      *(uint4*)(outB + (size_t)v * 128 + 8 * c) = o;
    }
  }
}

extern "C" void kernel_launch(void* const* d_in, const int* in_sizes, int n_in,
                              void* d_out, int out_size, void* d_ws, size_t ws_size,
                              hipStream_t stream) {
  const float* x   = (const float*)d_in[0];
  const void*  ei  = d_in[1];
  const float* W0  = (const float*)d_in[2];
  const float* b0  = (const float*)d_in[3];
  const float* g0  = (const float*)d_in[4];
  const float* be0 = (const float*)d_in[5];
  const float* W1  = (const float*)d_in[6];
  const float* b1  = (const float*)d_in[7];
  const float* g1  = (const float*)d_in[8];
  const float* be1 = (const float*)d_in[9];
  const float* W2  = (const float*)d_in[10];
  const float* b2  = (const float*)d_in[11];
  const float* g2  = (const float*)d_in[12];
  const float* be2 = (const float*)d_in[13];
  const float* Wr  = (const float*)d_in[14];

  char* ws = (char*)d_ws;
  int*      sedge  = (int*)(ws + OFF_SRC);
  int*      offs   = (int*)(ws + OFF_OFFS);
  float*    dinv   = (float*)(ws + OFF_DINV);
  float*    dsc    = (float*)(ws + OFF_DSC);
  int*      cntg   = (int*)(ws + OFF_CNTG);
  uint16_t* wpk0   = (uint16_t*)(ws + OFF_WPK0);
  uint16_t* wpk1   = (uint16_t*)(ws + OFF_WPK1);
  uint16_t* wpk2   = (uint16_t*)(ws + OFF_WPK2);
  uint16_t* wpkr   = (uint16_t*)(ws + OFF_WPKR);
  int*      flag   = (int*)(ws + OFF_FLAG);
  int*      bcnt   = (int*)(ws + OFF_BCNT);
  int*      bbase  = (int*)(ws + OFF_BBASE);
  int*      bcur   = (int*)(ws + OFF_BCUR);
  int*      ptot   = (int*)(ws + OFF_PTOT);
  int*      pbase  = (int*)(ws + OFF_PBASE);
  uint8_t*  h8     = (uint8_t*)(ws + OFF_H8);
  int2*     part   = (int2*)(ws + OFF_PART);
  uint16_t* resB   = (uint16_t*)(ws + OFF_RESB);
  uint16_t* hbA    = (uint16_t*)(ws + OFF_HBA);
  uint16_t* hbB    = (uint16_t*)(ws + OFF_HBB);
  float*    out    = (float*)d_out;

  // ---- edge preprocessing: hist -> scan -> partition -> padded per-bucket CSR ----
  k_flag<<<1, 256, 0, stream>>>((const uint32_t*)ei, flag);
  hipMemsetAsync(bcnt, 0, NBUK * sizeof(int), stream);
  k_hist<<<2048, 256, 0, stream>>>(ei, flag, bcnt);
  k_bscan<<<1, 64, 0, stream>>>(bcnt, bbase, bcur);
  k_part<<<(N_EDGES + PCHUNK - 1) / PCHUNK, 256, 0, stream>>>(ei, flag, bcur, part);
  k_bucketA<<<NBUK, 256, 0, stream>>>(part, bbase, cntg, dinv, ptot);
  k_bscan2<<<1, 64, 0, stream>>>(ptot, pbase, offs, dsc);
  k_bucketB<<<NBUK, 256, 0, stream>>>(part, bbase, pbase, cntg, offs, sedge);

  // ---- weight packing ----
  k_packW<<<16, 256, 0, stream>>>(W0, wpk0, IN_CH);
  k_packW<<<8, 256, 0, stream>>>(W1, wpk1, HID);
  k_packW<<<8, 256, 0, stream>>>(W2, wpk2, HID);
  k_packW<<<16, 256, 0, stream>>>(Wr, wpkr, IN_CH);

  // ---- layer 0: fused dual GEMM (x@W0 -> int8, x@Wr -> bf16 residual) ----
  k_gemm0<<<GEMM_GRID, 256, 0, stream>>>(x, wpk0, wpkr, h8, dsc, dinv, resB);
  k_agg<<<25000, 256, 0, stream>>>(h8, dsc, sedge, offs, dinv, b0, g0, be0, resB, nullptr, hbA);

  // ---- layer 1 ----
  k_gemm8<<<GEMM_GRID, 256, 0, stream>>>(hbA, wpk1, h8, dsc, dinv);
  k_agg<<<25000, 256, 0, stream>>>(h8, dsc, sedge, offs, dinv, b1, g1, be1, hbA, nullptr, hbB);

  // ---- layer 2 (writes d_out f32) ----
  k_gemm8<<<GEMM_GRID, 256, 0, stream>>>(hbB, wpk2, h8, dsc, dinv);
  k_agg<<<25000, 256, 0, stream>>>(h8, dsc, sedge, offs, dinv, b2, g2, be2, hbB, out, nullptr);

  (void)in_sizes; (void)n_in; (void)out_size; (void)ws_size;
}

// Round 8
// 504.400 us; speedup vs baseline: 1.8655x; 1.0173x over previous
//
#include <hip/hip_runtime.h>
#include <hip/hip_bf16.h>
#include <stdint.h>

#define N_NODES 100000
#define N_EDGES 3200000
#define IN_CH 256
#define HID 128
#define EPS 1e-5f
#define BSH 9              // bucket = dst >> 9  (512 nodes per bucket)
#define NBUK 196           // ceil(100000/512)
#define PCHUNK 4096
#define GEMM_GRID 782      // ceil(100000/128)

using bf16x8 = __attribute__((ext_vector_type(8))) short;
using f32x4  = __attribute__((ext_vector_type(4))) float;
using f32x2  = __attribute__((ext_vector_type(2))) float;

__device__ __forceinline__ uint32_t f2bf(float f) {
  uint32_t u = __float_as_uint(f);
  return (u + 0x7FFFu + ((u >> 16) & 1u)) >> 16;
}
__device__ __forceinline__ float bflo(uint32_t u) { return __uint_as_float(u << 16); }
__device__ __forceinline__ float bfhi(uint32_t u) { return __uint_as_float(u & 0xFFFF0000u); }

// ---- workspace layout (bytes), all 128-aligned ----
static const size_t OFF_SRC   = 0;            // int[3,600,000] padded CSR src = 14,400,000
static const size_t OFF_OFFS  = 14400000;     // int[100001]
static const size_t OFF_DINV  = 14800128;     // float[100000]
static const size_t OFF_CNTG  = 15600256;     // int[100000]
static const size_t OFF_WPK0  = 16000256;     // 65,536
static const size_t OFF_WPK1  = 16065792;     // 32,768
static const size_t OFF_WPK2  = 16098560;     // 32,768
static const size_t OFF_WPKR  = 16131328;     // 65,536
static const size_t OFF_FLAG  = 16196864;     // int (+pad)
static const size_t OFF_BCNT  = 16196992;     // int[NBUK]
static const size_t OFF_BBASE = 16198016;     // int[NBUK+1]
static const size_t OFF_BCUR  = 16199040;     // int[NBUK]
static const size_t OFF_PTOT  = 16200064;     // int[NBUK]
static const size_t OFF_PBASE = 16201088;     // int[NBUK+1]
static const size_t OFF_H8    = 16202240;     // fp8[100001*128] = 12,800,128
static const size_t OFF_PART  = 16202240;     // int2[3.2M] = 25.6MB (aliases H8; dead before GEMM)
static const size_t OFF_RESB  = 41802240;     // bf16[100000*128] = 25,600,000
static const size_t OFF_HBA   = 67402240;     // bf16[100000*128]
static const size_t OFF_HBB   = 93002240;     // bf16[100000*128]  (end ~118.6MB)

// ---- edge dtype detection: int64 edges have zero high words ----
__global__ void k_flag(const uint32_t* __restrict__ e, int* flag) {
  __shared__ int any;
  if (threadIdx.x == 0) any = 0;
  __syncthreads();
  uint32_t acc = 0;
  for (int i = threadIdx.x; i < 2048; i += blockDim.x) acc |= e[2 * i + 1];
  if (acc) atomicOr(&any, 1);
  __syncthreads();
  if (threadIdx.x == 0) *flag = (any == 0) ? 1 : 0;  // 1 => int64 layout
}

// ---- bucket histogram (LDS-aggregated) ----
__global__ __launch_bounds__(256) void k_hist(const void* __restrict__ eidx,
                                              const int* __restrict__ flag,
                                              int* __restrict__ bcnt) {
  __shared__ int h[NBUK];
  for (int t = threadIdx.x; t < NBUK; t += 256) h[t] = 0;
  __syncthreads();
  bool i64 = (*flag != 0);
  int stride = gridDim.x * blockDim.x;
  for (int e = blockIdx.x * blockDim.x + threadIdx.x; e < N_EDGES; e += stride) {
    int d = i64 ? (int)((const uint32_t*)eidx)[2 * ((size_t)N_EDGES + e)]
                : ((const int*)eidx)[N_EDGES + e];
    atomicAdd(&h[d >> BSH], 1);
  }
  __syncthreads();
  for (int t = threadIdx.x; t < NBUK; t += 256)
    if (h[t]) atomicAdd(&bcnt[t], h[t]);
}

// ---- serial bucket scan (196 elems) ----
__global__ void k_bscan(const int* __restrict__ bcnt, int* __restrict__ bbase,
                        int* __restrict__ bcur) {
  if (threadIdx.x == 0 && blockIdx.x == 0) {
    int run = 0;
    for (int b = 0; b < NBUK; ++b) {
      bbase[b] = run;
      bcur[b] = run;
      run += bcnt[b];
    }
    bbase[NBUK] = run;
  }
}

// ---- LDS-staged partition into buckets (coalesced writes) ----
__global__ __launch_bounds__(256) void k_part(const void* __restrict__ eidx,
                                              const int* __restrict__ flag,
                                              int* __restrict__ bcur,
                                              int2* __restrict__ part) {
  __shared__ int lhist[NBUK];
  __shared__ int lbase[NBUK];
  __shared__ int gbase[NBUK];
  __shared__ int sm[256];
  __shared__ int2 sbuf[PCHUNK];
  __shared__ uint8_t bbuf[PCHUNK];
  int tid = threadIdx.x;
  int base = blockIdx.x * PCHUNK;
  int nE = N_EDGES - base;
  if (nE > PCHUNK) nE = PCHUNK;
  for (int t = tid; t < NBUK; t += 256) lhist[t] = 0;
  __syncthreads();
  bool i64 = (*flag != 0);
  int es[16], ed[16], ml[16];
  #pragma unroll
  for (int k = 0; k < 16; ++k) {
    int ci = k * 256 + tid;
    if (ci < nE) {
      int e = base + ci;
      int s, d;
      if (i64) {
        const uint32_t* u = (const uint32_t*)eidx;
        s = (int)u[2 * (size_t)e];
        d = (int)u[2 * ((size_t)N_EDGES + e)];
      } else {
        const int* u = (const int*)eidx;
        s = u[e];
        d = u[N_EDGES + e];
      }
      es[k] = s; ed[k] = d;
      ml[k] = atomicAdd(&lhist[d >> BSH], 1);
    }
  }
  __syncthreads();
  sm[tid] = (tid < NBUK) ? lhist[tid] : 0;
  __syncthreads();
  for (int s = 1; s < 256; s <<= 1) {
    int t = (tid >= s) ? sm[tid - s] : 0;
    __syncthreads();
    sm[tid] += t;
    __syncthreads();
  }
  if (tid < NBUK) lbase[tid] = sm[tid] - lhist[tid];
  __syncthreads();
  #pragma unroll
  for (int k = 0; k < 16; ++k) {
    int ci = k * 256 + tid;
    if (ci < nE) {
      int b = ed[k] >> BSH;
      int slot = lbase[b] + ml[k];
      sbuf[slot] = make_int2(es[k], ed[k]);
      bbuf[slot] = (uint8_t)b;
    }
  }
  if (tid < NBUK && lhist[tid] > 0) gbase[tid] = atomicAdd(&bcur[tid], lhist[tid]);
  __syncthreads();
  for (int i = tid; i < nE; i += 256) {
    int b = bbuf[i];
    part[(size_t)gbase[b] + (i - lbase[b])] = sbuf[i];
  }
}

// ---- bucketA: per-node exact counts + dinv + padded bucket totals ----
__global__ __launch_bounds__(256) void k_bucketA(const int2* __restrict__ part,
                                                 const int* __restrict__ bbase,
                                                 int* __restrict__ cntg,
                                                 float* __restrict__ dinv,
                                                 int* __restrict__ ptot) {
  __shared__ int cnt[512];
  __shared__ int s2[256];
  int tid = threadIdx.x, b = blockIdx.x;
  int v0 = b << BSH;
  int e0 = bbase[b], e1 = bbase[b + 1];
  cnt[tid] = 0; cnt[tid + 256] = 0;
  __syncthreads();
  for (int i = e0 + tid; i < e1; i += 256) atomicAdd(&cnt[part[i].y - v0], 1);
  __syncthreads();
  int pa = (cnt[2 * tid] + 3) & ~3, pb = (cnt[2 * tid + 1] + 3) & ~3;
  s2[tid] = pa + pb;
  __syncthreads();
  for (int s = 128; s > 0; s >>= 1) {
    if (tid < s) s2[tid] += s2[tid + s];
    __syncthreads();
  }
  if (tid == 0) ptot[b] = s2[0];
  #pragma unroll
  for (int k = 0; k < 2; ++k) {
    int t = tid + k * 256, v = v0 + t;
    if (v < N_NODES) {
      cntg[v] = cnt[t];
      dinv[v] = rsqrtf((float)(cnt[t] + 1));
    }
  }
}

// ---- serial padded-base scan ----
__global__ void k_bscan2(const int* __restrict__ ptot, int* __restrict__ pbase,
                         int* __restrict__ offs) {
  if (threadIdx.x == 0 && blockIdx.x == 0) {
    int run = 0;
    for (int b = 0; b < NBUK; ++b) { pbase[b] = run; run += ptot[b]; }
    pbase[NBUK] = run;
    offs[N_NODES] = run;
  }
}

// ---- bucketB: padded offs + scatter + sentinel pad fill ----
__global__ __launch_bounds__(256) void k_bucketB(const int2* __restrict__ part,
                                                 const int* __restrict__ bbase,
                                                 const int* __restrict__ pbase,
                                                 const int* __restrict__ cntg,
                                                 int* __restrict__ offs,
                                                 int* __restrict__ sedge) {
  __shared__ int pre[512];
  __shared__ int cur[512];
  __shared__ int s2[256];
  int tid = threadIdx.x, b = blockIdx.x;
  int v0 = b << BSH;
  int e0 = bbase[b], e1 = bbase[b + 1];
  int e0p = pbase[b];
  int c0 = (v0 + 2 * tid < N_NODES) ? cntg[v0 + 2 * tid] : 0;
  int c1 = (v0 + 2 * tid + 1 < N_NODES) ? cntg[v0 + 2 * tid + 1] : 0;
  int pa = (c0 + 3) & ~3, pb = (c1 + 3) & ~3;
  s2[tid] = pa + pb;
  __syncthreads();
  for (int s = 1; s < 256; s <<= 1) {
    int t = (tid >= s) ? s2[tid - s] : 0;
    __syncthreads();
    s2[tid] += t;
    __syncthreads();
  }
  int eb = s2[tid] - (pa + pb);
  pre[2 * tid] = eb;       cur[2 * tid] = eb;
  pre[2 * tid + 1] = eb + pa; cur[2 * tid + 1] = eb + pa;
  __syncthreads();
  #pragma unroll
  for (int k = 0; k < 2; ++k) {
    int t = tid + k * 256, v = v0 + t;
    if (v < N_NODES) offs[v] = e0p + pre[t];
  }
  for (int i = e0 + tid; i < e1; i += 256) {
    int2 e = part[i];
    int p = atomicAdd(&cur[e.y - v0], 1);
    sedge[e0p + p] = e.x;
  }
  __syncthreads();
  #pragma unroll
  for (int k = 0; k < 2; ++k) {
    int t = tid + k * 256, v = v0 + t;
    if (v < N_NODES) {
      int endx = cur[t];
      int endp = pre[t] + ((endx - pre[t] + 3) & ~3);
      for (int u = endx; u < endp; ++u) sedge[e0p + u] = N_NODES;  // sentinel row
    }
  }
}

// pack W [K][HID] f32 row-major into MFMA B-fragment-ready bf16 layout
__global__ void k_packW(const float* __restrict__ W, uint16_t* __restrict__ Wp, int K) {
  int t = blockIdx.x * blockDim.x + threadIdx.x;
  int total = (K / 32) * 8 * 64;
  if (t >= total) return;
  int l = t & 63;
  int nt = (t >> 6) & 7;
  int ks = t >> 9;
  int kbase = ks * 32 + (l >> 4) * 8;
  int col = nt * 16 + (l & 15);
  #pragma unroll
  for (int j = 0; j < 8; ++j)
    Wp[(size_t)t * 8 + j] = (uint16_t)f2bf(W[(size_t)(kbase + j) * HID + col]);
}

// epilogue: store h' = dinv[row] * acc as fp8 e4m3 rows, via swizzled LDS repack
__device__ __forceinline__ void epilogue_fp8(const f32x4* acc, int l, int row0,
                                             uint8_t* lds_my,
                                             uint8_t* __restrict__ H8,
                                             const float* __restrict__ dinv) {
  float dv[4];
  #pragma unroll
  for (int j = 0; j < 4; ++j) {
    int r = row0 + (l >> 4) * 4 + j;
    dv[j] = dinv[min(r, N_NODES - 1)];
  }
  #pragma unroll
  for (int nt = 0; nt < 8; ++nt)
    #pragma unroll
    for (int j = 0; j < 4; ++j) {
      int r = (l >> 4) * 4 + j, c = nt * 16 + (l & 15);
      uint32_t pk = __builtin_amdgcn_cvt_pk_fp8_f32(acc[nt][j] * dv[j], 0.f, 0u, false);
      lds_my[r * 128 + (c ^ ((r & 7) << 2))] = (uint8_t)pk;  // 4B-granule swizzle by row
    }
  asm volatile("s_waitcnt lgkmcnt(0)" ::: "memory");
  int r = l >> 2;
  uint32_t w[8];
  #pragma unroll
  for (int t = 0; t < 8; ++t) {
    int c4 = (l & 3) * 8 + t;
    w[t] = *(const uint32_t*)(lds_my + r * 128 + ((c4 ^ (r & 7)) << 2));
  }
  if (row0 + r < N_NODES) {
    uint4* gp = (uint4*)(H8 + (size_t)(row0 + r) * 128 + (l & 3) * 32);
    gp[0] = make_uint4(w[0], w[1], w[2], w[3]);
    gp[1] = make_uint4(w[4], w[5], w[6], w[7]);
  }
}

// layer-0 fused dual GEMM: X f32 [N][256]: X@W0 -> fp8 h', X@Wr -> bf16 residual
__global__ __launch_bounds__(256) void k_gemm0(const float* __restrict__ X,
                                               const uint16_t* __restrict__ Wp0,
                                               const uint16_t* __restrict__ WpR,
                                               uint8_t* __restrict__ H8,
                                               const float* __restrict__ dinv,
                                               uint16_t* __restrict__ resB) {
  __shared__ __align__(16) char smem[65536];
  int tid = threadIdx.x, wid = tid >> 6, l = tid & 63;
  int r0 = blockIdx.x * 128 + wid * 32;
  int hk = l >> 4, rl = l & 15;
  int ra0 = min(r0 + rl, N_NODES - 1);
  int ra1 = min(r0 + 16 + rl, N_NODES - 1);
  f32x4 acc0[2][8] = {}, accR[2][8] = {};
  #pragma unroll
  for (int kh = 0; kh < 2; ++kh) {
    __syncthreads();
    #pragma unroll
    for (int i = 0; i < 8; ++i) {
      int g = i * 256 + tid;
      *(uint4*)(smem + g * 16) =
          *(const uint4*)((const char*)Wp0 + kh * 32768 + g * 16);
      *(uint4*)(smem + 32768 + g * 16) =
          *(const uint4*)((const char*)WpR + kh * 32768 + g * 16);
    }
    __syncthreads();
    #pragma unroll
    for (int ksl = 0; ksl < 4; ++ksl) {
      int kof = kh * 128 + ksl * 32 + hk * 8;
      float4 u0 = *(const float4*)(X + (size_t)ra0 * 256 + kof);
      float4 u1 = *(const float4*)(X + (size_t)ra0 * 256 + kof + 4);
      float4 v0 = *(const float4*)(X + (size_t)ra1 * 256 + kof);
      float4 v1 = *(const float4*)(X + (size_t)ra1 * 256 + kof + 4);
      bf16x8 a0, a1;
      a0[0] = (short)f2bf(u0.x); a0[1] = (short)f2bf(u0.y);
      a0[2] = (short)f2bf(u0.z); a0[3] = (short)f2bf(u0.w);
      a0[4] = (short)f2bf(u1.x); a0[5] = (short)f2bf(u1.y);
      a0[6] = (short)f2bf(u1.z); a0[7] = (short)f2bf(u1.w);
      a1[0] = (short)f2bf(v0.x); a1[1] = (short)f2bf(v0.y);
      a1[2] = (short)f2bf(v0.z); a1[3] = (short)f2bf(v0.w);
      a1[4] = (short)f2bf(v1.x); a1[5] = (short)f2bf(v1.y);
      a1[6] = (short)f2bf(v1.z); a1[7] = (short)f2bf(v1.w);
      #pragma unroll
      for (int nt = 0; nt < 8; ++nt) {
        bf16x8 b0 = *(const bf16x8*)(smem + ((ksl * 8 + nt) * 64 + l) * 16);
        acc0[0][nt] = __builtin_amdgcn_mfma_f32_16x16x32_bf16(a0, b0, acc0[0][nt], 0, 0, 0);
        acc0[1][nt] = __builtin_amdgcn_mfma_f32_16x16x32_bf16(a1, b0, acc0[1][nt], 0, 0, 0);
        bf16x8 br = *(const bf16x8*)(smem + 32768 + ((ksl * 8 + nt) * 64 + l) * 16);
        accR[0][nt] = __builtin_amdgcn_mfma_f32_16x16x32_bf16(a0, br, accR[0][nt], 0, 0, 0);
        accR[1][nt] = __builtin_amdgcn_mfma_f32_16x16x32_bf16(a1, br, accR[1][nt], 0, 0, 0);
      }
    }
  }
  __syncthreads();  // B dead; smem becomes per-wave epilogue scratch
  uint8_t*  lds8 = (uint8_t*)(smem + wid * 16384);
  uint16_t* ldsb = (uint16_t*)(smem + wid * 16384 + 4096);
  #pragma unroll
  for (int rt = 0; rt < 2; ++rt) {
    int row0 = r0 + rt * 16;
    epilogue_fp8(acc0[rt], l, row0, lds8, H8, dinv);
    #pragma unroll
    for (int nt = 0; nt < 8; ++nt)
      #pragma unroll
      for (int j = 0; j < 4; ++j)
        ldsb[((l >> 4) * 4 + j) * 128 + nt * 16 + (l & 15)] = (uint16_t)f2bf(accR[rt][nt][j]);
    asm volatile("s_waitcnt lgkmcnt(0)" ::: "memory");
    const uint4* sb = (const uint4*)ldsb;
    if (row0 + (l >> 2) < N_NODES) {
      uint4* gb = (uint4*)(resB + (size_t)(row0 + (l >> 2)) * 128 + (l & 3) * 32);
      #pragma unroll
      for (int t = 0; t < 4; ++t) gb[t] = sb[l * 4 + t];
    }
  }
}

// layers 1/2 GEMM: A bf16 [N][128] @ Wp(LDS-shared) -> fp8 h'
__global__ __launch_bounds__(256) void k_gemm8(const uint16_t* __restrict__ A,
                                               const uint16_t* __restrict__ Wp,
                                               uint8_t* __restrict__ H8,
                                               const float* __restrict__ dinv) {
  __shared__ __align__(16) char smem[32768];
  int tid = threadIdx.x, wid = tid >> 6, l = tid & 63;
  #pragma unroll
  for (int i = 0; i < 8; ++i) {
    int g = i * 256 + tid;
    *(uint4*)(smem + g * 16) = *(const uint4*)((const char*)Wp + g * 16);
  }
  __syncthreads();
  int r0 = blockIdx.x * 128 + wid * 32;
  int hk = l >> 4, rl = l & 15;
  int ra0 = min(r0 + rl, N_NODES - 1);
  int ra1 = min(r0 + 16 + rl, N_NODES - 1);
  f32x4 acc[2][8] = {};
  #pragma unroll
  for (int ks = 0; ks < 4; ++ks) {
    bf16x8 a0 = *(const bf16x8*)(A + (size_t)ra0 * 128 + ks * 32 + hk * 8);
    bf16x8 a1 = *(const bf16x8*)(A + (size_t)ra1 * 128 + ks * 32 + hk * 8);
    #pragma unroll
    for (int nt = 0; nt < 8; ++nt) {
      bf16x8 b = *(const bf16x8*)(smem + ((ks * 8 + nt) * 64 + l) * 16);
      acc[0][nt] = __builtin_amdgcn_mfma_f32_16x16x32_bf16(a0, b, acc[0][nt], 0, 0, 0);
      acc[1][nt] = __builtin_amdgcn_mfma_f32_16x16x32_bf16(a1, b, acc[1][nt], 0, 0, 0);
    }
  }
  __syncthreads();  // B dead; reuse as epilogue scratch
  uint8_t* lds8 = (uint8_t*)(smem + wid * 4096);
  epilogue_fp8(acc[0], l, r0, lds8, H8, dinv);
  epilogue_fp8(acc[1], l, r0 + 16, lds8, H8, dinv);
}

// fused: fp8 gather-sum + bias + LN + ReLU + bf16 residual
// four 16-lane quarters; quarter q owns 4-edge blocks jb%4==q (uint4 index loads);
// lane owns 8 channels (uint2 gather); unweighted fp8 row sum (scales pre-folded).
#define PROC(hx, hy)                                                   \
  do {                                                                 \
    f32x2 f_;                                                          \
    f_ = __builtin_amdgcn_cvt_pk_f32_fp8((hx), false);                 \
    asm("v_pk_add_f32 %0, %0, %1" : "+v"(A01) : "v"(f_));              \
    f_ = __builtin_amdgcn_cvt_pk_f32_fp8((hx), true);                  \
    asm("v_pk_add_f32 %0, %0, %1" : "+v"(A23) : "v"(f_));              \
    f_ = __builtin_amdgcn_cvt_pk_f32_fp8((hy), false);                 \
    asm("v_pk_add_f32 %0, %0, %1" : "+v"(A45) : "v"(f_));              \
    f_ = __builtin_amdgcn_cvt_pk_f32_fp8((hy), true);                  \
    asm("v_pk_add_f32 %0, %0, %1" : "+v"(A67) : "v"(f_));              \
  } while (0)

__global__ __launch_bounds__(256) void k_agg(const uint8_t* __restrict__ H8,
                                             const int* __restrict__ sedge,
                                             const int* __restrict__ offs,
                                             const float* __restrict__ dinv,
                                             const float* __restrict__ bias,
                                             const float* __restrict__ g,
                                             const float* __restrict__ be,
                                             const uint16_t* __restrict__ residB,
                                             float* __restrict__ outF,
                                             uint16_t* __restrict__ outB) {
  int wid = threadIdx.x >> 6, l = threadIdx.x & 63;
  int v = blockIdx.x * 4 + wid;
  if (v >= N_NODES) return;
  int q = l >> 4, c = l & 15;
  uint32_t coff = (uint32_t)c << 3;
  f32x2 A01 = {0.f, 0.f}, A23 = {0.f, 0.f}, A45 = {0.f, 0.f}, A67 = {0.f, 0.f};
  int p0 = offs[v];
  int nb = (offs[v + 1] - p0) >> 2;      // 4-edge blocks (padded, exact)
  const uint4* sblk = (const uint4*)(sedge + p0);
  int jb = q;
  for (; jb + 4 < nb; jb += 8) {
    uint4 i0 = sblk[jb];
    uint4 i1 = sblk[jb + 4];
    uint2 h0 = *(const uint2*)(H8 + ((i0.x << 7) | coff));
    uint2 h1 = *(const uint2*)(H8 + ((i0.y << 7) | coff));
    uint2 h2 = *(const uint2*)(H8 + ((i0.z << 7) | coff));
    uint2 h3 = *(const uint2*)(H8 + ((i0.w << 7) | coff));
    uint2 h4 = *(const uint2*)(H8 + ((i1.x << 7) | coff));
    uint2 h5 = *(const uint2*)(H8 + ((i1.y << 7) | coff));
    uint2 h6 = *(const uint2*)(H8 + ((i1.z << 7) | coff));
    uint2 h7 = *(const uint2*)(H8 + ((i1.w << 7) | coff));
    PROC(h0.x, h0.y); PROC(h1.x, h1.y); PROC(h2.x, h2.y); PROC(h3.x, h3.y);
    PROC(h4.x, h4.y); PROC(h5.x, h5.y); PROC(h6.x, h6.y); PROC(h7.x, h7.y);
  }
  for (; jb < nb; jb += 4) {
    uint4 i0 = sblk[jb];
    uint2 h0 = *(const uint2*)(H8 + ((i0.x << 7) | coff));
    uint2 h1 = *(const uint2*)(H8 + ((i0.y << 7) | coff));
    uint2 h2 = *(const uint2*)(H8 + ((i0.z << 7) | coff));
    uint2 h3 = *(const uint2*)(H8 + ((i0.w << 7) | coff));
    PROC(h0.x, h0.y); PROC(h1.x, h1.y); PROC(h2.x, h2.y); PROC(h3.x, h3.y);
  }
  if (q == 0) {  // self loop: + own h' row
    uint2 h = *(const uint2*)(H8 + (((uint32_t)v << 7) | coff));
    PROC(h.x, h.y);
  }
  // combine the 4 quarters
  float a0 = A01.x, a1 = A01.y, a2 = A23.x, a3 = A23.y;
  float a4 = A45.x, a5 = A45.y, a6 = A67.x, a7 = A67.y;
  #pragma unroll
  for (int m = 16; m <= 32; m <<= 1) {
    a0 += __shfl_xor(a0, m, 64); a1 += __shfl_xor(a1, m, 64);
    a2 += __shfl_xor(a2, m, 64); a3 += __shfl_xor(a3, m, 64);
    a4 += __shfl_xor(a4, m, 64); a5 += __shfl_xor(a5, m, 64);
    a6 += __shfl_xor(a6, m, 64); a7 += __shfl_xor(a7, m, 64);
  }
  float dv = dinv[v];
  float4 bb0 = *(const float4*)(bias + 8 * c);
  float4 bb1 = *(const float4*)(bias + 8 * c + 4);
  a0 = dv * a0 + bb0.x; a1 = dv * a1 + bb0.y;
  a2 = dv * a2 + bb0.z; a3 = dv * a3 + bb0.w;
  a4 = dv * a4 + bb1.x; a5 = dv * a5 + bb1.y;
  a6 = dv * a6 + bb1.z; a7 = dv * a7 + bb1.w;
  // LayerNorm over 128 channels (16-lane reduction, replicated across quarters)
  float s = a0 + a1 + a2 + a3 + a4 + a5 + a6 + a7;
  #pragma unroll
  for (int m = 1; m < 16; m <<= 1) s += __shfl_xor(s, m, 64);
  float mu = s * (1.f / 128.f);
  float d0 = a0 - mu, d1 = a1 - mu, d2 = a2 - mu, d3 = a3 - mu;
  float d4 = a4 - mu, d5 = a5 - mu, d6 = a6 - mu, d7 = a7 - mu;
  float qq = d0 * d0 + d1 * d1 + d2 * d2 + d3 * d3 +
             d4 * d4 + d5 * d5 + d6 * d6 + d7 * d7;
  #pragma unroll
  for (int m = 1; m < 16; m <<= 1) qq += __shfl_xor(qq, m, 64);
  float rs = rsqrtf(qq * (1.f / 128.f) + EPS);
  float4 gg0 = *(const float4*)(g + 8 * c);
  float4 gg1 = *(const float4*)(g + 8 * c + 4);
  float4 ee0 = *(const float4*)(be + 8 * c);
  float4 ee1 = *(const float4*)(be + 8 * c + 4);
  float y0 = fmaxf(d0 * rs * gg0.x + ee0.x, 0.f);
  float y1 = fmaxf(d1 * rs * gg0.y + ee0.y, 0.f);
  float y2 = fmaxf(d2 * rs * gg0.z + ee0.z, 0.f);
  float y3 = fmaxf(d3 * rs * gg0.w + ee0.w, 0.f);
  float y4 = fmaxf(d4 * rs * gg1.x + ee1.x, 0.f);
  float y5 = fmaxf(d5 * rs * gg1.y + ee1.y, 0.f);
  float y6 = fmaxf(d6 * rs * gg1.z + ee1.z, 0.f);
  float y7 = fmaxf(d7 * rs * gg1.w + ee1.w, 0.f);
  uint4 rr = *(const uint4*)(residB + (size_t)v * 128 + 8 * c);
  y0 += bflo(rr.x); y1 += bfhi(rr.x);
  y2 += bflo(rr.y); y3 += bfhi(rr.y);
  y4 += bflo(rr.z); y5 += bfhi(rr.z);
  y6 += bflo(rr.w); y7 += bfhi(rr.w);
  if (q == 0) {
    if (outF) {
      float* op = outF + (size_t)v * HID + 8 * c;
      *(float4*)op = make_float4(y0, y1, y2, y3);
      *(float4*)(op + 4) = make_float4(y4, y5, y6, y7);
    }
    if (outB) {
      uint4 o;
      o.x = f2bf(y0) | (f2bf(y1) << 16);
      o.y = f2bf(y2) | (f2bf(y3) << 16);
      o.z = f2bf(y4) | (f2bf(y5) << 16);
      o.w = f2bf(y6) | (f2bf(y7) << 16);
      *(uint4*)(outB + (size_t)v * 128 + 8 * c) = o;
    }
  }
}

extern "C" void kernel_launch(void* const* d_in, const int* in_sizes, int n_in,
                              void* d_out, int out_size, void* d_ws, size_t ws_size,
                              hipStream_t stream) {
  const float* x   = (const float*)d_in[0];
  const void*  ei  = d_in[1];
  const float* W0  = (const float*)d_in[2];
  const float* b0  = (const float*)d_in[3];
  const float* g0  = (const float*)d_in[4];
  const float* be0 = (const float*)d_in[5];
  const float* W1  = (const float*)d_in[6];
  const float* b1  = (const float*)d_in[7];
  const float* g1  = (const float*)d_in[8];
  const float* be1 = (const float*)d_in[9];
  const float* W2  = (const float*)d_in[10];
  const float* b2  = (const float*)d_in[11];
  const float* g2  = (const float*)d_in[12];
  const float* be2 = (const float*)d_in[13];
  const float* Wr  = (const float*)d_in[14];

  char* ws = (char*)d_ws;
  int*      sedge  = (int*)(ws + OFF_SRC);
  int*      offs   = (int*)(ws + OFF_OFFS);
  float*    dinv   = (float*)(ws + OFF_DINV);
  int*      cntg   = (int*)(ws + OFF_CNTG);
  uint16_t* wpk0   = (uint16_t*)(ws + OFF_WPK0);
  uint16_t* wpk1   = (uint16_t*)(ws + OFF_WPK1);
  uint16_t* wpk2   = (uint16_t*)(ws + OFF_WPK2);
  uint16_t* wpkr   = (uint16_t*)(ws + OFF_WPKR);
  int*      flag   = (int*)(ws + OFF_FLAG);
  int*      bcnt   = (int*)(ws + OFF_BCNT);
  int*      bbase  = (int*)(ws + OFF_BBASE);
  int*      bcur   = (int*)(ws + OFF_BCUR);
  int*      ptot   = (int*)(ws + OFF_PTOT);
  int*      pbase  = (int*)(ws + OFF_PBASE);
  uint8_t*  h8     = (uint8_t*)(ws + OFF_H8);
  int2*     part   = (int2*)(ws + OFF_PART);
  uint16_t* resB   = (uint16_t*)(ws + OFF_RESB);
  uint16_t* hbA    = (uint16_t*)(ws + OFF_HBA);
  uint16_t* hbB    = (uint16_t*)(ws + OFF_HBB);
  float*    out    = (float*)d_out;

  // ---- edge preprocessing: hist -> scan -> partition -> padded per-bucket CSR ----
  k_flag<<<1, 256, 0, stream>>>((const uint32_t*)ei, flag);
  hipMemsetAsync(bcnt, 0, NBUK * sizeof(int), stream);
  k_hist<<<2048, 256, 0, stream>>>(ei, flag, bcnt);
  k_bscan<<<1, 64, 0, stream>>>(bcnt, bbase, bcur);
  k_part<<<(N_EDGES + PCHUNK - 1) / PCHUNK, 256, 0, stream>>>(ei, flag, bcur, part);
  k_bucketA<<<NBUK, 256, 0, stream>>>(part, bbase, cntg, dinv, ptot);
  k_bscan2<<<1, 64, 0, stream>>>(ptot, pbase, offs);
  k_bucketB<<<NBUK, 256, 0, stream>>>(part, bbase, pbase, cntg, offs, sedge);
  // sentinel row (src == N_NODES) must be zero; part buffer is dead now
  hipMemsetAsync(h8 + (size_t)N_NODES * 128, 0, 128, stream);

  // ---- weight packing ----
  k_packW<<<16, 256, 0, stream>>>(W0, wpk0, IN_CH);
  k_packW<<<8, 256, 0, stream>>>(W1, wpk1, HID);
  k_packW<<<8, 256, 0, stream>>>(W2, wpk2, HID);
  k_packW<<<16, 256, 0, stream>>>(Wr, wpkr, IN_CH);

  // ---- layer 0: fused dual GEMM (x@W0 -> fp8 h', x@Wr -> bf16 residual) ----
  k_gemm0<<<GEMM_GRID, 256, 0, stream>>>(x, wpk0, wpkr, h8, dinv, resB);
  k_agg<<<25000, 256, 0, stream>>>(h8, sedge, offs, dinv, b0, g0, be0, resB, nullptr, hbA);

  // ---- layer 1 ----
  k_gemm8<<<GEMM_GRID, 256, 0, stream>>>(hbA, wpk1, h8, dinv);
  k_agg<<<25000, 256, 0, stream>>>(h8, sedge, offs, dinv, b1, g1, be1, hbA, nullptr, hbB);

  // ---- layer 2 (writes d_out f32) ----
  k_gemm8<<<GEMM_GRID, 256, 0, stream>>>(hbB, wpk2, h8, dinv);
  k_agg<<<25000, 256, 0, stream>>>(h8, sedge, offs, dinv, b2, g2, be2, hbB, out, nullptr);

  (void)in_sizes; (void)n_in; (void)out_size; (void)ws_size;
}

// Round 9
// 467.865 us; speedup vs baseline: 2.0112x; 1.0781x over previous
//
#include <hip/hip_runtime.h>
#include <hip/hip_bf16.h>
#include <stdint.h>

#define N_NODES 100000
#define N_EDGES 3200000
#define IN_CH 256
#define HID 128
#define EPS 1e-5f
#define BSH 9              // bucket = dst >> 9  (512 nodes per bucket)
#define NBUK 196           // ceil(100000/512)
#define PCHUNK 4096
#define GEMM_GRID 782      // ceil(100000/128)

using bf16x8 = __attribute__((ext_vector_type(8))) short;
using f32x4  = __attribute__((ext_vector_type(4))) float;
using f32x2  = __attribute__((ext_vector_type(2))) float;

__device__ __forceinline__ uint32_t f2bf(float f) {
  uint32_t u = __float_as_uint(f);
  return (u + 0x7FFFu + ((u >> 16) & 1u)) >> 16;
}
__device__ __forceinline__ float bflo(uint32_t u) { return __uint_as_float(u << 16); }
__device__ __forceinline__ float bfhi(uint32_t u) { return __uint_as_float(u & 0xFFFF0000u); }

// ---- workspace layout (bytes), all 128-aligned ----
static const size_t OFF_SRC   = 0;            // int[3,600,000] padded CSR src = 14,400,000
static const size_t OFF_OFFS  = 14400000;     // int[100001]
static const size_t OFF_DINV  = 14800128;     // float[100000]
static const size_t OFF_CNTG  = 15600256;     // int[100000]
static const size_t OFF_WPK0  = 16000256;     // 65,536
static const size_t OFF_WPK1  = 16065792;     // 32,768
static const size_t OFF_WPK2  = 16098560;     // 32,768
static const size_t OFF_WPKR  = 16131328;     // 65,536
static const size_t OFF_FLAG  = 16196864;     // int (+pad)
static const size_t OFF_BCNT  = 16196992;     // int[NBUK]
static const size_t OFF_BBASE = 16198016;     // int[NBUK+1]
static const size_t OFF_BCUR  = 16199040;     // int[NBUK]
static const size_t OFF_PTOT  = 16200064;     // int[NBUK]
static const size_t OFF_PBASE = 16201088;     // int[NBUK+1]
static const size_t OFF_H8    = 16202240;     // fp8[100001*128] = 12,800,128
static const size_t OFF_PART  = 16202240;     // int2[3.2M] = 25.6MB (aliases H8; dead before GEMM)
static const size_t OFF_RESB  = 41802240;     // bf16[100000*128] = 25,600,000
static const size_t OFF_HBA   = 67402240;     // bf16[100000*128]
static const size_t OFF_HBB   = 93002240;     // bf16[100000*128]
static const size_t OFF_XB16  = 118602240;    // bf16[100000*256] = 51,200,000 (end ~169.8MB)

// ---- edge dtype detection: int64 edges have zero high words ----
__global__ void k_flag(const uint32_t* __restrict__ e, int* flag) {
  __shared__ int any;
  if (threadIdx.x == 0) any = 0;
  __syncthreads();
  uint32_t acc = 0;
  for (int i = threadIdx.x; i < 2048; i += blockDim.x) acc |= e[2 * i + 1];
  if (acc) atomicOr(&any, 1);
  __syncthreads();
  if (threadIdx.x == 0) *flag = (any == 0) ? 1 : 0;  // 1 => int64 layout
}

// ---- bucket histogram (LDS-aggregated) ----
__global__ __launch_bounds__(256) void k_hist(const void* __restrict__ eidx,
                                              const int* __restrict__ flag,
                                              int* __restrict__ bcnt) {
  __shared__ int h[NBUK];
  for (int t = threadIdx.x; t < NBUK; t += 256) h[t] = 0;
  __syncthreads();
  bool i64 = (*flag != 0);
  int stride = gridDim.x * blockDim.x;
  for (int e = blockIdx.x * blockDim.x + threadIdx.x; e < N_EDGES; e += stride) {
    int d = i64 ? (int)((const uint32_t*)eidx)[2 * ((size_t)N_EDGES + e)]
                : ((const int*)eidx)[N_EDGES + e];
    atomicAdd(&h[d >> BSH], 1);
  }
  __syncthreads();
  for (int t = threadIdx.x; t < NBUK; t += 256)
    if (h[t]) atomicAdd(&bcnt[t], h[t]);
}

// ---- serial bucket scan (196 elems) ----
__global__ void k_bscan(const int* __restrict__ bcnt, int* __restrict__ bbase,
                        int* __restrict__ bcur) {
  if (threadIdx.x == 0 && blockIdx.x == 0) {
    int run = 0;
    for (int b = 0; b < NBUK; ++b) {
      bbase[b] = run;
      bcur[b] = run;
      run += bcnt[b];
    }
    bbase[NBUK] = run;
  }
}

// ---- LDS-staged partition into buckets (coalesced writes) ----
__global__ __launch_bounds__(256) void k_part(const void* __restrict__ eidx,
                                              const int* __restrict__ flag,
                                              int* __restrict__ bcur,
                                              int2* __restrict__ part) {
  __shared__ int lhist[NBUK];
  __shared__ int lbase[NBUK];
  __shared__ int gbase[NBUK];
  __shared__ int sm[256];
  __shared__ int2 sbuf[PCHUNK];
  __shared__ uint8_t bbuf[PCHUNK];
  int tid = threadIdx.x;
  int base = blockIdx.x * PCHUNK;
  int nE = N_EDGES - base;
  if (nE > PCHUNK) nE = PCHUNK;
  for (int t = tid; t < NBUK; t += 256) lhist[t] = 0;
  __syncthreads();
  bool i64 = (*flag != 0);
  int es[16], ed[16], ml[16];
  #pragma unroll
  for (int k = 0; k < 16; ++k) {
    int ci = k * 256 + tid;
    if (ci < nE) {
      int e = base + ci;
      int s, d;
      if (i64) {
        const uint32_t* u = (const uint32_t*)eidx;
        s = (int)u[2 * (size_t)e];
        d = (int)u[2 * ((size_t)N_EDGES + e)];
      } else {
        const int* u = (const int*)eidx;
        s = u[e];
        d = u[N_EDGES + e];
      }
      es[k] = s; ed[k] = d;
      ml[k] = atomicAdd(&lhist[d >> BSH], 1);
    }
  }
  __syncthreads();
  sm[tid] = (tid < NBUK) ? lhist[tid] : 0;
  __syncthreads();
  for (int s = 1; s < 256; s <<= 1) {
    int t = (tid >= s) ? sm[tid - s] : 0;
    __syncthreads();
    sm[tid] += t;
    __syncthreads();
  }
  if (tid < NBUK) lbase[tid] = sm[tid] - lhist[tid];
  __syncthreads();
  #pragma unroll
  for (int k = 0; k < 16; ++k) {
    int ci = k * 256 + tid;
    if (ci < nE) {
      int b = ed[k] >> BSH;
      int slot = lbase[b] + ml[k];
      sbuf[slot] = make_int2(es[k], ed[k]);
      bbuf[slot] = (uint8_t)b;
    }
  }
  if (tid < NBUK && lhist[tid] > 0) gbase[tid] = atomicAdd(&bcur[tid], lhist[tid]);
  __syncthreads();
  for (int i = tid; i < nE; i += 256) {
    int b = bbuf[i];
    part[(size_t)gbase[b] + (i - lbase[b])] = sbuf[i];
  }
}

// ---- bucketA: per-node exact counts + dinv + padded bucket totals ----
__global__ __launch_bounds__(256) void k_bucketA(const int2* __restrict__ part,
                                                 const int* __restrict__ bbase,
                                                 int* __restrict__ cntg,
                                                 float* __restrict__ dinv,
                                                 int* __restrict__ ptot) {
  __shared__ int cnt[512];
  __shared__ int s2[256];
  int tid = threadIdx.x, b = blockIdx.x;
  int v0 = b << BSH;
  int e0 = bbase[b], e1 = bbase[b + 1];
  cnt[tid] = 0; cnt[tid + 256] = 0;
  __syncthreads();
  for (int i = e0 + tid; i < e1; i += 256) atomicAdd(&cnt[part[i].y - v0], 1);
  __syncthreads();
  int pa = (cnt[2 * tid] + 3) & ~3, pb = (cnt[2 * tid + 1] + 3) & ~3;
  s2[tid] = pa + pb;
  __syncthreads();
  for (int s = 128; s > 0; s >>= 1) {
    if (tid < s) s2[tid] += s2[tid + s];
    __syncthreads();
  }
  if (tid == 0) ptot[b] = s2[0];
  #pragma unroll
  for (int k = 0; k < 2; ++k) {
    int t = tid + k * 256, v = v0 + t;
    if (v < N_NODES) {
      cntg[v] = cnt[t];
      dinv[v] = rsqrtf((float)(cnt[t] + 1));
    }
  }
}

// ---- serial padded-base scan ----
__global__ void k_bscan2(const int* __restrict__ ptot, int* __restrict__ pbase,
                         int* __restrict__ offs) {
  if (threadIdx.x == 0 && blockIdx.x == 0) {
    int run = 0;
    for (int b = 0; b < NBUK; ++b) { pbase[b] = run; run += ptot[b]; }
    pbase[NBUK] = run;
    offs[N_NODES] = run;
  }
}

// ---- bucketB: padded offs + scatter + sentinel pad fill ----
__global__ __launch_bounds__(256) void k_bucketB(const int2* __restrict__ part,
                                                 const int* __restrict__ bbase,
                                                 const int* __restrict__ pbase,
                                                 const int* __restrict__ cntg,
                                                 int* __restrict__ offs,
                                                 int* __restrict__ sedge) {
  __shared__ int pre[512];
  __shared__ int cur[512];
  __shared__ int s2[256];
  int tid = threadIdx.x, b = blockIdx.x;
  int v0 = b << BSH;
  int e0 = bbase[b], e1 = bbase[b + 1];
  int e0p = pbase[b];
  int c0 = (v0 + 2 * tid < N_NODES) ? cntg[v0 + 2 * tid] : 0;
  int c1 = (v0 + 2 * tid + 1 < N_NODES) ? cntg[v0 + 2 * tid + 1] : 0;
  int pa = (c0 + 3) & ~3, pb = (c1 + 3) & ~3;
  s2[tid] = pa + pb;
  __syncthreads();
  for (int s = 1; s < 256; s <<= 1) {
    int t = (tid >= s) ? s2[tid - s] : 0;
    __syncthreads();
    s2[tid] += t;
    __syncthreads();
  }
  int eb = s2[tid] - (pa + pb);
  pre[2 * tid] = eb;       cur[2 * tid] = eb;
  pre[2 * tid + 1] = eb + pa; cur[2 * tid + 1] = eb + pa;
  __syncthreads();
  #pragma unroll
  for (int k = 0; k < 2; ++k) {
    int t = tid + k * 256, v = v0 + t;
    if (v < N_NODES) offs[v] = e0p + pre[t];
  }
  for (int i = e0 + tid; i < e1; i += 256) {
    int2 e = part[i];
    int p = atomicAdd(&cur[e.y - v0], 1);
    sedge[e0p + p] = e.x;
  }
  __syncthreads();
  #pragma unroll
  for (int k = 0; k < 2; ++k) {
    int t = tid + k * 256, v = v0 + t;
    if (v < N_NODES) {
      int endx = cur[t];
      int endp = pre[t] + ((endx - pre[t] + 3) & ~3);
      for (int u = endx; u < endp; ++u) sedge[e0p + u] = N_NODES;  // sentinel row
    }
  }
}

// pack W [K][HID] f32 row-major into MFMA B-fragment-ready bf16 layout
__global__ void k_packW(const float* __restrict__ W, uint16_t* __restrict__ Wp, int K) {
  int t = blockIdx.x * blockDim.x + threadIdx.x;
  int total = (K / 32) * 8 * 64;
  if (t >= total) return;
  int l = t & 63;
  int nt = (t >> 6) & 7;
  int ks = t >> 9;
  int kbase = ks * 32 + (l >> 4) * 8;
  int col = nt * 16 + (l & 15);
  #pragma unroll
  for (int j = 0; j < 8; ++j)
    Wp[(size_t)t * 8 + j] = (uint16_t)f2bf(W[(size_t)(kbase + j) * HID + col]);
}

// ---- X f32 -> bf16 streaming convert (8 elems/thread) ----
__global__ __launch_bounds__(256) void k_cvtX(const float* __restrict__ X,
                                              uint16_t* __restrict__ Xb) {
  int i = blockIdx.x * blockDim.x + threadIdx.x;
  if (i >= N_NODES * IN_CH / 8) return;
  const float4* src = (const float4*)(X + (size_t)i * 8);
  float4 v0 = src[0], v1 = src[1];
  uint4 o;
  o.x = f2bf(v0.x) | (f2bf(v0.y) << 16);
  o.y = f2bf(v0.z) | (f2bf(v0.w) << 16);
  o.z = f2bf(v1.x) | (f2bf(v1.y) << 16);
  o.w = f2bf(v1.z) | (f2bf(v1.w) << 16);
  *(uint4*)(Xb + (size_t)i * 8) = o;
}

// epilogue: store h' = dinv[row] * acc as fp8 e4m3 rows, via swizzled LDS repack
__device__ __forceinline__ void epilogue_fp8(const f32x4* acc, int l, int row0,
                                             uint8_t* lds_my,
                                             uint8_t* __restrict__ H8,
                                             const float* __restrict__ dinv) {
  float dv[4];
  #pragma unroll
  for (int j = 0; j < 4; ++j) {
    int r = row0 + (l >> 4) * 4 + j;
    dv[j] = dinv[min(r, N_NODES - 1)];
  }
  #pragma unroll
  for (int nt = 0; nt < 8; ++nt)
    #pragma unroll
    for (int j = 0; j < 4; ++j) {
      int r = (l >> 4) * 4 + j, c = nt * 16 + (l & 15);
      uint32_t pk = __builtin_amdgcn_cvt_pk_fp8_f32(acc[nt][j] * dv[j], 0.f, 0u, false);
      lds_my[r * 128 + (c ^ ((r & 7) << 2))] = (uint8_t)pk;  // 4B-granule swizzle by row
    }
  asm volatile("s_waitcnt lgkmcnt(0)" ::: "memory");
  int r = l >> 2;
  uint32_t w[8];
  #pragma unroll
  for (int t = 0; t < 8; ++t) {
    int c4 = (l & 3) * 8 + t;
    w[t] = *(const uint32_t*)(lds_my + r * 128 + ((c4 ^ (r & 7)) << 2));
  }
  if (row0 + r < N_NODES) {
    uint4* gp = (uint4*)(H8 + (size_t)(row0 + r) * 128 + (l & 3) * 32);
    gp[0] = make_uint4(w[0], w[1], w[2], w[3]);
    gp[1] = make_uint4(w[4], w[5], w[6], w[7]);
  }
}

// generic GEMM: A bf16 [N][K] @ Wp(LDS, 32KB K-phases) -> fp8 h' or bf16 rows.
// Block = 4 waves x 32 rows = 128 rows; 32KB LDS -> high occupancy.
template <int K, bool FP8OUT>
__global__ __launch_bounds__(256) void k_gemmT(const uint16_t* __restrict__ A,
                                               const uint16_t* __restrict__ Wp,
                                               uint8_t* __restrict__ H8,
                                               const float* __restrict__ dinv,
                                               uint16_t* __restrict__ outB) {
  __shared__ __align__(16) char smem[32768];
  int tid = threadIdx.x, wid = tid >> 6, l = tid & 63;
  int r0 = blockIdx.x * 128 + wid * 32;
  int hk = l >> 4, rl = l & 15;
  int ra0 = min(r0 + rl, N_NODES - 1);
  int ra1 = min(r0 + 16 + rl, N_NODES - 1);
  f32x4 acc[2][8] = {};
  #pragma unroll
  for (int kh = 0; kh < K / 128; ++kh) {
    __syncthreads();
    #pragma unroll
    for (int i = 0; i < 8; ++i) {
      int gidx = i * 256 + tid;
      *(uint4*)(smem + gidx * 16) =
          *(const uint4*)((const char*)Wp + (size_t)kh * 32768 + gidx * 16);
    }
    __syncthreads();
    #pragma unroll
    for (int ksl = 0; ksl < 4; ++ksl) {
      bf16x8 a0 = *(const bf16x8*)(A + (size_t)ra0 * K + kh * 128 + ksl * 32 + hk * 8);
      bf16x8 a1 = *(const bf16x8*)(A + (size_t)ra1 * K + kh * 128 + ksl * 32 + hk * 8);
      #pragma unroll
      for (int nt = 0; nt < 8; ++nt) {
        bf16x8 b = *(const bf16x8*)(smem + ((ksl * 8 + nt) * 64 + l) * 16);
        acc[0][nt] = __builtin_amdgcn_mfma_f32_16x16x32_bf16(a0, b, acc[0][nt], 0, 0, 0);
        acc[1][nt] = __builtin_amdgcn_mfma_f32_16x16x32_bf16(a1, b, acc[1][nt], 0, 0, 0);
      }
    }
  }
  __syncthreads();  // B dead; per-wave epilogue scratch (8KB each)
  if (FP8OUT) {
    uint8_t* lds8 = (uint8_t*)(smem + wid * 8192);
    epilogue_fp8(acc[0], l, r0, lds8, H8, dinv);
    epilogue_fp8(acc[1], l, r0 + 16, lds8, H8, dinv);
  } else {
    uint16_t* ldsb = (uint16_t*)(smem + wid * 8192);
    #pragma unroll
    for (int rt = 0; rt < 2; ++rt) {
      int row0 = r0 + rt * 16;
      #pragma unroll
      for (int nt = 0; nt < 8; ++nt)
        #pragma unroll
        for (int j = 0; j < 4; ++j)
          ldsb[((l >> 4) * 4 + j) * 128 + nt * 16 + (l & 15)] = (uint16_t)f2bf(acc[rt][nt][j]);
      asm volatile("s_waitcnt lgkmcnt(0)" ::: "memory");
      const uint4* sb = (const uint4*)ldsb;
      if (row0 + (l >> 2) < N_NODES) {
        uint4* gb = (uint4*)(outB + (size_t)(row0 + (l >> 2)) * 128 + (l & 3) * 32);
        #pragma unroll
        for (int t = 0; t < 4; ++t) gb[t] = sb[l * 4 + t];
      }
      asm volatile("s_waitcnt lgkmcnt(0)" ::: "memory");
    }
  }
}

// fused: fp8 gather-sum + bias + LN + ReLU + bf16 residual
// four 16-lane quarters; quarter q owns 4-edge blocks jb%4==q (uint4 index loads);
// lane owns 8 channels (uint2 gather); unweighted fp8 row sum (scales pre-folded).
#define PROC(hx, hy)                                                   \
  do {                                                                 \
    f32x2 f_;                                                          \
    f_ = __builtin_amdgcn_cvt_pk_f32_fp8((hx), false);                 \
    asm("v_pk_add_f32 %0, %0, %1" : "+v"(A01) : "v"(f_));              \
    f_ = __builtin_amdgcn_cvt_pk_f32_fp8((hx), true);                  \
    asm("v_pk_add_f32 %0, %0, %1" : "+v"(A23) : "v"(f_));              \
    f_ = __builtin_amdgcn_cvt_pk_f32_fp8((hy), false);                 \
    asm("v_pk_add_f32 %0, %0, %1" : "+v"(A45) : "v"(f_));              \
    f_ = __builtin_amdgcn_cvt_pk_f32_fp8((hy), true);                  \
    asm("v_pk_add_f32 %0, %0, %1" : "+v"(A67) : "v"(f_));              \
  } while (0)

__global__ __launch_bounds__(256) void k_agg(const uint8_t* __restrict__ H8,
                                             const int* __restrict__ sedge,
                                             const int* __restrict__ offs,
                                             const float* __restrict__ dinv,
                                             const float* __restrict__ bias,
                                             const float* __restrict__ g,
                                             const float* __restrict__ be,
                                             const uint16_t* __restrict__ residB,
                                             float* __restrict__ outF,
                                             uint16_t* __restrict__ outB) {
  int wid = threadIdx.x >> 6, l = threadIdx.x & 63;
  int v = blockIdx.x * 4 + wid;
  if (v >= N_NODES) return;
  int q = l >> 4, c = l & 15;
  uint32_t coff = (uint32_t)c << 3;
  f32x2 A01 = {0.f, 0.f}, A23 = {0.f, 0.f}, A45 = {0.f, 0.f}, A67 = {0.f, 0.f};
  int p0 = offs[v];
  int nb = (offs[v + 1] - p0) >> 2;      // 4-edge blocks (padded, exact)
  const uint4* sblk = (const uint4*)(sedge + p0);
  int jb = q;
  for (; jb + 4 < nb; jb += 8) {
    uint4 i0 = sblk[jb];
    uint4 i1 = sblk[jb + 4];
    uint2 h0 = *(const uint2*)(H8 + ((i0.x << 7) | coff));
    uint2 h1 = *(const uint2*)(H8 + ((i0.y << 7) | coff));
    uint2 h2 = *(const uint2*)(H8 + ((i0.z << 7) | coff));
    uint2 h3 = *(const uint2*)(H8 + ((i0.w << 7) | coff));
    uint2 h4 = *(const uint2*)(H8 + ((i1.x << 7) | coff));
    uint2 h5 = *(const uint2*)(H8 + ((i1.y << 7) | coff));
    uint2 h6 = *(const uint2*)(H8 + ((i1.z << 7) | coff));
    uint2 h7 = *(const uint2*)(H8 + ((i1.w << 7) | coff));
    PROC(h0.x, h0.y); PROC(h1.x, h1.y); PROC(h2.x, h2.y); PROC(h3.x, h3.y);
    PROC(h4.x, h4.y); PROC(h5.x, h5.y); PROC(h6.x, h6.y); PROC(h7.x, h7.y);
  }
  for (; jb < nb; jb += 4) {
    uint4 i0 = sblk[jb];
    uint2 h0 = *(const uint2*)(H8 + ((i0.x << 7) | coff));
    uint2 h1 = *(const uint2*)(H8 + ((i0.y << 7) | coff));
    uint2 h2 = *(const uint2*)(H8 + ((i0.z << 7) | coff));
    uint2 h3 = *(const uint2*)(H8 + ((i0.w << 7) | coff));
    PROC(h0.x, h0.y); PROC(h1.x, h1.y); PROC(h2.x, h2.y); PROC(h3.x, h3.y);
  }
  if (q == 0) {  // self loop: + own h' row
    uint2 h = *(const uint2*)(H8 + (((uint32_t)v << 7) | coff));
    PROC(h.x, h.y);
  }
  // combine the 4 quarters
  float a0 = A01.x, a1 = A01.y, a2 = A23.x, a3 = A23.y;
  float a4 = A45.x, a5 = A45.y, a6 = A67.x, a7 = A67.y;
  #pragma unroll
  for (int m = 16; m <= 32; m <<= 1) {
    a0 += __shfl_xor(a0, m, 64); a1 += __shfl_xor(a1, m, 64);
    a2 += __shfl_xor(a2, m, 64); a3 += __shfl_xor(a3, m, 64);
    a4 += __shfl_xor(a4, m, 64); a5 += __shfl_xor(a5, m, 64);
    a6 += __shfl_xor(a6, m, 64); a7 += __shfl_xor(a7, m, 64);
  }
  float dv = dinv[v];
  float4 bb0 = *(const float4*)(bias + 8 * c);
  float4 bb1 = *(const float4*)(bias + 8 * c + 4);
  a0 = dv * a0 + bb0.x; a1 = dv * a1 + bb0.y;
  a2 = dv * a2 + bb0.z; a3 = dv * a3 + bb0.w;
  a4 = dv * a4 + bb1.x; a5 = dv * a5 + bb1.y;
  a6 = dv * a6 + bb1.z; a7 = dv * a7 + bb1.w;
  // LayerNorm over 128 channels (16-lane reduction, replicated across quarters)
  float s = a0 + a1 + a2 + a3 + a4 + a5 + a6 + a7;
  #pragma unroll
  for (int m = 1; m < 16; m <<= 1) s += __shfl_xor(s, m, 64);
  float mu = s * (1.f / 128.f);
  float d0 = a0 - mu, d1 = a1 - mu, d2 = a2 - mu, d3 = a3 - mu;
  float d4 = a4 - mu, d5 = a5 - mu, d6 = a6 - mu, d7 = a7 - mu;
  float qq = d0 * d0 + d1 * d1 + d2 * d2 + d3 * d3 +
             d4 * d4 + d5 * d5 + d6 * d6 + d7 * d7;
  #pragma unroll
  for (int m = 1; m < 16; m <<= 1) qq += __shfl_xor(qq, m, 64);
  float rs = rsqrtf(qq * (1.f / 128.f) + EPS);
  float4 gg0 = *(const float4*)(g + 8 * c);
  float4 gg1 = *(const float4*)(g + 8 * c + 4);
  float4 ee0 = *(const float4*)(be + 8 * c);
  float4 ee1 = *(const float4*)(be + 8 * c + 4);
  float y0 = fmaxf(d0 * rs * gg0.x + ee0.x, 0.f);
  float y1 = fmaxf(d1 * rs * gg0.y + ee0.y, 0.f);
  float y2 = fmaxf(d2 * rs * gg0.z + ee0.z, 0.f);
  float y3 = fmaxf(d3 * rs * gg0.w + ee0.w, 0.f);
  float y4 = fmaxf(d4 * rs * gg1.x + ee1.x, 0.f);
  float y5 = fmaxf(d5 * rs * gg1.y + ee1.y, 0.f);
  float y6 = fmaxf(d6 * rs * gg1.z + ee1.z, 0.f);
  float y7 = fmaxf(d7 * rs * gg1.w + ee1.w, 0.f);
  uint4 rr = *(const uint4*)(residB + (size_t)v * 128 + 8 * c);
  y0 += bflo(rr.x); y1 += bfhi(rr.x);
  y2 += bflo(rr.y); y3 += bfhi(rr.y);
  y4 += bflo(rr.z); y5 += bfhi(rr.z);
  y6 += bflo(rr.w); y7 += bfhi(rr.w);
  if (q == 0) {
    if (outF) {
      float* op = outF + (size_t)v * HID + 8 * c;
      *(float4*)op = make_float4(y0, y1, y2, y3);
      *(float4*)(op + 4) = make_float4(y4, y5, y6, y7);
    }
    if (outB) {
      uint4 o;
      o.x = f2bf(y0) | (f2bf(y1) << 16);
      o.y = f2bf(y2) | (f2bf(y3) << 16);
      o.z = f2bf(y4) | (f2bf(y5) << 16);
      o.w = f2bf(y6) | (f2bf(y7) << 16);
      *(uint4*)(outB + (size_t)v * 128 + 8 * c) = o;
    }
  }
}

extern "C" void kernel_launch(void* const* d_in, const int* in_sizes, int n_in,
                              void* d_out, int out_size, void* d_ws, size_t ws_size,
                              hipStream_t stream) {
  const float* x   = (const float*)d_in[0];
  const void*  ei  = d_in[1];
  const float* W0  = (const float*)d_in[2];
  const float* b0  = (const float*)d_in[3];
  const float* g0  = (const float*)d_in[4];
  const float* be0 = (const float*)d_in[5];
  const float* W1  = (const float*)d_in[6];
  const float* b1  = (const float*)d_in[7];
  const float* g1  = (const float*)d_in[8];
  const float* be1 = (const float*)d_in[9];
  const float* W2  = (const float*)d_in[10];
  const float* b2  = (const float*)d_in[11];
  const float* g2  = (const float*)d_in[12];
  const float* be2 = (const float*)d_in[13];
  const float* Wr  = (const float*)d_in[14];

  char* ws = (char*)d_ws;
  int*      sedge  = (int*)(ws + OFF_SRC);
  int*      offs   = (int*)(ws + OFF_OFFS);
  float*    dinv   = (float*)(ws + OFF_DINV);
  int*      cntg   = (int*)(ws + OFF_CNTG);
  uint16_t* wpk0   = (uint16_t*)(ws + OFF_WPK0);
  uint16_t* wpk1   = (uint16_t*)(ws + OFF_WPK1);
  uint16_t* wpk2   = (uint16_t*)(ws + OFF_WPK2);
  uint16_t* wpkr   = (uint16_t*)(ws + OFF_WPKR);
  int*      flag   = (int*)(ws + OFF_FLAG);
  int*      bcnt   = (int*)(ws + OFF_BCNT);
  int*      bbase  = (int*)(ws + OFF_BBASE);
  int*      bcur   = (int*)(ws + OFF_BCUR);
  int*      ptot   = (int*)(ws + OFF_PTOT);
  int*      pbase  = (int*)(ws + OFF_PBASE);
  uint8_t*  h8     = (uint8_t*)(ws + OFF_H8);
  int2*     part   = (int2*)(ws + OFF_PART);
  uint16_t* resB   = (uint16_t*)(ws + OFF_RESB);
  uint16_t* hbA    = (uint16_t*)(ws + OFF_HBA);
  uint16_t* hbB    = (uint16_t*)(ws + OFF_HBB);
  uint16_t* xb16   = (uint16_t*)(ws + OFF_XB16);
  float*    out    = (float*)d_out;

  // ---- edge preprocessing: hist -> scan -> partition -> padded per-bucket CSR ----
  k_flag<<<1, 256, 0, stream>>>((const uint32_t*)ei, flag);
  hipMemsetAsync(bcnt, 0, NBUK * sizeof(int), stream);
  k_hist<<<2048, 256, 0, stream>>>(ei, flag, bcnt);
  k_bscan<<<1, 64, 0, stream>>>(bcnt, bbase, bcur);
  k_part<<<(N_EDGES + PCHUNK - 1) / PCHUNK, 256, 0, stream>>>(ei, flag, bcur, part);
  k_bucketA<<<NBUK, 256, 0, stream>>>(part, bbase, cntg, dinv, ptot);
  k_bscan2<<<1, 64, 0, stream>>>(ptot, pbase, offs);
  k_bucketB<<<NBUK, 256, 0, stream>>>(part, bbase, pbase, cntg, offs, sedge);
  // sentinel row (src == N_NODES) must be zero; part buffer is dead now
  hipMemsetAsync(h8 + (size_t)N_NODES * 128, 0, 128, stream);

  // ---- weight packing + X bf16 convert ----
  k_packW<<<16, 256, 0, stream>>>(W0, wpk0, IN_CH);
  k_packW<<<8, 256, 0, stream>>>(W1, wpk1, HID);
  k_packW<<<8, 256, 0, stream>>>(W2, wpk2, HID);
  k_packW<<<16, 256, 0, stream>>>(Wr, wpkr, IN_CH);
  k_cvtX<<<12500, 256, 0, stream>>>(x, xb16);

  // ---- layer 0: two K=256 GEMMs (x@W0 -> fp8 h', x@Wr -> bf16 residual) ----
  k_gemmT<256, true><<<GEMM_GRID, 256, 0, stream>>>(xb16, wpk0, h8, dinv, nullptr);
  k_gemmT<256, false><<<GEMM_GRID, 256, 0, stream>>>(xb16, wpkr, nullptr, dinv, resB);
  k_agg<<<25000, 256, 0, stream>>>(h8, sedge, offs, dinv, b0, g0, be0, resB, nullptr, hbA);

  // ---- layer 1 ----
  k_gemmT<128, true><<<GEMM_GRID, 256, 0, stream>>>(hbA, wpk1, h8, dinv, nullptr);
  k_agg<<<25000, 256, 0, stream>>>(h8, sedge, offs, dinv, b1, g1, be1, hbA, nullptr, hbB);

  // ---- layer 2 (writes d_out f32) ----
  k_gemmT<128, true><<<GEMM_GRID, 256, 0, stream>>>(hbB, wpk2, h8, dinv, nullptr);
  k_agg<<<25000, 256, 0, stream>>>(h8, sedge, offs, dinv, b2, g2, be2, hbB, out, nullptr);

  (void)in_sizes; (void)n_in; (void)out_size; (void)ws_size;
}